// Round 1
// 575.041 us; speedup vs baseline: 1.0186x; 1.0186x over previous
//
#include <hip/hip_runtime.h>

#define NN 50000
#define EE 400000
#define NB 49   // ceil(NN/1024) scan blocks

typedef __attribute__((ext_vector_type(8))) short bf16x8;
typedef __attribute__((ext_vector_type(4))) float f32x4;

__device__ __forceinline__ void fma4(float4& a, float s, const float4& w){
  a.x = fmaf(s, w.x, a.x);
  a.y = fmaf(s, w.y, a.y);
  a.z = fmaf(s, w.z, a.z);
  a.w = fmaf(s, w.w, a.w);
}

__device__ __forceinline__ unsigned short f2bf(float f){
  unsigned u = __float_as_uint(f);
  unsigned r = (u + 0x7fffu + ((u >> 16) & 1u)) >> 16;   // RNE
  return (unsigned short)r;
}

__device__ __forceinline__ bf16x8 cvt8(float4 lo, float4 hi){
  bf16x8 r;
  r[0]=(short)f2bf(lo.x); r[1]=(short)f2bf(lo.y); r[2]=(short)f2bf(lo.z); r[3]=(short)f2bf(lo.w);
  r[4]=(short)f2bf(hi.x); r[5]=(short)f2bf(hi.y); r[6]=(short)f2bf(hi.z); r[7]=(short)f2bf(hi.w);
  return r;
}

__device__ __forceinline__ unsigned rotl32(unsigned v, int d){ return (v<<d)|(v>>(32-d)); }

// jax.random.normal(key(42)) under jax_threefry_partitionable: counter (0,idx), bits=x0^x1. Verified R3.
__device__ __forceinline__ float eps_at(unsigned idx){
  const unsigned k0 = 0u, k1 = 42u, k2 = 0x1BD11BDAu ^ 0u ^ 42u;
  unsigned x0 = 0u + k0, x1 = idx + k1;
  const int rotA[4] = {13,15,26,6};
  const int rotB[4] = {17,29,16,24};
  #pragma unroll
  for (int i=0;i<4;i++){ x0 += x1; x1 = rotl32(x1, rotA[i]); x1 ^= x0; }
  x0 += k1; x1 += k2 + 1u;
  #pragma unroll
  for (int i=0;i<4;i++){ x0 += x1; x1 = rotl32(x1, rotB[i]); x1 ^= x0; }
  x0 += k2; x1 += k0 + 2u;
  #pragma unroll
  for (int i=0;i<4;i++){ x0 += x1; x1 = rotl32(x1, rotA[i]); x1 ^= x0; }
  x0 += k0; x1 += k1 + 3u;
  #pragma unroll
  for (int i=0;i<4;i++){ x0 += x1; x1 = rotl32(x1, rotB[i]); x1 ^= x0; }
  x0 += k1; x1 += k2 + 4u;
  #pragma unroll
  for (int i=0;i<4;i++){ x0 += x1; x1 = rotl32(x1, rotA[i]); x1 ^= x0; }
  x0 += k2; x1 += k0 + 5u;
  unsigned bits = x0 ^ x1;
  float f = __uint_as_float((bits >> 9) | 0x3f800000u) - 1.0f;
  const float lo = -0.99999994f;
  float u = f * 2.0f + lo;
  u = fmaxf(u, lo);
  float w = -log1pf(-u*u);
  float p;
  if (w < 5.0f){
    w -= 2.5f;
    p = 2.81022636e-08f;
    p = fmaf(p,w, 3.43273939e-07f);
    p = fmaf(p,w,-3.5233877e-06f);
    p = fmaf(p,w,-4.39150654e-06f);
    p = fmaf(p,w, 0.00021858087f);
    p = fmaf(p,w,-0.00125372503f);
    p = fmaf(p,w,-0.00417768164f);
    p = fmaf(p,w, 0.246640727f);
    p = fmaf(p,w, 1.50140941f);
  } else {
    w = sqrtf(w) - 3.0f;
    p = -0.000200214257f;
    p = fmaf(p,w, 0.000100950558f);
    p = fmaf(p,w, 0.00134934322f);
    p = fmaf(p,w,-0.00367342844f);
    p = fmaf(p,w, 0.00573950773f);
    p = fmaf(p,w,-0.0076224613f);
    p = fmaf(p,w, 0.00943887047f);
    p = fmaf(p,w, 1.00167406f);
    p = fmaf(p,w, 2.83297682f);
  }
  return 1.41421356237f * (p * u);
}

// ================= prep: bf16 conversions =================
__global__ __launch_bounds__(256) void k_prep_x(const float* __restrict__ x,
                                                unsigned short* __restrict__ xb){
  int t = blockIdx.x*256 + threadIdx.x;           // one bf16x8 per thread
  if (t < NN*64/8){
    const float4* p = (const float4*)(x + t*8);
    bf16x8 v = cvt8(p[0], p[1]);
    *(bf16x8*)(xb + t*8) = v;
  }
}

// W1T[n][k] = W1[k][n] (128x128), W2T[n][k] = W2[k][n] (64x128), bf16
__global__ __launch_bounds__(256) void k_prep_w(const float* __restrict__ W1,
                                                const float* __restrict__ W2,
                                                unsigned short* __restrict__ W1T,
                                                unsigned short* __restrict__ W2T){
  for (int i = threadIdx.x; i < 128*128; i += 256){
    int n = i >> 7, k = i & 127;
    W1T[i] = f2bf(W1[k*128 + n]);
  }
  for (int i = threadIdx.x; i < 64*128; i += 256){
    int n = i >> 7, k = i & 127;
    W2T[i] = f2bf(W2[k*64 + n]);
  }
}

// ================= CSR construction =================
__global__ __launch_bounds__(256) void k_hist(const int* __restrict__ ei, int* __restrict__ cnt){
  int e = blockIdx.x*256 + threadIdx.x;
  if (e < EE) atomicAdd(&cnt[ei[EE + e]], 1);
}

__global__ __launch_bounds__(256) void k_scan1(const int* __restrict__ cnt,
                                               int* __restrict__ offs,
                                               int* __restrict__ partials){
  __shared__ int sdata[256];
  const int t = threadIdx.x, b = blockIdx.x;
  const int base = b*1024 + t*4;
  int v0 = (base+0 < NN) ? cnt[base+0] : 0;
  int v1 = (base+1 < NN) ? cnt[base+1] : 0;
  int v2 = (base+2 < NN) ? cnt[base+2] : 0;
  int v3 = (base+3 < NN) ? cnt[base+3] : 0;
  int tsum = v0+v1+v2+v3;
  sdata[t] = tsum;
  __syncthreads();
  for (int off=1; off<256; off<<=1){
    int add = (t >= off) ? sdata[t-off] : 0;
    __syncthreads();
    sdata[t] += add;
    __syncthreads();
  }
  int run = sdata[t] - tsum;
  if (base+0 < NN) offs[base+0] = run;  run += v0;
  if (base+1 < NN) offs[base+1] = run;  run += v1;
  if (base+2 < NN) offs[base+2] = run;  run += v2;
  if (base+3 < NN) offs[base+3] = run;
  if (t == 255) partials[b] = sdata[255];
}

__global__ __launch_bounds__(64) void k_scan2(int* __restrict__ partials){
  int l = threadIdx.x;
  int v = (l < NB) ? partials[l] : 0;
  int inc = v;
  #pragma unroll
  for (int off=1; off<64; off<<=1){
    int t = __shfl_up(inc, off);
    if (l >= off) inc += t;
  }
  if (l < NB) partials[l] = inc - v;
}

__global__ __launch_bounds__(256) void k_scan3(int* __restrict__ offs,
                                               const int* __restrict__ partials,
                                               int* __restrict__ cursor){
  const int t = threadIdx.x, b = blockIdx.x;
  const int base = b*1024 + t*4;
  int add = partials[b];
  #pragma unroll
  for (int k=0;k<4;k++){
    int i = base + k;
    if (i < NN){ int o = offs[i] + add; offs[i] = o; cursor[i] = o; }
  }
}

// inverse permutation: epos[e] = CSR slot of edge e  (coalesced write)
__global__ __launch_bounds__(256) void k_fill(const int* __restrict__ ei,
                                              int* __restrict__ cursor,
                                              int* __restrict__ epos){
  int e = blockIdx.x*256 + threadIdx.x;
  if (e < EE){
    int c = ei[EE + e];
    epos[e] = atomicAdd(&cursor[c], 1);
  }
}

// ---------------- kernel 2: edge MLP via MFMA -> h_ws (CSR-ordered) ----------------
// GEMM1: M=64 edges, N=128, K=128 ([x_bf16[row] | cvt(ea)]);  LN+ReLU fp32 in LDS;
// GEMM2: M=64, N=64, K=128.  mfma_f32_16x16x32_bf16.
// Epilogue stores edge m's h row at CSR slot epos[e] so k_node reads contiguously.
#define H1STR 132
__global__ __launch_bounds__(256, 4) void k_edge(const int* __restrict__ ei,
    const float* __restrict__ ea,
    const unsigned short* __restrict__ xb,
    const unsigned short* __restrict__ W1T, const float* __restrict__ b1,
    const float* __restrict__ g1, const float* __restrict__ be1,
    const unsigned short* __restrict__ W2T, const float* __restrict__ b2,
    const int* __restrict__ epos,
    float* __restrict__ h_ws){
  __shared__ __align__(16) float h1[64*H1STR];   // 33,792 B
  __shared__ int rows_l[64];
  __shared__ int slot_l[64];
  const int tid  = threadIdx.x;
  const int base = blockIdx.x * 64;
  const int wv   = tid >> 6;        // wave 0..3
  const int lane = tid & 63;
  const int quad = lane >> 4;       // 0..3
  const int l16  = lane & 15;
  if (tid < 64) rows_l[tid] = ei[base + tid];
  if (tid >= 128 && tid < 192) slot_l[tid-128] = epos[base + tid - 128];
  __syncthreads();
  // ---- GEMM1: wave wv owns n-groups {2wv, 2wv+1}, all 4 m-groups ----
  {
    int rw[4];
    #pragma unroll
    for (int m=0;m<4;m++) rw[m] = rows_l[m*16 + l16];
    f32x4 acc[4][2];
    #pragma unroll
    for (int m=0;m<4;m++){ acc[m][0] = (f32x4){0.f,0.f,0.f,0.f}; acc[m][1] = (f32x4){0.f,0.f,0.f,0.f}; }
    #pragma unroll
    for (int ks=0; ks<4; ks++){
      bf16x8 af[4];
      if (ks < 2){
        #pragma unroll
        for (int m=0;m<4;m++)
          af[m] = *(const bf16x8*)(xb + (size_t)rw[m]*64 + ks*32 + quad*8);
      } else {
        #pragma unroll
        for (int m=0;m<4;m++){
          const float* p = ea + (size_t)(base + m*16 + l16)*64 + (ks-2)*32 + quad*8;
          af[m] = cvt8(*(const float4*)p, *(const float4*)(p+4));
        }
      }
      bf16x8 bf0 = *(const bf16x8*)(W1T + (size_t)((2*wv+0)*16 + l16)*128 + ks*32 + quad*8);
      bf16x8 bf1 = *(const bf16x8*)(W1T + (size_t)((2*wv+1)*16 + l16)*128 + ks*32 + quad*8);
      #pragma unroll
      for (int m=0;m<4;m++){
        acc[m][0] = __builtin_amdgcn_mfma_f32_16x16x32_bf16(af[m], bf0, acc[m][0], 0, 0, 0);
        acc[m][1] = __builtin_amdgcn_mfma_f32_16x16x32_bf16(af[m], bf1, acc[m][1], 0, 0, 0);
      }
    }
    // bias + scatter D (col=lane&15, row=quad*4+reg) into LDS fp32
    #pragma unroll
    for (int nl=0; nl<2; nl++){
      float b1c = b1[(2*wv+nl)*16 + l16];
      #pragma unroll
      for (int m=0;m<4;m++){
        #pragma unroll
        for (int r=0;r<4;r++)
          h1[(m*16 + quad*4 + r)*H1STR + (2*wv+nl)*16 + l16] = acc[m][nl][r] + b1c;
      }
    }
  }
  __syncthreads();
  // ---- LayerNorm(128) + ReLU (fp32, wave per row) ----
  {
    const float gA = g1[lane], gB = g1[lane+64];
    const float bA = be1[lane], bB = be1[lane+64];
    for (int r = wv*16; r < wv*16 + 16; ++r){
      float a = h1[r*H1STR + lane];
      float b = h1[r*H1STR + 64 + lane];
      float s = a + b, ss = fmaf(a,a,b*b);
      #pragma unroll
      for (int off=32; off; off>>=1){
        s  += __shfl_xor(s, off);
        ss += __shfl_xor(ss, off);
      }
      float mean = s * (1.0f/128.0f);
      float var  = ss * (1.0f/128.0f) - mean*mean;
      float inv = rsqrtf(var + 1e-5f);
      h1[r*H1STR + lane]      = fmaxf(fmaf((a-mean)*inv, gA, bA), 0.f);
      h1[r*H1STR + 64 + lane] = fmaxf(fmaf((b-mean)*inv, gB, bB), 0.f);
    }
  }
  __syncthreads();
  // ---- GEMM2: wave wv owns n-group wv, all 4 m-groups ----
  {
    f32x4 acc2[4];
    #pragma unroll
    for (int m=0;m<4;m++) acc2[m] = (f32x4){0.f,0.f,0.f,0.f};
    #pragma unroll
    for (int ks=0; ks<4; ks++){
      bf16x8 bfr = *(const bf16x8*)(W2T + (size_t)(wv*16 + l16)*128 + ks*32 + quad*8);
      #pragma unroll
      for (int m=0;m<4;m++){
        const float* p = h1 + (m*16 + l16)*H1STR + ks*32 + quad*8;
        bf16x8 af = cvt8(*(const float4*)p, *(const float4*)(p+4));
        acc2[m] = __builtin_amdgcn_mfma_f32_16x16x32_bf16(af, bfr, acc2[m], 0, 0, 0);
      }
    }
    float b2c = b2[wv*16 + l16];
    #pragma unroll
    for (int m=0;m<4;m++){
      #pragma unroll
      for (int r=0;r<4;r++)
        h_ws[(size_t)slot_l[m*16 + quad*4 + r]*64 + wv*16 + l16] = acc2[m][r] + b2c;
    }
  }
}

// ---------------- kernel 3: streaming CSR-aggregate + node MLP + heads + reparam ----------------
#define T2STR 132
#define ZSSTR 36
__global__ __launch_bounds__(256, 3) void k_node(const float* __restrict__ x,
    const float* __restrict__ u, const int* __restrict__ batch,
    const float* __restrict__ h_ws, const int* __restrict__ cnt,
    const int* __restrict__ offs,
    const float* __restrict__ W3, const float* __restrict__ b3,
    const float* __restrict__ g3, const float* __restrict__ be3,
    const float* __restrict__ W4, const float* __restrict__ b4,
    const float* __restrict__ g4, const float* __restrict__ be4,
    const float* __restrict__ Wm, const float* __restrict__ bm,
    const float* __restrict__ Wv, const float* __restrict__ bv,
    const float* __restrict__ Wx, const float* __restrict__ bx,
    float* __restrict__ out){
  __shared__ __align__(16) float zS[32*160];   // z (160) -> t2 (132) -> zs (36)
  __shared__ __align__(16) float h3S[32*256];  // h3 -> hm (32x64 mu|lv)
  const int tid = threadIdx.x;
  const int base = blockIdx.x * 32;
  #pragma unroll
  for (int i=0;i<2;i++){
    int l = tid + 256*i;
    int r = l >> 4, c4 = (l & 15) * 4;
    int n = base + r;
    float4 v = make_float4(0.f,0.f,0.f,0.f);
    if (n < NN) v = *(const float4*)(x + (size_t)n*64 + c4);
    *(float4*)(zS + r*160 + c4) = v;
  }
  {
    int r = tid >> 3, c4 = (tid & 7) * 4;
    int n = base + r;
    float4 v = make_float4(0.f,0.f,0.f,0.f);
    if (n < NN) v = *(const float4*)(u + (size_t)batch[n]*32 + c4);
    *(float4*)(zS + r*160 + 128 + c4) = v;
  }
  // ---- aggregation: h_ws is CSR-ordered, node n's rows at [offs[n], offs[n]+deg) ----
  {
    int r = tid >> 3, p = tid & 7;
    int n = base + r;
    float4 a0 = make_float4(0.f,0.f,0.f,0.f), a1 = a0;
    int deg = 0;
    if (n < NN){
      deg = cnt[n];
      const float* hp = h_ws + (size_t)offs[n]*64 + p*8;
      int j = 0;
      for (; j + 2 <= deg; j += 2){
        float4 v0 = *(const float4*)(hp);
        float4 v1 = *(const float4*)(hp + 4);
        float4 w0 = *(const float4*)(hp + 64);
        float4 w1 = *(const float4*)(hp + 68);
        hp += 128;
        a0.x += v0.x; a0.y += v0.y; a0.z += v0.z; a0.w += v0.w;
        a1.x += v1.x; a1.y += v1.y; a1.z += v1.z; a1.w += v1.w;
        a0.x += w0.x; a0.y += w0.y; a0.z += w0.z; a0.w += w0.w;
        a1.x += w1.x; a1.y += w1.y; a1.z += w1.z; a1.w += w1.w;
      }
      if (j < deg){
        float4 v0 = *(const float4*)(hp);
        float4 v1 = *(const float4*)(hp + 4);
        a0.x += v0.x; a0.y += v0.y; a0.z += v0.z; a0.w += v0.w;
        a1.x += v1.x; a1.y += v1.y; a1.z += v1.z; a1.w += v1.w;
      }
    }
    float rc = 1.0f / fmaxf((float)deg, 1.0f);
    a0.x*=rc; a0.y*=rc; a0.z*=rc; a0.w*=rc;
    a1.x*=rc; a1.y*=rc; a1.z*=rc; a1.w*=rc;
    *(float4*)(zS + r*160 + 64 + p*8)     = a0;
    *(float4*)(zS + r*160 + 64 + p*8 + 4) = a1;
  }
  __syncthreads();   // B0
  {
    const int jq = tid & 63, rb = tid >> 6;
    float4 acc[8];
    #pragma unroll
    for (int r=0;r<8;r++) acc[r] = make_float4(0.f,0.f,0.f,0.f);
    for (int k=0;k<160;k+=4){
      float4 w0 = *(const float4*)(W3 + (k+0)*256 + 4*jq);
      float4 w1 = *(const float4*)(W3 + (k+1)*256 + 4*jq);
      float4 w2 = *(const float4*)(W3 + (k+2)*256 + 4*jq);
      float4 w3v= *(const float4*)(W3 + (k+3)*256 + 4*jq);
      #pragma unroll
      for (int r=0;r<8;r++){
        float4 z = *(const float4*)(zS + (rb*8+r)*160 + k);
        fma4(acc[r], z.x, w0); fma4(acc[r], z.y, w1);
        fma4(acc[r], z.z, w2); fma4(acc[r], z.w, w3v);
      }
    }
    float4 bb  = *(const float4*)(b3 + 4*jq);
    float4 gg  = *(const float4*)(g3 + 4*jq);
    float4 bet = *(const float4*)(be3 + 4*jq);
    #pragma unroll
    for (int r=0;r<8;r++){
      float4 v = acc[r];
      v.x += bb.x; v.y += bb.y; v.z += bb.z; v.w += bb.w;
      float s  = v.x + v.y + v.z + v.w;
      float ss = fmaf(v.x,v.x, fmaf(v.y,v.y, fmaf(v.z,v.z, v.w*v.w)));
      #pragma unroll
      for (int off=32; off; off>>=1){ s += __shfl_xor(s,off); ss += __shfl_xor(ss,off); }
      float mean = s * (1.0f/256.0f);
      float inv  = rsqrtf(ss*(1.0f/256.0f) - mean*mean + 1e-5f);
      float4 o;
      o.x = fmaxf(fmaf((v.x-mean)*inv, gg.x, bet.x), 0.f);
      o.y = fmaxf(fmaf((v.y-mean)*inv, gg.y, bet.y), 0.f);
      o.z = fmaxf(fmaf((v.z-mean)*inv, gg.z, bet.z), 0.f);
      o.w = fmaxf(fmaf((v.w-mean)*inv, gg.w, bet.w), 0.f);
      *(float4*)(h3S + (rb*8+r)*256 + 4*jq) = o;
    }
  }
  __syncthreads();   // B1
  {
    const int jq = tid & 31, rb = tid >> 5;
    float4 acc[4];
    #pragma unroll
    for (int r=0;r<4;r++) acc[r] = make_float4(0.f,0.f,0.f,0.f);
    for (int k=0;k<256;k+=4){
      float4 w0 = *(const float4*)(W4 + (k+0)*128 + 4*jq);
      float4 w1 = *(const float4*)(W4 + (k+1)*128 + 4*jq);
      float4 w2 = *(const float4*)(W4 + (k+2)*128 + 4*jq);
      float4 w3 = *(const float4*)(W4 + (k+3)*128 + 4*jq);
      #pragma unroll
      for (int r=0;r<4;r++){
        float4 z = *(const float4*)(h3S + (rb*4+r)*256 + k);
        fma4(acc[r], z.x, w0); fma4(acc[r], z.y, w1);
        fma4(acc[r], z.z, w2); fma4(acc[r], z.w, w3);
      }
    }
    float4 bb  = *(const float4*)(b4 + 4*jq);
    float4 gg  = *(const float4*)(g4 + 4*jq);
    float4 bet = *(const float4*)(be4 + 4*jq);
    #pragma unroll
    for (int r=0;r<4;r++){
      float4 v = acc[r];
      v.x += bb.x; v.y += bb.y; v.z += bb.z; v.w += bb.w;
      float s  = v.x + v.y + v.z + v.w;
      float ss = fmaf(v.x,v.x, fmaf(v.y,v.y, fmaf(v.z,v.z, v.w*v.w)));
      #pragma unroll
      for (int off=16; off; off>>=1){ s += __shfl_xor(s,off); ss += __shfl_xor(ss,off); }
      float mean = s * (1.0f/128.0f);
      float inv  = rsqrtf(ss*(1.0f/128.0f) - mean*mean + 1e-5f);
      float4 o;
      o.x = fmaxf(fmaf((v.x-mean)*inv, gg.x, bet.x), 0.f);
      o.y = fmaxf(fmaf((v.y-mean)*inv, gg.y, bet.y), 0.f);
      o.z = fmaxf(fmaf((v.z-mean)*inv, gg.z, bet.z), 0.f);
      o.w = fmaxf(fmaf((v.w-mean)*inv, gg.w, bet.w), 0.f);
      *(float4*)(zS + (rb*4+r)*T2STR + 4*jq) = o;
    }
  }
  __syncthreads();   // B2
  {
    const int jq = tid & 15, rb = tid >> 4;
    const float* Wp = (jq < 8) ? Wm : Wv;
    const int cq = (jq & 7) * 4;
    float4 acc[2];
    #pragma unroll
    for (int r=0;r<2;r++) acc[r] = make_float4(0.f,0.f,0.f,0.f);
    for (int k=0;k<128;k+=4){
      float4 w0 = *(const float4*)(Wp + (k+0)*32 + cq);
      float4 w1 = *(const float4*)(Wp + (k+1)*32 + cq);
      float4 w2 = *(const float4*)(Wp + (k+2)*32 + cq);
      float4 w3 = *(const float4*)(Wp + (k+3)*32 + cq);
      #pragma unroll
      for (int r=0;r<2;r++){
        float4 z = *(const float4*)(zS + (rb*2+r)*T2STR + k);
        fma4(acc[r], z.x, w0); fma4(acc[r], z.y, w1);
        fma4(acc[r], z.z, w2); fma4(acc[r], z.w, w3);
      }
    }
    const float* bp = (jq < 8) ? bm : bv;
    float4 bb = *(const float4*)(bp + cq);
    const long long sec = (jq < 8) ? (long long)NN*64 : ((long long)NN*64 + (long long)NN*32);
    #pragma unroll
    for (int r=0;r<2;r++){
      float4 v = acc[r];
      v.x += bb.x; v.y += bb.y; v.z += bb.z; v.w += bb.w;
      int rr = rb*2 + r;
      *(float4*)(h3S + rr*64 + ((jq<8)?0:32) + cq) = v;
      int n = base + rr;
      if (n < NN) *(float4*)(out + sec + (long long)n*32 + cq) = v;
    }
  }
  __syncthreads();   // B3
  #pragma unroll
  for (int i=0;i<4;i++){
    int l = tid + 256*i;
    int r = l >> 5, jj = l & 31;
    float mu = h3S[r*64 + jj];
    float lv = h3S[r*64 + 32 + jj];
    unsigned idx = (unsigned)((base + r)*32 + jj);
    float e = eps_at(idx);
    zS[r*ZSSTR + jj] = fmaf(e, expf(0.5f*lv), mu);
  }
  __syncthreads();   // B4
  {
    const int jq = tid & 15, rb = tid >> 4;
    float4 acc[2];
    #pragma unroll
    for (int r=0;r<2;r++) acc[r] = make_float4(0.f,0.f,0.f,0.f);
    for (int k=0;k<32;k+=4){
      float4 w0 = *(const float4*)(Wx + (k+0)*64 + 4*jq);
      float4 w1 = *(const float4*)(Wx + (k+1)*64 + 4*jq);
      float4 w2 = *(const float4*)(Wx + (k+2)*64 + 4*jq);
      float4 w3 = *(const float4*)(Wx + (k+3)*64 + 4*jq);
      #pragma unroll
      for (int r=0;r<2;r++){
        float4 z = *(const float4*)(zS + (rb*2+r)*ZSSTR + k);
        fma4(acc[r], z.x, w0); fma4(acc[r], z.y, w1);
        fma4(acc[r], z.z, w2); fma4(acc[r], z.w, w3);
      }
    }
    float4 bb = *(const float4*)(bx + 4*jq);
    #pragma unroll
    for (int r=0;r<2;r++){
      int n = base + rb*2 + r;
      if (n < NN){
        float4 v = acc[r];
        v.x += bb.x; v.y += bb.y; v.z += bb.z; v.w += bb.w;
        *(float4*)(out + (long long)n*64 + 4*jq) = v;
      }
    }
  }
}

extern "C" void kernel_launch(void* const* d_in, const int* in_sizes, int n_in,
                              void* d_out, int out_size, void* d_ws, size_t ws_size,
                              hipStream_t stream) {
  const float* x     = (const float*)d_in[0];
  const int*   ei    = (const int*)d_in[1];
  const float* ea    = (const float*)d_in[2];
  const float* u     = (const float*)d_in[3];
  const int*   batch = (const int*)d_in[4];
  const float* W1 = (const float*)d_in[6];
  const float* b1 = (const float*)d_in[7];
  const float* g1 = (const float*)d_in[8];
  const float* be1= (const float*)d_in[9];
  const float* W2 = (const float*)d_in[10];
  const float* b2 = (const float*)d_in[11];
  const float* W3 = (const float*)d_in[12];
  const float* b3 = (const float*)d_in[13];
  const float* g3 = (const float*)d_in[14];
  const float* be3= (const float*)d_in[15];
  const float* W4 = (const float*)d_in[16];
  const float* b4 = (const float*)d_in[17];
  const float* g4 = (const float*)d_in[18];
  const float* be4= (const float*)d_in[19];
  const float* Wm = (const float*)d_in[20];
  const float* bm = (const float*)d_in[21];
  const float* Wv = (const float*)d_in[22];
  const float* bv = (const float*)d_in[23];
  const float* Wx = (const float*)d_in[24];
  const float* bx = (const float*)d_in[25];

  char* W = (char*)d_ws;
  size_t off = 0;
  float* h_ws = (float*)(W + off);  off += (size_t)EE*64*4;     // 102.4 MB
  int* cnt      = (int*)(W + off);  off += (size_t)NN*4;
  int* offs     = (int*)(W + off);  off += (size_t)NN*4;
  int* cursor   = (int*)(W + off);  off += (size_t)NN*4;
  int* epos     = (int*)(W + off);  off += (size_t)EE*4;
  int* partials = (int*)(W + off);  off += 256;
  unsigned short* xb  = (unsigned short*)(W + off); off += (size_t)NN*64*2;  // 6.4 MB
  unsigned short* W1T = (unsigned short*)(W + off); off += 128*128*2;
  unsigned short* W2T = (unsigned short*)(W + off); off += 64*128*2;
  float* out = (float*)d_out;

  hipMemsetAsync(cnt, 0, (size_t)NN*sizeof(int), stream);

  k_prep_x<<<(NN*64/8 + 255)/256, 256, 0, stream>>>(x, xb);
  k_prep_w<<<1, 256, 0, stream>>>(W1, W2, W1T, W2T);
  k_hist <<<(EE+255)/256, 256, 0, stream>>>(ei, cnt);
  k_scan1<<<NB, 256, 0, stream>>>(cnt, offs, partials);
  k_scan2<<<1, 64, 0, stream>>>(partials);
  k_scan3<<<NB, 256, 0, stream>>>(offs, partials, cursor);
  k_fill <<<(EE+255)/256, 256, 0, stream>>>(ei, cursor, epos);

  k_edge<<<EE/64, 256, 0, stream>>>(ei, ea, xb, W1T, b1, g1, be1, W2T, b2, epos, h_ws);
  k_node<<<(NN+31)/32, 256, 0, stream>>>(x, u, batch, h_ws, cnt, offs,
                                         W3,b3,g3,be3, W4,b4,g4,be4,
                                         Wm,bm, Wv,bv, Wx,bx, out);
}

// Round 3
// 572.306 us; speedup vs baseline: 1.0235x; 1.0048x over previous
//
#include <hip/hip_runtime.h>

#define NN 50000
#define EE 400000
#define NB 49   // ceil(NN/1024) scan blocks

typedef __attribute__((ext_vector_type(8))) short bf16x8;
typedef __attribute__((ext_vector_type(4))) float f32x4;

__device__ __forceinline__ void fma4(float4& a, float s, const float4& w){
  a.x = fmaf(s, w.x, a.x);
  a.y = fmaf(s, w.y, a.y);
  a.z = fmaf(s, w.z, a.z);
  a.w = fmaf(s, w.w, a.w);
}

__device__ __forceinline__ unsigned short f2bf(float f){
  unsigned u = __float_as_uint(f);
  unsigned r = (u + 0x7fffu + ((u >> 16) & 1u)) >> 16;   // RNE
  return (unsigned short)r;
}

__device__ __forceinline__ bf16x8 cvt8(float4 lo, float4 hi){
  bf16x8 r;
  r[0]=(short)f2bf(lo.x); r[1]=(short)f2bf(lo.y); r[2]=(short)f2bf(lo.z); r[3]=(short)f2bf(lo.w);
  r[4]=(short)f2bf(hi.x); r[5]=(short)f2bf(hi.y); r[6]=(short)f2bf(hi.z); r[7]=(short)f2bf(hi.w);
  return r;
}

// pack fp32 -> (bf16_hi << 16) | bf16_lo, where hi+lo ~= v to ~16 mantissa bits
__device__ __forceinline__ unsigned packhl(float v){
  unsigned hi = f2bf(v);
  float fh = __uint_as_float(hi << 16);
  unsigned lo = f2bf(v - fh);
  return (hi << 16) | lo;
}

__device__ __forceinline__ uint4 pack4(float4 v){
  uint4 p;
  p.x = packhl(v.x); p.y = packhl(v.y); p.z = packhl(v.z); p.w = packhl(v.w);
  return p;
}

__device__ __forceinline__ void unpack8(uint4 p0, uint4 p1, bf16x8& hi, bf16x8& lo){
  hi[0]=(short)(p0.x>>16); lo[0]=(short)(p0.x & 0xffffu);
  hi[1]=(short)(p0.y>>16); lo[1]=(short)(p0.y & 0xffffu);
  hi[2]=(short)(p0.z>>16); lo[2]=(short)(p0.z & 0xffffu);
  hi[3]=(short)(p0.w>>16); lo[3]=(short)(p0.w & 0xffffu);
  hi[4]=(short)(p1.x>>16); lo[4]=(short)(p1.x & 0xffffu);
  hi[5]=(short)(p1.y>>16); lo[5]=(short)(p1.y & 0xffffu);
  hi[6]=(short)(p1.z>>16); lo[6]=(short)(p1.z & 0xffffu);
  hi[7]=(short)(p1.w>>16); lo[7]=(short)(p1.w & 0xffffu);
}

__device__ __forceinline__ unsigned rotl32(unsigned v, int d){ return (v<<d)|(v>>(32-d)); }

// jax.random.normal(key(42)) under jax_threefry_partitionable: counter (0,idx), bits=x0^x1. Verified R3.
__device__ __forceinline__ float eps_at(unsigned idx){
  const unsigned k0 = 0u, k1 = 42u, k2 = 0x1BD11BDAu ^ 0u ^ 42u;
  unsigned x0 = 0u + k0, x1 = idx + k1;
  const int rotA[4] = {13,15,26,6};
  const int rotB[4] = {17,29,16,24};
  #pragma unroll
  for (int i=0;i<4;i++){ x0 += x1; x1 = rotl32(x1, rotA[i]); x1 ^= x0; }
  x0 += k1; x1 += k2 + 1u;
  #pragma unroll
  for (int i=0;i<4;i++){ x0 += x1; x1 = rotl32(x1, rotB[i]); x1 ^= x0; }
  x0 += k2; x1 += k0 + 2u;
  #pragma unroll
  for (int i=0;i<4;i++){ x0 += x1; x1 = rotl32(x1, rotA[i]); x1 ^= x0; }
  x0 += k0; x1 += k1 + 3u;
  #pragma unroll
  for (int i=0;i<4;i++){ x0 += x1; x1 = rotl32(x1, rotB[i]); x1 ^= x0; }
  x0 += k1; x1 += k2 + 4u;
  #pragma unroll
  for (int i=0;i<4;i++){ x0 += x1; x1 = rotl32(x1, rotA[i]); x1 ^= x0; }
  x0 += k2; x1 += k0 + 5u;
  unsigned bits = x0 ^ x1;
  float f = __uint_as_float((bits >> 9) | 0x3f800000u) - 1.0f;
  const float lo = -0.99999994f;
  float u = f * 2.0f + lo;
  u = fmaxf(u, lo);
  float w = -log1pf(-u*u);
  float p;
  if (w < 5.0f){
    w -= 2.5f;
    p = 2.81022636e-08f;
    p = fmaf(p,w, 3.43273939e-07f);
    p = fmaf(p,w,-3.5233877e-06f);
    p = fmaf(p,w,-4.39150654e-06f);
    p = fmaf(p,w, 0.00021858087f);
    p = fmaf(p,w,-0.00125372503f);
    p = fmaf(p,w,-0.00417768164f);
    p = fmaf(p,w, 0.246640727f);
    p = fmaf(p,w, 1.50140941f);
  } else {
    w = sqrtf(w) - 3.0f;
    p = -0.000200214257f;
    p = fmaf(p,w, 0.000100950558f);
    p = fmaf(p,w, 0.00134934322f);
    p = fmaf(p,w,-0.00367342844f);
    p = fmaf(p,w, 0.00573950773f);
    p = fmaf(p,w,-0.0076224613f);
    p = fmaf(p,w, 0.00943887047f);
    p = fmaf(p,w, 1.00167406f);
    p = fmaf(p,w, 2.83297682f);
  }
  return 1.41421356237f * (p * u);
}

// ================= prep: bf16 conversions =================
__global__ __launch_bounds__(256) void k_prep_x(const float* __restrict__ x,
                                                unsigned short* __restrict__ xb){
  int t = blockIdx.x*256 + threadIdx.x;           // one bf16x8 per thread
  if (t < NN*64/8){
    const float4* p = (const float4*)(x + t*8);
    bf16x8 v = cvt8(p[0], p[1]);
    *(bf16x8*)(xb + t*8) = v;
  }
}

// W1T[n][k] = W1[k][n] (128x128), W2T[n][k] = W2[k][n] (64x128), bf16
__global__ __launch_bounds__(256) void k_prep_w(const float* __restrict__ W1,
                                                const float* __restrict__ W2,
                                                unsigned short* __restrict__ W1T,
                                                unsigned short* __restrict__ W2T){
  for (int i = threadIdx.x; i < 128*128; i += 256){
    int n = i >> 7, k = i & 127;
    W1T[i] = f2bf(W1[k*128 + n]);
  }
  for (int i = threadIdx.x; i < 64*128; i += 256){
    int n = i >> 7, k = i & 127;
    W2T[i] = f2bf(W2[k*64 + n]);
  }
}

// W3T hi/lo [256][160] from W3[160][256]; W4T hi/lo [128][256] from W4[256][128]
__global__ __launch_bounds__(256) void k_prep_w34(const float* __restrict__ W3,
                                                  const float* __restrict__ W4,
                                                  unsigned short* __restrict__ W3Th,
                                                  unsigned short* __restrict__ W3Tl,
                                                  unsigned short* __restrict__ W4Th,
                                                  unsigned short* __restrict__ W4Tl){
  int b = blockIdx.x;
  if (b < 256){
    int n = b;
    for (int k = threadIdx.x; k < 160; k += 256){
      float w = W3[k*256 + n];
      unsigned h = f2bf(w);
      float fh = __uint_as_float(h << 16);
      W3Th[n*160 + k] = (unsigned short)h;
      W3Tl[n*160 + k] = f2bf(w - fh);
    }
  } else {
    int n = b - 256;            // < 128
    int k = threadIdx.x;        // 256 threads, K=256
    float w = W4[k*128 + n];
    unsigned h = f2bf(w);
    float fh = __uint_as_float(h << 16);
    W4Th[n*256 + k] = (unsigned short)h;
    W4Tl[n*256 + k] = f2bf(w - fh);
  }
}

// ================= CSR construction =================
__global__ __launch_bounds__(256) void k_hist(const int* __restrict__ ei, int* __restrict__ cnt){
  int e = blockIdx.x*256 + threadIdx.x;
  if (e < EE) atomicAdd(&cnt[ei[EE + e]], 1);
}

__global__ __launch_bounds__(256) void k_scan1(const int* __restrict__ cnt,
                                               int* __restrict__ offs,
                                               int* __restrict__ partials){
  __shared__ int sdata[256];
  const int t = threadIdx.x, b = blockIdx.x;
  const int base = b*1024 + t*4;
  int v0 = (base+0 < NN) ? cnt[base+0] : 0;
  int v1 = (base+1 < NN) ? cnt[base+1] : 0;
  int v2 = (base+2 < NN) ? cnt[base+2] : 0;
  int v3 = (base+3 < NN) ? cnt[base+3] : 0;
  int tsum = v0+v1+v2+v3;
  sdata[t] = tsum;
  __syncthreads();
  for (int off=1; off<256; off<<=1){
    int add = (t >= off) ? sdata[t-off] : 0;
    __syncthreads();
    sdata[t] += add;
    __syncthreads();
  }
  int run = sdata[t] - tsum;
  if (base+0 < NN) offs[base+0] = run;  run += v0;
  if (base+1 < NN) offs[base+1] = run;  run += v1;
  if (base+2 < NN) offs[base+2] = run;  run += v2;
  if (base+3 < NN) offs[base+3] = run;
  if (t == 255) partials[b] = sdata[255];
}

__global__ __launch_bounds__(64) void k_scan2(int* __restrict__ partials){
  int l = threadIdx.x;
  int v = (l < NB) ? partials[l] : 0;
  int inc = v;
  #pragma unroll
  for (int off=1; off<64; off<<=1){
    int t = __shfl_up(inc, off);
    if (l >= off) inc += t;
  }
  if (l < NB) partials[l] = inc - v;
}

__global__ __launch_bounds__(256) void k_scan3(int* __restrict__ offs,
                                               const int* __restrict__ partials,
                                               int* __restrict__ cursor){
  const int t = threadIdx.x, b = blockIdx.x;
  const int base = b*1024 + t*4;
  int add = partials[b];
  #pragma unroll
  for (int k=0;k<4;k++){
    int i = base + k;
    if (i < NN){ int o = offs[i] + add; offs[i] = o; cursor[i] = o; }
  }
}

// inverse permutation: epos[e] = CSR slot of edge e  (coalesced write)
__global__ __launch_bounds__(256) void k_fill(const int* __restrict__ ei,
                                              int* __restrict__ cursor,
                                              int* __restrict__ epos){
  int e = blockIdx.x*256 + threadIdx.x;
  if (e < EE){
    int c = ei[EE + e];
    epos[e] = atomicAdd(&cursor[c], 1);
  }
}

// ---------------- kernel 2: edge MLP via MFMA -> h_ws (CSR-ordered) ----------------
#define H1STR 132
__global__ __launch_bounds__(256, 4) void k_edge(const int* __restrict__ ei,
    const float* __restrict__ ea,
    const unsigned short* __restrict__ xb,
    const unsigned short* __restrict__ W1T, const float* __restrict__ b1,
    const float* __restrict__ g1, const float* __restrict__ be1,
    const unsigned short* __restrict__ W2T, const float* __restrict__ b2,
    const int* __restrict__ epos,
    float* __restrict__ h_ws){
  __shared__ __align__(16) float h1[64*H1STR];   // 33,792 B
  __shared__ int rows_l[64];
  __shared__ int slot_l[64];
  const int tid  = threadIdx.x;
  const int base = blockIdx.x * 64;
  const int wv   = tid >> 6;        // wave 0..3
  const int lane = tid & 63;
  const int quad = lane >> 4;       // 0..3
  const int l16  = lane & 15;
  if (tid < 64) rows_l[tid] = ei[base + tid];
  if (tid >= 128 && tid < 192) slot_l[tid-128] = epos[base + tid - 128];
  __syncthreads();
  // ---- GEMM1: wave wv owns n-groups {2wv, 2wv+1}, all 4 m-groups ----
  {
    int rw[4];
    #pragma unroll
    for (int m=0;m<4;m++) rw[m] = rows_l[m*16 + l16];
    f32x4 acc[4][2];
    #pragma unroll
    for (int m=0;m<4;m++){ acc[m][0] = (f32x4){0.f,0.f,0.f,0.f}; acc[m][1] = (f32x4){0.f,0.f,0.f,0.f}; }
    #pragma unroll
    for (int ks=0; ks<4; ks++){
      bf16x8 af[4];
      if (ks < 2){
        #pragma unroll
        for (int m=0;m<4;m++)
          af[m] = *(const bf16x8*)(xb + (size_t)rw[m]*64 + ks*32 + quad*8);
      } else {
        #pragma unroll
        for (int m=0;m<4;m++){
          const float* p = ea + (size_t)(base + m*16 + l16)*64 + (ks-2)*32 + quad*8;
          af[m] = cvt8(*(const float4*)p, *(const float4*)(p+4));
        }
      }
      bf16x8 bf0 = *(const bf16x8*)(W1T + (size_t)((2*wv+0)*16 + l16)*128 + ks*32 + quad*8);
      bf16x8 bf1 = *(const bf16x8*)(W1T + (size_t)((2*wv+1)*16 + l16)*128 + ks*32 + quad*8);
      #pragma unroll
      for (int m=0;m<4;m++){
        acc[m][0] = __builtin_amdgcn_mfma_f32_16x16x32_bf16(af[m], bf0, acc[m][0], 0, 0, 0);
        acc[m][1] = __builtin_amdgcn_mfma_f32_16x16x32_bf16(af[m], bf1, acc[m][1], 0, 0, 0);
      }
    }
    #pragma unroll
    for (int nl=0; nl<2; nl++){
      float b1c = b1[(2*wv+nl)*16 + l16];
      #pragma unroll
      for (int m=0;m<4;m++){
        #pragma unroll
        for (int r=0;r<4;r++)
          h1[(m*16 + quad*4 + r)*H1STR + (2*wv+nl)*16 + l16] = acc[m][nl][r] + b1c;
      }
    }
  }
  __syncthreads();
  // ---- LayerNorm(128) + ReLU ----
  {
    const float gA = g1[lane], gB = g1[lane+64];
    const float bA = be1[lane], bB = be1[lane+64];
    for (int r = wv*16; r < wv*16 + 16; ++r){
      float a = h1[r*H1STR + lane];
      float b = h1[r*H1STR + 64 + lane];
      float s = a + b, ss = fmaf(a,a,b*b);
      #pragma unroll
      for (int off=32; off; off>>=1){
        s  += __shfl_xor(s, off);
        ss += __shfl_xor(ss, off);
      }
      float mean = s * (1.0f/128.0f);
      float var  = ss * (1.0f/128.0f) - mean*mean;
      float inv = rsqrtf(var + 1e-5f);
      h1[r*H1STR + lane]      = fmaxf(fmaf((a-mean)*inv, gA, bA), 0.f);
      h1[r*H1STR + 64 + lane] = fmaxf(fmaf((b-mean)*inv, gB, bB), 0.f);
    }
  }
  __syncthreads();
  // ---- GEMM2 ----
  {
    f32x4 acc2[4];
    #pragma unroll
    for (int m=0;m<4;m++) acc2[m] = (f32x4){0.f,0.f,0.f,0.f};
    #pragma unroll
    for (int ks=0; ks<4; ks++){
      bf16x8 bfr = *(const bf16x8*)(W2T + (size_t)(wv*16 + l16)*128 + ks*32 + quad*8);
      #pragma unroll
      for (int m=0;m<4;m++){
        const float* p = h1 + (m*16 + l16)*H1STR + ks*32 + quad*8;
        bf16x8 af = cvt8(*(const float4*)p, *(const float4*)(p+4));
        acc2[m] = __builtin_amdgcn_mfma_f32_16x16x32_bf16(af, bfr, acc2[m], 0, 0, 0);
      }
    }
    float b2c = b2[wv*16 + l16];
    #pragma unroll
    for (int m=0;m<4;m++){
      #pragma unroll
      for (int r=0;r<4;r++)
        h_ws[(size_t)slot_l[m*16 + quad*4 + r]*64 + wv*16 + l16] = acc2[m][r] + b2c;
    }
  }
}

// ---------------- kernel 3: aggregate + node MLP (MFMA hi/lo) + heads + reparam ----------------
#define T2STR 132
#define ZSSTR 36
#define ZPSTR 164   // packed z stride (u32 elems), 16B-aligned rows
#define H3STR 260   // h3 stride (f32 / packed u32 elems), 16B-aligned rows
__global__ __launch_bounds__(256, 3) void k_node(const float* __restrict__ x,
    const float* __restrict__ u, const int* __restrict__ batch,
    const float* __restrict__ h_ws, const int* __restrict__ cnt,
    const int* __restrict__ offs,
    const unsigned short* __restrict__ W3Th, const unsigned short* __restrict__ W3Tl,
    const float* __restrict__ b3,
    const float* __restrict__ g3, const float* __restrict__ be3,
    const unsigned short* __restrict__ W4Th, const unsigned short* __restrict__ W4Tl,
    const float* __restrict__ b4,
    const float* __restrict__ g4, const float* __restrict__ be4,
    const float* __restrict__ Wm, const float* __restrict__ bm,
    const float* __restrict__ Wv, const float* __restrict__ bv,
    const float* __restrict__ Wx, const float* __restrict__ bx,
    float* __restrict__ out){
  // arena: [0, 32*H3STR*4) h3f: GEMM1 out fp32 -> packed h3 -> hm[32][64]
  //        rest: zPK packed z u32 -> t2 fp32 (T2STR) -> zs fp32 (ZSSTR)
  __shared__ __align__(16) char arena[(32*H3STR + 32*ZPSTR)*4];   // 54,272 B
  float*    h3f = (float*)arena;
  unsigned* h3p = (unsigned*)arena;
  unsigned* zPK = (unsigned*)(arena + 32*H3STR*4);
  float*    t2S = (float*)(arena + 32*H3STR*4);

  const int tid = threadIdx.x;
  const int base = blockIdx.x * 32;
  const int wv   = tid >> 6;
  const int lane = tid & 63;
  const int quad = lane >> 4;
  const int l16  = lane & 15;

  // ---- phase A: build packed z[32][160]  (x | agg | u) ----
  #pragma unroll
  for (int i=0;i<2;i++){
    int l = tid + 256*i;
    int r = l >> 4, c4 = (l & 15) * 4;
    int n = base + r;
    float4 v = make_float4(0.f,0.f,0.f,0.f);
    if (n < NN) v = *(const float4*)(x + (size_t)n*64 + c4);
    *(uint4*)(zPK + r*ZPSTR + c4) = pack4(v);
  }
  {
    int r = tid >> 3, c4 = (tid & 7) * 4;
    int n = base + r;
    float4 v = make_float4(0.f,0.f,0.f,0.f);
    if (n < NN) v = *(const float4*)(u + (size_t)batch[n]*32 + c4);
    *(uint4*)(zPK + r*ZPSTR + 128 + c4) = pack4(v);
  }
  {
    int r = tid >> 3, p = tid & 7;
    int n = base + r;
    float4 a0 = make_float4(0.f,0.f,0.f,0.f), a1 = a0;
    int deg = 0;
    if (n < NN){
      deg = cnt[n];
      const float* hp = h_ws + (size_t)offs[n]*64 + p*8;
      int j = 0;
      for (; j + 2 <= deg; j += 2){
        float4 v0 = *(const float4*)(hp);
        float4 v1 = *(const float4*)(hp + 4);
        float4 w0 = *(const float4*)(hp + 64);
        float4 w1 = *(const float4*)(hp + 68);
        hp += 128;
        a0.x += v0.x; a0.y += v0.y; a0.z += v0.z; a0.w += v0.w;
        a1.x += v1.x; a1.y += v1.y; a1.z += v1.z; a1.w += v1.w;
        a0.x += w0.x; a0.y += w0.y; a0.z += w0.z; a0.w += w0.w;
        a1.x += w1.x; a1.y += w1.y; a1.z += w1.z; a1.w += w1.w;
      }
      if (j < deg){
        float4 v0 = *(const float4*)(hp);
        float4 v1 = *(const float4*)(hp + 4);
        a0.x += v0.x; a0.y += v0.y; a0.z += v0.z; a0.w += v0.w;
        a1.x += v1.x; a1.y += v1.y; a1.z += v1.z; a1.w += v1.w;
      }
    }
    float rc = 1.0f / fmaxf((float)deg, 1.0f);
    a0.x*=rc; a0.y*=rc; a0.z*=rc; a0.w*=rc;
    a1.x*=rc; a1.y*=rc; a1.z*=rc; a1.w*=rc;
    *(uint4*)(zPK + r*ZPSTR + 64 + p*8)     = pack4(a0);
    *(uint4*)(zPK + r*ZPSTR + 64 + p*8 + 4) = pack4(a1);
  }
  __syncthreads();   // B0
  // ---- GEMM1 (MFMA): C[32x256] = Z[32x160] @ W3, hi/lo compensated ----
  // wave -> m-tile (wv&1), n-tiles (wv>>1)*8 .. +7  => full 2x16 tile coverage
  {
    const int mt = wv & 1;
    const int ng = wv >> 1;
    f32x4 acc[8];
    #pragma unroll
    for (int i=0;i<8;i++) acc[i] = (f32x4){0.f,0.f,0.f,0.f};
    #pragma unroll
    for (int ks=0; ks<5; ks++){
      const unsigned* ap = zPK + (mt*16 + l16)*ZPSTR + ks*32 + quad*8;
      uint4 p0 = *(const uint4*)ap;
      uint4 p1 = *(const uint4*)(ap + 4);
      bf16x8 ah, al;
      unpack8(p0, p1, ah, al);
      #pragma unroll
      for (int i=0;i<8;i++){
        int nt = ng*8 + i;
        bf16x8 bh = *(const bf16x8*)(W3Th + (size_t)(nt*16 + l16)*160 + ks*32 + quad*8);
        bf16x8 bl = *(const bf16x8*)(W3Tl + (size_t)(nt*16 + l16)*160 + ks*32 + quad*8);
        acc[i] = __builtin_amdgcn_mfma_f32_16x16x32_bf16(ah, bh, acc[i], 0, 0, 0);
        acc[i] = __builtin_amdgcn_mfma_f32_16x16x32_bf16(al, bh, acc[i], 0, 0, 0);
        acc[i] = __builtin_amdgcn_mfma_f32_16x16x32_bf16(ah, bl, acc[i], 0, 0, 0);
      }
    }
    #pragma unroll
    for (int i=0;i<8;i++){
      int nt = ng*8 + i;
      float bc = b3[nt*16 + l16];
      #pragma unroll
      for (int r=0;r<4;r++)
        h3f[(mt*16 + quad*4 + r)*H3STR + nt*16 + l16] = acc[i][r] + bc;
    }
  }
  __syncthreads();   // B1a
  // ---- LN(256)+ReLU, pack hi/lo in place (wave per row, 8 rows/wave) ----
  {
    float4 gg  = *(const float4*)(g3 + lane*4);
    float4 bet = *(const float4*)(be3 + lane*4);
    #pragma unroll
    for (int r=0;r<8;r++){
      int row = wv*8 + r;
      float4 v = *(const float4*)(h3f + row*H3STR + lane*4);
      float s  = v.x + v.y + v.z + v.w;
      float ss = fmaf(v.x,v.x, fmaf(v.y,v.y, fmaf(v.z,v.z, v.w*v.w)));
      #pragma unroll
      for (int off=32; off; off>>=1){ s += __shfl_xor(s,off); ss += __shfl_xor(ss,off); }
      float mean = s * (1.0f/256.0f);
      float inv  = rsqrtf(ss*(1.0f/256.0f) - mean*mean + 1e-5f);
      float4 o;
      o.x = fmaxf(fmaf((v.x-mean)*inv, gg.x, bet.x), 0.f);
      o.y = fmaxf(fmaf((v.y-mean)*inv, gg.y, bet.y), 0.f);
      o.z = fmaxf(fmaf((v.z-mean)*inv, gg.z, bet.z), 0.f);
      o.w = fmaxf(fmaf((v.w-mean)*inv, gg.w, bet.w), 0.f);
      *(uint4*)(h3p + row*H3STR + lane*4) = pack4(o);
    }
  }
  __syncthreads();   // B1b
  // ---- GEMM2 (MFMA): C2[32x128] = H3[32x256] @ W4, hi/lo compensated ----
  // wave -> m-tile (wv&1), n-tiles (wv>>1)*4 .. +3  => full 2x8 tile coverage
  {
    const int mt = wv & 1;
    const int np = wv >> 1;
    f32x4 acc[4];
    #pragma unroll
    for (int i=0;i<4;i++) acc[i] = (f32x4){0.f,0.f,0.f,0.f};
    #pragma unroll
    for (int ks=0; ks<8; ks++){
      const unsigned* ap = h3p + (mt*16 + l16)*H3STR + ks*32 + quad*8;
      uint4 p0 = *(const uint4*)ap;
      uint4 p1 = *(const uint4*)(ap + 4);
      bf16x8 ah, al;
      unpack8(p0, p1, ah, al);
      #pragma unroll
      for (int i=0;i<4;i++){
        int nt = np*4 + i;
        bf16x8 bh = *(const bf16x8*)(W4Th + (size_t)(nt*16 + l16)*256 + ks*32 + quad*8);
        bf16x8 bl = *(const bf16x8*)(W4Tl + (size_t)(nt*16 + l16)*256 + ks*32 + quad*8);
        acc[i] = __builtin_amdgcn_mfma_f32_16x16x32_bf16(ah, bh, acc[i], 0, 0, 0);
        acc[i] = __builtin_amdgcn_mfma_f32_16x16x32_bf16(al, bh, acc[i], 0, 0, 0);
        acc[i] = __builtin_amdgcn_mfma_f32_16x16x32_bf16(ah, bl, acc[i], 0, 0, 0);
      }
    }
    #pragma unroll
    for (int i=0;i<4;i++){
      int nt = np*4 + i;
      float bc = b4[nt*16 + l16];
      #pragma unroll
      for (int r=0;r<4;r++)
        t2S[(mt*16 + quad*4 + r)*T2STR + nt*16 + l16] = acc[i][r] + bc;
    }
  }
  __syncthreads();   // B2a
  // ---- LN(128)+ReLU in place (fp32, heads read fp32) ----
  {
    const int jq = tid & 31, rb = tid >> 5;
    float4 gg  = *(const float4*)(g4 + 4*jq);
    float4 bet = *(const float4*)(be4 + 4*jq);
    #pragma unroll
    for (int r=0;r<4;r++){
      int row = rb*4 + r;
      float4 v = *(const float4*)(t2S + row*T2STR + 4*jq);
      float s  = v.x + v.y + v.z + v.w;
      float ss = fmaf(v.x,v.x, fmaf(v.y,v.y, fmaf(v.z,v.z, v.w*v.w)));
      #pragma unroll
      for (int off=16; off; off>>=1){ s += __shfl_xor(s,off); ss += __shfl_xor(ss,off); }
      float mean = s * (1.0f/128.0f);
      float inv  = rsqrtf(ss*(1.0f/128.0f) - mean*mean + 1e-5f);
      float4 o;
      o.x = fmaxf(fmaf((v.x-mean)*inv, gg.x, bet.x), 0.f);
      o.y = fmaxf(fmaf((v.y-mean)*inv, gg.y, bet.y), 0.f);
      o.z = fmaxf(fmaf((v.z-mean)*inv, gg.z, bet.z), 0.f);
      o.w = fmaxf(fmaf((v.w-mean)*inv, gg.w, bet.w), 0.f);
      *(float4*)(t2S + row*T2STR + 4*jq) = o;
    }
  }
  __syncthreads();   // B2
  // ---- heads: mu | lv  (fp32 VALU) ----
  {
    const int jq = tid & 15, rb = tid >> 4;
    const float* Wp = (jq < 8) ? Wm : Wv;
    const int cq = (jq & 7) * 4;
    float4 acc[2];
    #pragma unroll
    for (int r=0;r<2;r++) acc[r] = make_float4(0.f,0.f,0.f,0.f);
    for (int k=0;k<128;k+=4){
      float4 w0 = *(const float4*)(Wp + (k+0)*32 + cq);
      float4 w1 = *(const float4*)(Wp + (k+1)*32 + cq);
      float4 w2 = *(const float4*)(Wp + (k+2)*32 + cq);
      float4 w3 = *(const float4*)(Wp + (k+3)*32 + cq);
      #pragma unroll
      for (int r=0;r<2;r++){
        float4 z = *(const float4*)(t2S + (rb*2+r)*T2STR + k);
        fma4(acc[r], z.x, w0); fma4(acc[r], z.y, w1);
        fma4(acc[r], z.z, w2); fma4(acc[r], z.w, w3);
      }
    }
    const float* bp = (jq < 8) ? bm : bv;
    float4 bb = *(const float4*)(bp + cq);
    const long long sec = (jq < 8) ? (long long)NN*64 : ((long long)NN*64 + (long long)NN*32);
    #pragma unroll
    for (int r=0;r<2;r++){
      float4 v = acc[r];
      v.x += bb.x; v.y += bb.y; v.z += bb.z; v.w += bb.w;
      int rr = rb*2 + r;
      *(float4*)(h3f + rr*64 + ((jq<8)?0:32) + cq) = v;
      int n = base + rr;
      if (n < NN) *(float4*)(out + sec + (long long)n*32 + cq) = v;
    }
  }
  __syncthreads();   // B3
  // ---- reparameterize ----
  #pragma unroll
  for (int i=0;i<4;i++){
    int l = tid + 256*i;
    int r = l >> 5, jj = l & 31;
    float mu = h3f[r*64 + jj];
    float lv = h3f[r*64 + 32 + jj];
    unsigned idx = (unsigned)((base + r)*32 + jj);
    float e = eps_at(idx);
    t2S[r*ZSSTR + jj] = fmaf(e, expf(0.5f*lv), mu);
  }
  __syncthreads();   // B4
  // ---- out = zs @ Wx + bx (fp32 VALU) ----
  {
    const int jq = tid & 15, rb = tid >> 4;
    float4 acc[2];
    #pragma unroll
    for (int r=0;r<2;r++) acc[r] = make_float4(0.f,0.f,0.f,0.f);
    for (int k=0;k<32;k+=4){
      float4 w0 = *(const float4*)(Wx + (k+0)*64 + 4*jq);
      float4 w1 = *(const float4*)(Wx + (k+1)*64 + 4*jq);
      float4 w2 = *(const float4*)(Wx + (k+2)*64 + 4*jq);
      float4 w3 = *(const float4*)(Wx + (k+3)*64 + 4*jq);
      #pragma unroll
      for (int r=0;r<2;r++){
        float4 z = *(const float4*)(t2S + (rb*2+r)*ZSSTR + k);
        fma4(acc[r], z.x, w0); fma4(acc[r], z.y, w1);
        fma4(acc[r], z.z, w2); fma4(acc[r], z.w, w3);
      }
    }
    float4 bb = *(const float4*)(bx + 4*jq);
    #pragma unroll
    for (int r=0;r<2;r++){
      int n = base + rb*2 + r;
      if (n < NN){
        float4 v = acc[r];
        v.x += bb.x; v.y += bb.y; v.z += bb.z; v.w += bb.w;
        *(float4*)(out + (long long)n*64 + 4*jq) = v;
      }
    }
  }
}

extern "C" void kernel_launch(void* const* d_in, const int* in_sizes, int n_in,
                              void* d_out, int out_size, void* d_ws, size_t ws_size,
                              hipStream_t stream) {
  const float* x     = (const float*)d_in[0];
  const int*   ei    = (const int*)d_in[1];
  const float* ea    = (const float*)d_in[2];
  const float* u     = (const float*)d_in[3];
  const int*   batch = (const int*)d_in[4];
  const float* W1 = (const float*)d_in[6];
  const float* b1 = (const float*)d_in[7];
  const float* g1 = (const float*)d_in[8];
  const float* be1= (const float*)d_in[9];
  const float* W2 = (const float*)d_in[10];
  const float* b2 = (const float*)d_in[11];
  const float* W3 = (const float*)d_in[12];
  const float* b3 = (const float*)d_in[13];
  const float* g3 = (const float*)d_in[14];
  const float* be3= (const float*)d_in[15];
  const float* W4 = (const float*)d_in[16];
  const float* b4 = (const float*)d_in[17];
  const float* g4 = (const float*)d_in[18];
  const float* be4= (const float*)d_in[19];
  const float* Wm = (const float*)d_in[20];
  const float* bm = (const float*)d_in[21];
  const float* Wv = (const float*)d_in[22];
  const float* bv = (const float*)d_in[23];
  const float* Wx = (const float*)d_in[24];
  const float* bx = (const float*)d_in[25];

  char* W = (char*)d_ws;
  size_t off = 0;
  float* h_ws = (float*)(W + off);  off += (size_t)EE*64*4;     // 102.4 MB
  int* cnt      = (int*)(W + off);  off += (size_t)NN*4;
  int* offs     = (int*)(W + off);  off += (size_t)NN*4;
  int* cursor   = (int*)(W + off);  off += (size_t)NN*4;
  int* epos     = (int*)(W + off);  off += (size_t)EE*4;
  int* partials = (int*)(W + off);  off += 256;
  unsigned short* xb  = (unsigned short*)(W + off); off += (size_t)NN*64*2;  // 6.4 MB
  unsigned short* W1T = (unsigned short*)(W + off); off += 128*128*2;
  unsigned short* W2T = (unsigned short*)(W + off); off += 64*128*2;
  unsigned short* W3Th = (unsigned short*)(W + off); off += 256*160*2;
  unsigned short* W3Tl = (unsigned short*)(W + off); off += 256*160*2;
  unsigned short* W4Th = (unsigned short*)(W + off); off += 128*256*2;
  unsigned short* W4Tl = (unsigned short*)(W + off); off += 128*256*2;
  float* out = (float*)d_out;

  hipMemsetAsync(cnt, 0, (size_t)NN*sizeof(int), stream);

  k_prep_x<<<(NN*64/8 + 255)/256, 256, 0, stream>>>(x, xb);
  k_prep_w<<<1, 256, 0, stream>>>(W1, W2, W1T, W2T);
  k_prep_w34<<<384, 256, 0, stream>>>(W3, W4, W3Th, W3Tl, W4Th, W4Tl);
  k_hist <<<(EE+255)/256, 256, 0, stream>>>(ei, cnt);
  k_scan1<<<NB, 256, 0, stream>>>(cnt, offs, partials);
  k_scan2<<<1, 64, 0, stream>>>(partials);
  k_scan3<<<NB, 256, 0, stream>>>(offs, partials, cursor);
  k_fill <<<(EE+255)/256, 256, 0, stream>>>(ei, cursor, epos);

  k_edge<<<EE/64, 256, 0, stream>>>(ei, ea, xb, W1T, b1, g1, be1, W2T, b2, epos, h_ws);
  k_node<<<(NN+31)/32, 256, 0, stream>>>(x, u, batch, h_ws, cnt, offs,
                                         W3Th, W3Tl, b3, g3, be3,
                                         W4Th, W4Tl, b4, g4, be4,
                                         Wm,bm, Wv,bv, Wx,bx, out);
}

// Round 4
// 560.806 us; speedup vs baseline: 1.0445x; 1.0205x over previous
//
#include <hip/hip_runtime.h>

#define NN 50000
#define EE 400000
#define NB 49   // ceil(NN/1024) scan blocks

typedef __attribute__((ext_vector_type(8))) short bf16x8;
typedef __attribute__((ext_vector_type(4))) float f32x4;

__device__ __forceinline__ void fma4(float4& a, float s, const float4& w){
  a.x = fmaf(s, w.x, a.x);
  a.y = fmaf(s, w.y, a.y);
  a.z = fmaf(s, w.z, a.z);
  a.w = fmaf(s, w.w, a.w);
}

__device__ __forceinline__ unsigned short f2bf(float f){
  unsigned u = __float_as_uint(f);
  unsigned r = (u + 0x7fffu + ((u >> 16) & 1u)) >> 16;   // RNE
  return (unsigned short)r;
}

__device__ __forceinline__ bf16x8 cvt8(float4 lo, float4 hi){
  bf16x8 r;
  r[0]=(short)f2bf(lo.x); r[1]=(short)f2bf(lo.y); r[2]=(short)f2bf(lo.z); r[3]=(short)f2bf(lo.w);
  r[4]=(short)f2bf(hi.x); r[5]=(short)f2bf(hi.y); r[6]=(short)f2bf(hi.z); r[7]=(short)f2bf(hi.w);
  return r;
}

// pack fp32 -> (bf16_hi << 16) | bf16_lo, where hi+lo ~= v to ~16 mantissa bits
__device__ __forceinline__ unsigned packhl(float v){
  unsigned hi = f2bf(v);
  float fh = __uint_as_float(hi << 16);
  unsigned lo = f2bf(v - fh);
  return (hi << 16) | lo;
}

__device__ __forceinline__ uint4 pack4(float4 v){
  uint4 p;
  p.x = packhl(v.x); p.y = packhl(v.y); p.z = packhl(v.z); p.w = packhl(v.w);
  return p;
}

__device__ __forceinline__ void unpack8(uint4 p0, uint4 p1, bf16x8& hi, bf16x8& lo){
  hi[0]=(short)(p0.x>>16); lo[0]=(short)(p0.x & 0xffffu);
  hi[1]=(short)(p0.y>>16); lo[1]=(short)(p0.y & 0xffffu);
  hi[2]=(short)(p0.z>>16); lo[2]=(short)(p0.z & 0xffffu);
  hi[3]=(short)(p0.w>>16); lo[3]=(short)(p0.w & 0xffffu);
  hi[4]=(short)(p1.x>>16); lo[4]=(short)(p1.x & 0xffffu);
  hi[5]=(short)(p1.y>>16); lo[5]=(short)(p1.y & 0xffffu);
  hi[6]=(short)(p1.z>>16); lo[6]=(short)(p1.z & 0xffffu);
  hi[7]=(short)(p1.w>>16); lo[7]=(short)(p1.w & 0xffffu);
}

// bf16-pair helpers for reading h_ws (bf16) as fp32
__device__ __forceinline__ float blo(unsigned u){ return __uint_as_float(u << 16); }
__device__ __forceinline__ float bhi(unsigned u){ return __uint_as_float(u & 0xffff0000u); }

__device__ __forceinline__ unsigned rotl32(unsigned v, int d){ return (v<<d)|(v>>(32-d)); }

// jax.random.normal(key(42)) under jax_threefry_partitionable: counter (0,idx), bits=x0^x1. Verified R3.
__device__ __forceinline__ float eps_at(unsigned idx){
  const unsigned k0 = 0u, k1 = 42u, k2 = 0x1BD11BDAu ^ 0u ^ 42u;
  unsigned x0 = 0u + k0, x1 = idx + k1;
  const int rotA[4] = {13,15,26,6};
  const int rotB[4] = {17,29,16,24};
  #pragma unroll
  for (int i=0;i<4;i++){ x0 += x1; x1 = rotl32(x1, rotA[i]); x1 ^= x0; }
  x0 += k1; x1 += k2 + 1u;
  #pragma unroll
  for (int i=0;i<4;i++){ x0 += x1; x1 = rotl32(x1, rotB[i]); x1 ^= x0; }
  x0 += k2; x1 += k0 + 2u;
  #pragma unroll
  for (int i=0;i<4;i++){ x0 += x1; x1 = rotl32(x1, rotA[i]); x1 ^= x0; }
  x0 += k0; x1 += k1 + 3u;
  #pragma unroll
  for (int i=0;i<4;i++){ x0 += x1; x1 = rotl32(x1, rotB[i]); x1 ^= x0; }
  x0 += k1; x1 += k2 + 4u;
  #pragma unroll
  for (int i=0;i<4;i++){ x0 += x1; x1 = rotl32(x1, rotA[i]); x1 ^= x0; }
  x0 += k2; x1 += k0 + 5u;
  unsigned bits = x0 ^ x1;
  float f = __uint_as_float((bits >> 9) | 0x3f800000u) - 1.0f;
  const float lo = -0.99999994f;
  float u = f * 2.0f + lo;
  u = fmaxf(u, lo);
  float w = -log1pf(-u*u);
  float p;
  if (w < 5.0f){
    w -= 2.5f;
    p = 2.81022636e-08f;
    p = fmaf(p,w, 3.43273939e-07f);
    p = fmaf(p,w,-3.5233877e-06f);
    p = fmaf(p,w,-4.39150654e-06f);
    p = fmaf(p,w, 0.00021858087f);
    p = fmaf(p,w,-0.00125372503f);
    p = fmaf(p,w,-0.00417768164f);
    p = fmaf(p,w, 0.246640727f);
    p = fmaf(p,w, 1.50140941f);
  } else {
    w = sqrtf(w) - 3.0f;
    p = -0.000200214257f;
    p = fmaf(p,w, 0.000100950558f);
    p = fmaf(p,w, 0.00134934322f);
    p = fmaf(p,w,-0.00367342844f);
    p = fmaf(p,w, 0.00573950773f);
    p = fmaf(p,w,-0.0076224613f);
    p = fmaf(p,w, 0.00943887047f);
    p = fmaf(p,w, 1.00167406f);
    p = fmaf(p,w, 2.83297682f);
  }
  return 1.41421356237f * (p * u);
}

// ================= prep: bf16 conversions =================
__global__ __launch_bounds__(256) void k_prep_x(const float* __restrict__ x,
                                                unsigned short* __restrict__ xb){
  int t = blockIdx.x*256 + threadIdx.x;           // one bf16x8 per thread
  if (t < NN*64/8){
    const float4* p = (const float4*)(x + t*8);
    bf16x8 v = cvt8(p[0], p[1]);
    *(bf16x8*)(xb + t*8) = v;
  }
}

// W1T[n][k] = W1[k][n] (128x128), W2T[n][k] = W2[k][n] (64x128), bf16
__global__ __launch_bounds__(256) void k_prep_w(const float* __restrict__ W1,
                                                const float* __restrict__ W2,
                                                unsigned short* __restrict__ W1T,
                                                unsigned short* __restrict__ W2T){
  for (int i = threadIdx.x; i < 128*128; i += 256){
    int n = i >> 7, k = i & 127;
    W1T[i] = f2bf(W1[k*128 + n]);
  }
  for (int i = threadIdx.x; i < 64*128; i += 256){
    int n = i >> 7, k = i & 127;
    W2T[i] = f2bf(W2[k*64 + n]);
  }
}

// W3T hi/lo [256][160] from W3[160][256]; W4T hi/lo [128][256] from W4[256][128]
__global__ __launch_bounds__(256) void k_prep_w34(const float* __restrict__ W3,
                                                  const float* __restrict__ W4,
                                                  unsigned short* __restrict__ W3Th,
                                                  unsigned short* __restrict__ W3Tl,
                                                  unsigned short* __restrict__ W4Th,
                                                  unsigned short* __restrict__ W4Tl){
  int b = blockIdx.x;
  if (b < 256){
    int n = b;
    for (int k = threadIdx.x; k < 160; k += 256){
      float w = W3[k*256 + n];
      unsigned h = f2bf(w);
      float fh = __uint_as_float(h << 16);
      W3Th[n*160 + k] = (unsigned short)h;
      W3Tl[n*160 + k] = f2bf(w - fh);
    }
  } else {
    int n = b - 256;            // < 128
    int k = threadIdx.x;        // 256 threads, K=256
    float w = W4[k*128 + n];
    unsigned h = f2bf(w);
    float fh = __uint_as_float(h << 16);
    W4Th[n*256 + k] = (unsigned short)h;
    W4Tl[n*256 + k] = f2bf(w - fh);
  }
}

// ================= CSR construction =================
__global__ __launch_bounds__(256) void k_hist(const int* __restrict__ ei, int* __restrict__ cnt){
  int e = blockIdx.x*256 + threadIdx.x;
  if (e < EE) atomicAdd(&cnt[ei[EE + e]], 1);
}

__global__ __launch_bounds__(256) void k_scan1(const int* __restrict__ cnt,
                                               int* __restrict__ offs,
                                               int* __restrict__ partials){
  __shared__ int sdata[256];
  const int t = threadIdx.x, b = blockIdx.x;
  const int base = b*1024 + t*4;
  int v0 = (base+0 < NN) ? cnt[base+0] : 0;
  int v1 = (base+1 < NN) ? cnt[base+1] : 0;
  int v2 = (base+2 < NN) ? cnt[base+2] : 0;
  int v3 = (base+3 < NN) ? cnt[base+3] : 0;
  int tsum = v0+v1+v2+v3;
  sdata[t] = tsum;
  __syncthreads();
  for (int off=1; off<256; off<<=1){
    int add = (t >= off) ? sdata[t-off] : 0;
    __syncthreads();
    sdata[t] += add;
    __syncthreads();
  }
  int run = sdata[t] - tsum;
  if (base+0 < NN) offs[base+0] = run;  run += v0;
  if (base+1 < NN) offs[base+1] = run;  run += v1;
  if (base+2 < NN) offs[base+2] = run;  run += v2;
  if (base+3 < NN) offs[base+3] = run;
  if (t == 255) partials[b] = sdata[255];
}

__global__ __launch_bounds__(64) void k_scan2(int* __restrict__ partials){
  int l = threadIdx.x;
  int v = (l < NB) ? partials[l] : 0;
  int inc = v;
  #pragma unroll
  for (int off=1; off<64; off<<=1){
    int t = __shfl_up(inc, off);
    if (l >= off) inc += t;
  }
  if (l < NB) partials[l] = inc - v;
}

__global__ __launch_bounds__(256) void k_scan3(int* __restrict__ offs,
                                               const int* __restrict__ partials,
                                               int* __restrict__ cursor){
  const int t = threadIdx.x, b = blockIdx.x;
  const int base = b*1024 + t*4;
  int add = partials[b];
  #pragma unroll
  for (int k=0;k<4;k++){
    int i = base + k;
    if (i < NN){ int o = offs[i] + add; offs[i] = o; cursor[i] = o; }
  }
}

// inverse permutation: epos[e] = CSR slot of edge e  (coalesced write)
__global__ __launch_bounds__(256) void k_fill(const int* __restrict__ ei,
                                              int* __restrict__ cursor,
                                              int* __restrict__ epos){
  int e = blockIdx.x*256 + threadIdx.x;
  if (e < EE){
    int c = ei[EE + e];
    epos[e] = atomicAdd(&cursor[c], 1);
  }
}

// ---------------- kernel 2: edge MLP via MFMA -> h_ws (bf16, CSR-ordered) ----------------
#define H1STR 132
__global__ __launch_bounds__(256, 4) void k_edge(const int* __restrict__ ei,
    const float* __restrict__ ea,
    const unsigned short* __restrict__ xb,
    const unsigned short* __restrict__ W1T, const float* __restrict__ b1,
    const float* __restrict__ g1, const float* __restrict__ be1,
    const unsigned short* __restrict__ W2T, const float* __restrict__ b2,
    const int* __restrict__ epos,
    unsigned short* __restrict__ h_ws){
  __shared__ __align__(16) float h1[64*H1STR];   // 33,792 B
  __shared__ int rows_l[64];
  __shared__ int slot_l[64];
  const int tid  = threadIdx.x;
  const int base = blockIdx.x * 64;
  const int wv   = tid >> 6;        // wave 0..3
  const int lane = tid & 63;
  const int quad = lane >> 4;       // 0..3
  const int l16  = lane & 15;
  if (tid < 64) rows_l[tid] = ei[base + tid];
  if (tid >= 128 && tid < 192) slot_l[tid-128] = epos[base + tid - 128];
  __syncthreads();
  // ---- GEMM1: wave wv owns n-groups {2wv, 2wv+1}, all 4 m-groups ----
  {
    int rw[4];
    #pragma unroll
    for (int m=0;m<4;m++) rw[m] = rows_l[m*16 + l16];
    f32x4 acc[4][2];
    #pragma unroll
    for (int m=0;m<4;m++){ acc[m][0] = (f32x4){0.f,0.f,0.f,0.f}; acc[m][1] = (f32x4){0.f,0.f,0.f,0.f}; }
    #pragma unroll
    for (int ks=0; ks<4; ks++){
      bf16x8 af[4];
      if (ks < 2){
        #pragma unroll
        for (int m=0;m<4;m++)
          af[m] = *(const bf16x8*)(xb + (size_t)rw[m]*64 + ks*32 + quad*8);
      } else {
        #pragma unroll
        for (int m=0;m<4;m++){
          const float* p = ea + (size_t)(base + m*16 + l16)*64 + (ks-2)*32 + quad*8;
          af[m] = cvt8(*(const float4*)p, *(const float4*)(p+4));
        }
      }
      bf16x8 bf0 = *(const bf16x8*)(W1T + (size_t)((2*wv+0)*16 + l16)*128 + ks*32 + quad*8);
      bf16x8 bf1 = *(const bf16x8*)(W1T + (size_t)((2*wv+1)*16 + l16)*128 + ks*32 + quad*8);
      #pragma unroll
      for (int m=0;m<4;m++){
        acc[m][0] = __builtin_amdgcn_mfma_f32_16x16x32_bf16(af[m], bf0, acc[m][0], 0, 0, 0);
        acc[m][1] = __builtin_amdgcn_mfma_f32_16x16x32_bf16(af[m], bf1, acc[m][1], 0, 0, 0);
      }
    }
    #pragma unroll
    for (int nl=0; nl<2; nl++){
      float b1c = b1[(2*wv+nl)*16 + l16];
      #pragma unroll
      for (int m=0;m<4;m++){
        #pragma unroll
        for (int r=0;r<4;r++)
          h1[(m*16 + quad*4 + r)*H1STR + (2*wv+nl)*16 + l16] = acc[m][nl][r] + b1c;
      }
    }
  }
  __syncthreads();
  // ---- LayerNorm(128) + ReLU ----
  {
    const float gA = g1[lane], gB = g1[lane+64];
    const float bA = be1[lane], bB = be1[lane+64];
    for (int r = wv*16; r < wv*16 + 16; ++r){
      float a = h1[r*H1STR + lane];
      float b = h1[r*H1STR + 64 + lane];
      float s = a + b, ss = fmaf(a,a,b*b);
      #pragma unroll
      for (int off=32; off; off>>=1){
        s  += __shfl_xor(s, off);
        ss += __shfl_xor(ss, off);
      }
      float mean = s * (1.0f/128.0f);
      float var  = ss * (1.0f/128.0f) - mean*mean;
      float inv = rsqrtf(var + 1e-5f);
      h1[r*H1STR + lane]      = fmaxf(fmaf((a-mean)*inv, gA, bA), 0.f);
      h1[r*H1STR + 64 + lane] = fmaxf(fmaf((b-mean)*inv, gB, bB), 0.f);
    }
  }
  __syncthreads();
  // ---- GEMM2 ----
  {
    f32x4 acc2[4];
    #pragma unroll
    for (int m=0;m<4;m++) acc2[m] = (f32x4){0.f,0.f,0.f,0.f};
    #pragma unroll
    for (int ks=0; ks<4; ks++){
      bf16x8 bfr = *(const bf16x8*)(W2T + (size_t)(wv*16 + l16)*128 + ks*32 + quad*8);
      #pragma unroll
      for (int m=0;m<4;m++){
        const float* p = h1 + (m*16 + l16)*H1STR + ks*32 + quad*8;
        bf16x8 af = cvt8(*(const float4*)p, *(const float4*)(p+4));
        acc2[m] = __builtin_amdgcn_mfma_f32_16x16x32_bf16(af, bfr, acc2[m], 0, 0, 0);
      }
    }
    float b2c = b2[wv*16 + l16];
    #pragma unroll
    for (int m=0;m<4;m++){
      #pragma unroll
      for (int r=0;r<4;r++)
        h_ws[(size_t)slot_l[m*16 + quad*4 + r]*64 + wv*16 + l16] = f2bf(acc2[m][r] + b2c);
    }
  }
}

// ---------------- kernel 2.5: streaming aggregation -> packed z (global) ----------------
// 8 threads per node. No LDS, no barriers: pure BW kernel, fully resident.
__global__ __launch_bounds__(256, 8) void k_agg(const float* __restrict__ x,
    const float* __restrict__ u, const int* __restrict__ batch,
    const unsigned short* __restrict__ h_ws, const int* __restrict__ cnt,
    const int* __restrict__ offs, unsigned* __restrict__ zg){
  int t = blockIdx.x*256 + threadIdx.x;
  int n = t >> 3, p = t & 7;
  if (n >= NN) return;
  unsigned* zr = zg + (size_t)n*160;
  // x: cols p*8 .. p*8+7
  {
    const float4* xp = (const float4*)(x + (size_t)n*64 + p*8);
    *(uint4*)(zr + p*8)     = pack4(xp[0]);
    *(uint4*)(zr + p*8 + 4) = pack4(xp[1]);
  }
  // u: cols 128 + p*4 .. +3
  {
    const float4* up = (const float4*)(u + (size_t)batch[n]*32 + p*4);
    *(uint4*)(zr + 128 + p*4) = pack4(up[0]);
  }
  // aggregation over CSR-contiguous bf16 rows
  float a0=0.f,a1=0.f,a2=0.f,a3=0.f,a4=0.f,a5=0.f,a6=0.f,a7=0.f;
  int deg = cnt[n];
  const unsigned short* hp = h_ws + (size_t)offs[n]*64 + p*8;
  int j = 0;
  for (; j + 4 <= deg; j += 4){
    uint4 v0 = *(const uint4*)(hp);
    uint4 v1 = *(const uint4*)(hp + 64);
    uint4 v2 = *(const uint4*)(hp + 128);
    uint4 v3 = *(const uint4*)(hp + 192);
    hp += 256;
    a0 += blo(v0.x); a1 += bhi(v0.x); a2 += blo(v0.y); a3 += bhi(v0.y);
    a4 += blo(v0.z); a5 += bhi(v0.z); a6 += blo(v0.w); a7 += bhi(v0.w);
    a0 += blo(v1.x); a1 += bhi(v1.x); a2 += blo(v1.y); a3 += bhi(v1.y);
    a4 += blo(v1.z); a5 += bhi(v1.z); a6 += blo(v1.w); a7 += bhi(v1.w);
    a0 += blo(v2.x); a1 += bhi(v2.x); a2 += blo(v2.y); a3 += bhi(v2.y);
    a4 += blo(v2.z); a5 += bhi(v2.z); a6 += blo(v2.w); a7 += bhi(v2.w);
    a0 += blo(v3.x); a1 += bhi(v3.x); a2 += blo(v3.y); a3 += bhi(v3.y);
    a4 += blo(v3.z); a5 += bhi(v3.z); a6 += blo(v3.w); a7 += bhi(v3.w);
  }
  for (; j < deg; ++j){
    uint4 v = *(const uint4*)(hp);
    hp += 64;
    a0 += blo(v.x); a1 += bhi(v.x); a2 += blo(v.y); a3 += bhi(v.y);
    a4 += blo(v.z); a5 += bhi(v.z); a6 += blo(v.w); a7 += bhi(v.w);
  }
  float rc = 1.0f / fmaxf((float)deg, 1.0f);
  *(uint4*)(zr + 64 + p*8)     = pack4(make_float4(a0*rc, a1*rc, a2*rc, a3*rc));
  *(uint4*)(zr + 64 + p*8 + 4) = pack4(make_float4(a4*rc, a5*rc, a6*rc, a7*rc));
}

// ---------------- kernel 3: node MLP (MFMA hi/lo) + heads + reparam ----------------
#define T2STR 132
#define ZSSTR 36
#define H3STR 260   // h3 stride (f32 / packed u32 elems), 16B-aligned rows
__global__ __launch_bounds__(256, 3) void k_node(const unsigned* __restrict__ zg,
    const unsigned short* __restrict__ W3Th, const unsigned short* __restrict__ W3Tl,
    const float* __restrict__ b3,
    const float* __restrict__ g3, const float* __restrict__ be3,
    const unsigned short* __restrict__ W4Th, const unsigned short* __restrict__ W4Tl,
    const float* __restrict__ b4,
    const float* __restrict__ g4, const float* __restrict__ be4,
    const float* __restrict__ Wm, const float* __restrict__ bm,
    const float* __restrict__ Wv, const float* __restrict__ bv,
    const float* __restrict__ Wx, const float* __restrict__ bx,
    float* __restrict__ out){
  // arena: [0, 32*H3STR*4) h3f: GEMM1 out fp32 -> packed h3 -> hm[32][64]
  //        rest: t2 fp32 (T2STR) -> zs fp32 (ZSSTR)
  __shared__ __align__(16) char arena[(32*H3STR + 32*T2STR)*4];   // 50,176 B
  float*    h3f = (float*)arena;
  unsigned* h3p = (unsigned*)arena;
  float*    t2S = (float*)(arena + 32*H3STR*4);

  const int tid = threadIdx.x;
  const int base = blockIdx.x * 32;
  const int wv   = tid >> 6;
  const int lane = tid & 63;
  const int quad = lane >> 4;
  const int l16  = lane & 15;

  // ---- GEMM1 (MFMA): C[32x256] = Z[32x160] @ W3, hi/lo compensated; A from global zg ----
  // wave -> m-tile (wv&1), n-tiles (wv>>1)*8 .. +7  => full 2x16 tile coverage
  {
    const int mt = wv & 1;
    const int ng = wv >> 1;
    const unsigned* az = zg + (size_t)(base + mt*16 + l16)*160 + quad*8;
    f32x4 acc[8];
    #pragma unroll
    for (int i=0;i<8;i++) acc[i] = (f32x4){0.f,0.f,0.f,0.f};
    #pragma unroll
    for (int ks=0; ks<5; ks++){
      uint4 p0 = *(const uint4*)(az + ks*32);
      uint4 p1 = *(const uint4*)(az + ks*32 + 4);
      bf16x8 ah, al;
      unpack8(p0, p1, ah, al);
      #pragma unroll
      for (int i=0;i<8;i++){
        int nt = ng*8 + i;
        bf16x8 bh = *(const bf16x8*)(W3Th + (size_t)(nt*16 + l16)*160 + ks*32 + quad*8);
        bf16x8 bl = *(const bf16x8*)(W3Tl + (size_t)(nt*16 + l16)*160 + ks*32 + quad*8);
        acc[i] = __builtin_amdgcn_mfma_f32_16x16x32_bf16(ah, bh, acc[i], 0, 0, 0);
        acc[i] = __builtin_amdgcn_mfma_f32_16x16x32_bf16(al, bh, acc[i], 0, 0, 0);
        acc[i] = __builtin_amdgcn_mfma_f32_16x16x32_bf16(ah, bl, acc[i], 0, 0, 0);
      }
    }
    #pragma unroll
    for (int i=0;i<8;i++){
      int nt = ng*8 + i;
      float bc = b3[nt*16 + l16];
      #pragma unroll
      for (int r=0;r<4;r++)
        h3f[(mt*16 + quad*4 + r)*H3STR + nt*16 + l16] = acc[i][r] + bc;
    }
  }
  __syncthreads();   // B1a
  // ---- LN(256)+ReLU, pack hi/lo in place (wave per row, 8 rows/wave) ----
  {
    float4 gg  = *(const float4*)(g3 + lane*4);
    float4 bet = *(const float4*)(be3 + lane*4);
    #pragma unroll
    for (int r=0;r<8;r++){
      int row = wv*8 + r;
      float4 v = *(const float4*)(h3f + row*H3STR + lane*4);
      float s  = v.x + v.y + v.z + v.w;
      float ss = fmaf(v.x,v.x, fmaf(v.y,v.y, fmaf(v.z,v.z, v.w*v.w)));
      #pragma unroll
      for (int off=32; off; off>>=1){ s += __shfl_xor(s,off); ss += __shfl_xor(ss,off); }
      float mean = s * (1.0f/256.0f);
      float inv  = rsqrtf(ss*(1.0f/256.0f) - mean*mean + 1e-5f);
      float4 o;
      o.x = fmaxf(fmaf((v.x-mean)*inv, gg.x, bet.x), 0.f);
      o.y = fmaxf(fmaf((v.y-mean)*inv, gg.y, bet.y), 0.f);
      o.z = fmaxf(fmaf((v.z-mean)*inv, gg.z, bet.z), 0.f);
      o.w = fmaxf(fmaf((v.w-mean)*inv, gg.w, bet.w), 0.f);
      *(uint4*)(h3p + row*H3STR + lane*4) = pack4(o);
    }
  }
  __syncthreads();   // B1b
  // ---- GEMM2 (MFMA): C2[32x128] = H3[32x256] @ W4, hi/lo compensated ----
  // wave -> m-tile (wv&1), n-tiles (wv>>1)*4 .. +3  => full 2x8 tile coverage
  {
    const int mt = wv & 1;
    const int np = wv >> 1;
    f32x4 acc[4];
    #pragma unroll
    for (int i=0;i<4;i++) acc[i] = (f32x4){0.f,0.f,0.f,0.f};
    #pragma unroll
    for (int ks=0; ks<8; ks++){
      const unsigned* ap = h3p + (mt*16 + l16)*H3STR + ks*32 + quad*8;
      uint4 p0 = *(const uint4*)ap;
      uint4 p1 = *(const uint4*)(ap + 4);
      bf16x8 ah, al;
      unpack8(p0, p1, ah, al);
      #pragma unroll
      for (int i=0;i<4;i++){
        int nt = np*4 + i;
        bf16x8 bh = *(const bf16x8*)(W4Th + (size_t)(nt*16 + l16)*256 + ks*32 + quad*8);
        bf16x8 bl = *(const bf16x8*)(W4Tl + (size_t)(nt*16 + l16)*256 + ks*32 + quad*8);
        acc[i] = __builtin_amdgcn_mfma_f32_16x16x32_bf16(ah, bh, acc[i], 0, 0, 0);
        acc[i] = __builtin_amdgcn_mfma_f32_16x16x32_bf16(al, bh, acc[i], 0, 0, 0);
        acc[i] = __builtin_amdgcn_mfma_f32_16x16x32_bf16(ah, bl, acc[i], 0, 0, 0);
      }
    }
    #pragma unroll
    for (int i=0;i<4;i++){
      int nt = np*4 + i;
      float bc = b4[nt*16 + l16];
      #pragma unroll
      for (int r=0;r<4;r++)
        t2S[(mt*16 + quad*4 + r)*T2STR + nt*16 + l16] = acc[i][r] + bc;
    }
  }
  __syncthreads();   // B2a
  // ---- LN(128)+ReLU in place (fp32, heads read fp32) ----
  {
    const int jq = tid & 31, rb = tid >> 5;
    float4 gg  = *(const float4*)(g4 + 4*jq);
    float4 bet = *(const float4*)(be4 + 4*jq);
    #pragma unroll
    for (int r=0;r<4;r++){
      int row = rb*4 + r;
      float4 v = *(const float4*)(t2S + row*T2STR + 4*jq);
      float s  = v.x + v.y + v.z + v.w;
      float ss = fmaf(v.x,v.x, fmaf(v.y,v.y, fmaf(v.z,v.z, v.w*v.w)));
      #pragma unroll
      for (int off=16; off; off>>=1){ s += __shfl_xor(s,off); ss += __shfl_xor(ss,off); }
      float mean = s * (1.0f/128.0f);
      float inv  = rsqrtf(ss*(1.0f/128.0f) - mean*mean + 1e-5f);
      float4 o;
      o.x = fmaxf(fmaf((v.x-mean)*inv, gg.x, bet.x), 0.f);
      o.y = fmaxf(fmaf((v.y-mean)*inv, gg.y, bet.y), 0.f);
      o.z = fmaxf(fmaf((v.z-mean)*inv, gg.z, bet.z), 0.f);
      o.w = fmaxf(fmaf((v.w-mean)*inv, gg.w, bet.w), 0.f);
      *(float4*)(t2S + row*T2STR + 4*jq) = o;
    }
  }
  __syncthreads();   // B2
  // ---- heads: mu | lv  (fp32 VALU) ----
  {
    const int jq = tid & 15, rb = tid >> 4;
    const float* Wp = (jq < 8) ? Wm : Wv;
    const int cq = (jq & 7) * 4;
    float4 acc[2];
    #pragma unroll
    for (int r=0;r<2;r++) acc[r] = make_float4(0.f,0.f,0.f,0.f);
    for (int k=0;k<128;k+=4){
      float4 w0 = *(const float4*)(Wp + (k+0)*32 + cq);
      float4 w1 = *(const float4*)(Wp + (k+1)*32 + cq);
      float4 w2 = *(const float4*)(Wp + (k+2)*32 + cq);
      float4 w3 = *(const float4*)(Wp + (k+3)*32 + cq);
      #pragma unroll
      for (int r=0;r<2;r++){
        float4 z = *(const float4*)(t2S + (rb*2+r)*T2STR + k);
        fma4(acc[r], z.x, w0); fma4(acc[r], z.y, w1);
        fma4(acc[r], z.z, w2); fma4(acc[r], z.w, w3);
      }
    }
    const float* bp = (jq < 8) ? bm : bv;
    float4 bb = *(const float4*)(bp + cq);
    const long long sec = (jq < 8) ? (long long)NN*64 : ((long long)NN*64 + (long long)NN*32);
    #pragma unroll
    for (int r=0;r<2;r++){
      float4 v = acc[r];
      v.x += bb.x; v.y += bb.y; v.z += bb.z; v.w += bb.w;
      int rr = rb*2 + r;
      *(float4*)(h3f + rr*64 + ((jq<8)?0:32) + cq) = v;
      int n = base + rr;
      if (n < NN) *(float4*)(out + sec + (long long)n*32 + cq) = v;
    }
  }
  __syncthreads();   // B3
  // ---- reparameterize ----
  #pragma unroll
  for (int i=0;i<4;i++){
    int l = tid + 256*i;
    int r = l >> 5, jj = l & 31;
    float mu = h3f[r*64 + jj];
    float lv = h3f[r*64 + 32 + jj];
    unsigned idx = (unsigned)((base + r)*32 + jj);
    float e = eps_at(idx);
    t2S[r*ZSSTR + jj] = fmaf(e, expf(0.5f*lv), mu);
  }
  __syncthreads();   // B4
  // ---- out = zs @ Wx + bx (fp32 VALU) ----
  {
    const int jq = tid & 15, rb = tid >> 4;
    float4 acc[2];
    #pragma unroll
    for (int r=0;r<2;r++) acc[r] = make_float4(0.f,0.f,0.f,0.f);
    for (int k=0;k<32;k+=4){
      float4 w0 = *(const float4*)(Wx + (k+0)*64 + 4*jq);
      float4 w1 = *(const float4*)(Wx + (k+1)*64 + 4*jq);
      float4 w2 = *(const float4*)(Wx + (k+2)*64 + 4*jq);
      float4 w3 = *(const float4*)(Wx + (k+3)*64 + 4*jq);
      #pragma unroll
      for (int r=0;r<2;r++){
        float4 z = *(const float4*)(t2S + (rb*2+r)*ZSSTR + k);
        fma4(acc[r], z.x, w0); fma4(acc[r], z.y, w1);
        fma4(acc[r], z.z, w2); fma4(acc[r], z.w, w3);
      }
    }
    float4 bb = *(const float4*)(bx + 4*jq);
    #pragma unroll
    for (int r=0;r<2;r++){
      int n = base + rb*2 + r;
      if (n < NN){
        float4 v = acc[r];
        v.x += bb.x; v.y += bb.y; v.z += bb.z; v.w += bb.w;
        *(float4*)(out + (long long)n*64 + 4*jq) = v;
      }
    }
  }
}

extern "C" void kernel_launch(void* const* d_in, const int* in_sizes, int n_in,
                              void* d_out, int out_size, void* d_ws, size_t ws_size,
                              hipStream_t stream) {
  const float* x     = (const float*)d_in[0];
  const int*   ei    = (const int*)d_in[1];
  const float* ea    = (const float*)d_in[2];
  const float* u     = (const float*)d_in[3];
  const int*   batch = (const int*)d_in[4];
  const float* W1 = (const float*)d_in[6];
  const float* b1 = (const float*)d_in[7];
  const float* g1 = (const float*)d_in[8];
  const float* be1= (const float*)d_in[9];
  const float* W2 = (const float*)d_in[10];
  const float* b2 = (const float*)d_in[11];
  const float* W3 = (const float*)d_in[12];
  const float* b3 = (const float*)d_in[13];
  const float* g3 = (const float*)d_in[14];
  const float* be3= (const float*)d_in[15];
  const float* W4 = (const float*)d_in[16];
  const float* b4 = (const float*)d_in[17];
  const float* g4 = (const float*)d_in[18];
  const float* be4= (const float*)d_in[19];
  const float* Wm = (const float*)d_in[20];
  const float* bm = (const float*)d_in[21];
  const float* Wv = (const float*)d_in[22];
  const float* bv = (const float*)d_in[23];
  const float* Wx = (const float*)d_in[24];
  const float* bx = (const float*)d_in[25];

  char* W = (char*)d_ws;
  size_t off = 0;
  unsigned short* h_ws = (unsigned short*)(W + off); off += (size_t)EE*64*2;  // 51.2 MB bf16
  int* cnt      = (int*)(W + off);  off += (size_t)NN*4;
  int* offs     = (int*)(W + off);  off += (size_t)NN*4;
  int* cursor   = (int*)(W + off);  off += (size_t)NN*4;
  int* epos     = (int*)(W + off);  off += (size_t)EE*4;
  int* partials = (int*)(W + off);  off += 256;
  unsigned short* xb  = (unsigned short*)(W + off); off += (size_t)NN*64*2;  // 6.4 MB
  unsigned short* W1T = (unsigned short*)(W + off); off += 128*128*2;
  unsigned short* W2T = (unsigned short*)(W + off); off += 64*128*2;
  unsigned short* W3Th = (unsigned short*)(W + off); off += 256*160*2;
  unsigned short* W3Tl = (unsigned short*)(W + off); off += 256*160*2;
  unsigned short* W4Th = (unsigned short*)(W + off); off += 128*256*2;
  unsigned short* W4Tl = (unsigned short*)(W + off); off += 128*256*2;
  off = (off + 255) & ~(size_t)255;
  unsigned* zg = (unsigned*)(W + off); off += (size_t)(NN + 32)*160*4;       // 32 MB packed z (+pad rows)
  float* out = (float*)d_out;

  hipMemsetAsync(cnt, 0, (size_t)NN*sizeof(int), stream);

  k_prep_x<<<(NN*64/8 + 255)/256, 256, 0, stream>>>(x, xb);
  k_prep_w<<<1, 256, 0, stream>>>(W1, W2, W1T, W2T);
  k_prep_w34<<<384, 256, 0, stream>>>(W3, W4, W3Th, W3Tl, W4Th, W4Tl);
  k_hist <<<(EE+255)/256, 256, 0, stream>>>(ei, cnt);
  k_scan1<<<NB, 256, 0, stream>>>(cnt, offs, partials);
  k_scan2<<<1, 64, 0, stream>>>(partials);
  k_scan3<<<NB, 256, 0, stream>>>(offs, partials, cursor);
  k_fill <<<(EE+255)/256, 256, 0, stream>>>(ei, cursor, epos);

  k_edge<<<EE/64, 256, 0, stream>>>(ei, ea, xb, W1T, b1, g1, be1, W2T, b2, epos, h_ws);
  k_agg <<<(NN*8 + 255)/256, 256, 0, stream>>>(x, u, batch, h_ws, cnt, offs, zg);
  k_node<<<(NN+31)/32, 256, 0, stream>>>(zg,
                                         W3Th, W3Tl, b3, g3, be3,
                                         W4Th, W4Tl, b4, g4, be4,
                                         Wm,bm, Wv,bv, Wx,bx, out);
}

// Round 5
// 551.602 us; speedup vs baseline: 1.0619x; 1.0167x over previous
//
#include <hip/hip_runtime.h>

#define NN 50000
#define EE 400000
#define NB 49   // ceil(NN/1024) scan blocks

typedef __attribute__((ext_vector_type(8))) short bf16x8;
typedef __attribute__((ext_vector_type(4))) float f32x4;

__device__ __forceinline__ void fma4(float4& a, float s, const float4& w){
  a.x = fmaf(s, w.x, a.x);
  a.y = fmaf(s, w.y, a.y);
  a.z = fmaf(s, w.z, a.z);
  a.w = fmaf(s, w.w, a.w);
}

__device__ __forceinline__ unsigned short f2bf(float f){
  unsigned u = __float_as_uint(f);
  unsigned r = (u + 0x7fffu + ((u >> 16) & 1u)) >> 16;   // RNE
  return (unsigned short)r;
}

__device__ __forceinline__ bf16x8 cvt8(float4 lo, float4 hi){
  bf16x8 r;
  r[0]=(short)f2bf(lo.x); r[1]=(short)f2bf(lo.y); r[2]=(short)f2bf(lo.z); r[3]=(short)f2bf(lo.w);
  r[4]=(short)f2bf(hi.x); r[5]=(short)f2bf(hi.y); r[6]=(short)f2bf(hi.z); r[7]=(short)f2bf(hi.w);
  return r;
}

// pack fp32 -> (bf16_hi << 16) | bf16_lo, where hi+lo ~= v to ~16 mantissa bits
__device__ __forceinline__ unsigned packhl(float v){
  unsigned hi = f2bf(v);
  float fh = __uint_as_float(hi << 16);
  unsigned lo = f2bf(v - fh);
  return (hi << 16) | lo;
}

__device__ __forceinline__ uint4 pack4(float4 v){
  uint4 p;
  p.x = packhl(v.x); p.y = packhl(v.y); p.z = packhl(v.z); p.w = packhl(v.w);
  return p;
}

__device__ __forceinline__ void unpack8(uint4 p0, uint4 p1, bf16x8& hi, bf16x8& lo){
  hi[0]=(short)(p0.x>>16); lo[0]=(short)(p0.x & 0xffffu);
  hi[1]=(short)(p0.y>>16); lo[1]=(short)(p0.y & 0xffffu);
  hi[2]=(short)(p0.z>>16); lo[2]=(short)(p0.z & 0xffffu);
  hi[3]=(short)(p0.w>>16); lo[3]=(short)(p0.w & 0xffffu);
  hi[4]=(short)(p1.x>>16); lo[4]=(short)(p1.x & 0xffffu);
  hi[5]=(short)(p1.y>>16); lo[5]=(short)(p1.y & 0xffffu);
  hi[6]=(short)(p1.z>>16); lo[6]=(short)(p1.z & 0xffffu);
  hi[7]=(short)(p1.w>>16); lo[7]=(short)(p1.w & 0xffffu);
}

// bf16-pair helpers for reading h_ws (bf16) as fp32
__device__ __forceinline__ float blo(unsigned u){ return __uint_as_float(u << 16); }
__device__ __forceinline__ float bhi(unsigned u){ return __uint_as_float(u & 0xffff0000u); }

__device__ __forceinline__ unsigned rotl32(unsigned v, int d){ return (v<<d)|(v>>(32-d)); }

// jax.random.normal(key(42)) under jax_threefry_partitionable: counter (0,idx), bits=x0^x1. Verified R3.
__device__ __forceinline__ float eps_at(unsigned idx){
  const unsigned k0 = 0u, k1 = 42u, k2 = 0x1BD11BDAu ^ 0u ^ 42u;
  unsigned x0 = 0u + k0, x1 = idx + k1;
  const int rotA[4] = {13,15,26,6};
  const int rotB[4] = {17,29,16,24};
  #pragma unroll
  for (int i=0;i<4;i++){ x0 += x1; x1 = rotl32(x1, rotA[i]); x1 ^= x0; }
  x0 += k1; x1 += k2 + 1u;
  #pragma unroll
  for (int i=0;i<4;i++){ x0 += x1; x1 = rotl32(x1, rotB[i]); x1 ^= x0; }
  x0 += k2; x1 += k0 + 2u;
  #pragma unroll
  for (int i=0;i<4;i++){ x0 += x1; x1 = rotl32(x1, rotA[i]); x1 ^= x0; }
  x0 += k0; x1 += k1 + 3u;
  #pragma unroll
  for (int i=0;i<4;i++){ x0 += x1; x1 = rotl32(x1, rotB[i]); x1 ^= x0; }
  x0 += k1; x1 += k2 + 4u;
  #pragma unroll
  for (int i=0;i<4;i++){ x0 += x1; x1 = rotl32(x1, rotA[i]); x1 ^= x0; }
  x0 += k2; x1 += k0 + 5u;
  unsigned bits = x0 ^ x1;
  float f = __uint_as_float((bits >> 9) | 0x3f800000u) - 1.0f;
  const float lo = -0.99999994f;
  float u = f * 2.0f + lo;
  u = fmaxf(u, lo);
  float w = -log1pf(-u*u);
  float p;
  if (w < 5.0f){
    w -= 2.5f;
    p = 2.81022636e-08f;
    p = fmaf(p,w, 3.43273939e-07f);
    p = fmaf(p,w,-3.5233877e-06f);
    p = fmaf(p,w,-4.39150654e-06f);
    p = fmaf(p,w, 0.00021858087f);
    p = fmaf(p,w,-0.00125372503f);
    p = fmaf(p,w,-0.00417768164f);
    p = fmaf(p,w, 0.246640727f);
    p = fmaf(p,w, 1.50140941f);
  } else {
    w = sqrtf(w) - 3.0f;
    p = -0.000200214257f;
    p = fmaf(p,w, 0.000100950558f);
    p = fmaf(p,w, 0.00134934322f);
    p = fmaf(p,w,-0.00367342844f);
    p = fmaf(p,w, 0.00573950773f);
    p = fmaf(p,w,-0.0076224613f);
    p = fmaf(p,w, 0.00943887047f);
    p = fmaf(p,w, 1.00167406f);
    p = fmaf(p,w, 2.83297682f);
  }
  return 1.41421356237f * (p * u);
}

// ================= prep: bf16 conversions =================
__global__ __launch_bounds__(256) void k_prep_x(const float* __restrict__ x,
                                                unsigned short* __restrict__ xb){
  int t = blockIdx.x*256 + threadIdx.x;           // one bf16x8 per thread
  if (t < NN*64/8){
    const float4* p = (const float4*)(x + t*8);
    bf16x8 v = cvt8(p[0], p[1]);
    *(bf16x8*)(xb + t*8) = v;
  }
}

// W1T[n][k] = W1[k][n] (128x128), W2T[n][k] = W2[k][n] (64x128), bf16
__global__ __launch_bounds__(256) void k_prep_w(const float* __restrict__ W1,
                                                const float* __restrict__ W2,
                                                unsigned short* __restrict__ W1T,
                                                unsigned short* __restrict__ W2T){
  for (int i = threadIdx.x; i < 128*128; i += 256){
    int n = i >> 7, k = i & 127;
    W1T[i] = f2bf(W1[k*128 + n]);
  }
  for (int i = threadIdx.x; i < 64*128; i += 256){
    int n = i >> 7, k = i & 127;
    W2T[i] = f2bf(W2[k*64 + n]);
  }
}

// W3T hi/lo [256][160] from W3[160][256]; W4T hi/lo [128][256] from W4[256][128]
__global__ __launch_bounds__(256) void k_prep_w34(const float* __restrict__ W3,
                                                  const float* __restrict__ W4,
                                                  unsigned short* __restrict__ W3Th,
                                                  unsigned short* __restrict__ W3Tl,
                                                  unsigned short* __restrict__ W4Th,
                                                  unsigned short* __restrict__ W4Tl){
  int b = blockIdx.x;
  if (b < 256){
    int n = b;
    for (int k = threadIdx.x; k < 160; k += 256){
      float w = W3[k*256 + n];
      unsigned h = f2bf(w);
      float fh = __uint_as_float(h << 16);
      W3Th[n*160 + k] = (unsigned short)h;
      W3Tl[n*160 + k] = f2bf(w - fh);
    }
  } else {
    int n = b - 256;            // < 128
    int k = threadIdx.x;        // 256 threads, K=256
    float w = W4[k*128 + n];
    unsigned h = f2bf(w);
    float fh = __uint_as_float(h << 16);
    W4Th[n*256 + k] = (unsigned short)h;
    W4Tl[n*256 + k] = f2bf(w - fh);
  }
}

// ================= CSR construction =================
__global__ __launch_bounds__(256) void k_hist(const int* __restrict__ ei, int* __restrict__ cnt){
  int e = blockIdx.x*256 + threadIdx.x;
  if (e < EE) atomicAdd(&cnt[ei[EE + e]], 1);
}

__global__ __launch_bounds__(256) void k_scan1(const int* __restrict__ cnt,
                                               int* __restrict__ offs,
                                               int* __restrict__ partials){
  __shared__ int sdata[256];
  const int t = threadIdx.x, b = blockIdx.x;
  const int base = b*1024 + t*4;
  int v0 = (base+0 < NN) ? cnt[base+0] : 0;
  int v1 = (base+1 < NN) ? cnt[base+1] : 0;
  int v2 = (base+2 < NN) ? cnt[base+2] : 0;
  int v3 = (base+3 < NN) ? cnt[base+3] : 0;
  int tsum = v0+v1+v2+v3;
  sdata[t] = tsum;
  __syncthreads();
  for (int off=1; off<256; off<<=1){
    int add = (t >= off) ? sdata[t-off] : 0;
    __syncthreads();
    sdata[t] += add;
    __syncthreads();
  }
  int run = sdata[t] - tsum;
  if (base+0 < NN) offs[base+0] = run;  run += v0;
  if (base+1 < NN) offs[base+1] = run;  run += v1;
  if (base+2 < NN) offs[base+2] = run;  run += v2;
  if (base+3 < NN) offs[base+3] = run;
  if (t == 255) partials[b] = sdata[255];
}

__global__ __launch_bounds__(64) void k_scan2(int* __restrict__ partials){
  int l = threadIdx.x;
  int v = (l < NB) ? partials[l] : 0;
  int inc = v;
  #pragma unroll
  for (int off=1; off<64; off<<=1){
    int t = __shfl_up(inc, off);
    if (l >= off) inc += t;
  }
  if (l < NB) partials[l] = inc - v;
}

__global__ __launch_bounds__(256) void k_scan3(int* __restrict__ offs,
                                               const int* __restrict__ partials,
                                               int* __restrict__ cursor){
  const int t = threadIdx.x, b = blockIdx.x;
  const int base = b*1024 + t*4;
  int add = partials[b];
  #pragma unroll
  for (int k=0;k<4;k++){
    int i = base + k;
    if (i < NN){ int o = offs[i] + add; offs[i] = o; cursor[i] = o; }
  }
}

// inverse permutation: epos[e] = CSR slot of edge e  (coalesced write)
__global__ __launch_bounds__(256) void k_fill(const int* __restrict__ ei,
                                              int* __restrict__ cursor,
                                              int* __restrict__ epos){
  int e = blockIdx.x*256 + threadIdx.x;
  if (e < EE){
    int c = ei[EE + e];
    epos[e] = atomicAdd(&cursor[c], 1);
  }
}

// ---------------- kernel 2: edge MLP via MFMA -> h_ws (bf16, CSR-ordered) ----------------
#define H1STR 132
__global__ __launch_bounds__(256, 4) void k_edge(const int* __restrict__ ei,
    const float* __restrict__ ea,
    const unsigned short* __restrict__ xb,
    const unsigned short* __restrict__ W1T, const float* __restrict__ b1,
    const float* __restrict__ g1, const float* __restrict__ be1,
    const unsigned short* __restrict__ W2T, const float* __restrict__ b2,
    const int* __restrict__ epos,
    unsigned short* __restrict__ h_ws){
  __shared__ __align__(16) float h1[64*H1STR];   // 33,792 B
  __shared__ int rows_l[64];
  __shared__ int slot_l[64];
  const int tid  = threadIdx.x;
  const int base = blockIdx.x * 64;
  const int wv   = tid >> 6;        // wave 0..3
  const int lane = tid & 63;
  const int quad = lane >> 4;       // 0..3
  const int l16  = lane & 15;
  if (tid < 64) rows_l[tid] = ei[base + tid];
  if (tid >= 128 && tid < 192) slot_l[tid-128] = epos[base + tid - 128];
  __syncthreads();
  // ---- GEMM1: wave wv owns n-groups {2wv, 2wv+1}, all 4 m-groups ----
  {
    int rw[4];
    #pragma unroll
    for (int m=0;m<4;m++) rw[m] = rows_l[m*16 + l16];
    f32x4 acc[4][2];
    #pragma unroll
    for (int m=0;m<4;m++){ acc[m][0] = (f32x4){0.f,0.f,0.f,0.f}; acc[m][1] = (f32x4){0.f,0.f,0.f,0.f}; }
    #pragma unroll
    for (int ks=0; ks<4; ks++){
      bf16x8 af[4];
      if (ks < 2){
        #pragma unroll
        for (int m=0;m<4;m++)
          af[m] = *(const bf16x8*)(xb + (size_t)rw[m]*64 + ks*32 + quad*8);
      } else {
        #pragma unroll
        for (int m=0;m<4;m++){
          const float* p = ea + (size_t)(base + m*16 + l16)*64 + (ks-2)*32 + quad*8;
          af[m] = cvt8(*(const float4*)p, *(const float4*)(p+4));
        }
      }
      bf16x8 bf0 = *(const bf16x8*)(W1T + (size_t)((2*wv+0)*16 + l16)*128 + ks*32 + quad*8);
      bf16x8 bf1 = *(const bf16x8*)(W1T + (size_t)((2*wv+1)*16 + l16)*128 + ks*32 + quad*8);
      #pragma unroll
      for (int m=0;m<4;m++){
        acc[m][0] = __builtin_amdgcn_mfma_f32_16x16x32_bf16(af[m], bf0, acc[m][0], 0, 0, 0);
        acc[m][1] = __builtin_amdgcn_mfma_f32_16x16x32_bf16(af[m], bf1, acc[m][1], 0, 0, 0);
      }
    }
    #pragma unroll
    for (int nl=0; nl<2; nl++){
      float b1c = b1[(2*wv+nl)*16 + l16];
      #pragma unroll
      for (int m=0;m<4;m++){
        #pragma unroll
        for (int r=0;r<4;r++)
          h1[(m*16 + quad*4 + r)*H1STR + (2*wv+nl)*16 + l16] = acc[m][nl][r] + b1c;
      }
    }
  }
  __syncthreads();
  // ---- LayerNorm(128) + ReLU ----
  {
    const float gA = g1[lane], gB = g1[lane+64];
    const float bA = be1[lane], bB = be1[lane+64];
    for (int r = wv*16; r < wv*16 + 16; ++r){
      float a = h1[r*H1STR + lane];
      float b = h1[r*H1STR + 64 + lane];
      float s = a + b, ss = fmaf(a,a,b*b);
      #pragma unroll
      for (int off=32; off; off>>=1){
        s  += __shfl_xor(s, off);
        ss += __shfl_xor(ss, off);
      }
      float mean = s * (1.0f/128.0f);
      float var  = ss * (1.0f/128.0f) - mean*mean;
      float inv = rsqrtf(var + 1e-5f);
      h1[r*H1STR + lane]      = fmaxf(fmaf((a-mean)*inv, gA, bA), 0.f);
      h1[r*H1STR + 64 + lane] = fmaxf(fmaf((b-mean)*inv, gB, bB), 0.f);
    }
  }
  __syncthreads();
  // ---- GEMM2 ----
  {
    f32x4 acc2[4];
    #pragma unroll
    for (int m=0;m<4;m++) acc2[m] = (f32x4){0.f,0.f,0.f,0.f};
    #pragma unroll
    for (int ks=0; ks<4; ks++){
      bf16x8 bfr = *(const bf16x8*)(W2T + (size_t)(wv*16 + l16)*128 + ks*32 + quad*8);
      #pragma unroll
      for (int m=0;m<4;m++){
        const float* p = h1 + (m*16 + l16)*H1STR + ks*32 + quad*8;
        bf16x8 af = cvt8(*(const float4*)p, *(const float4*)(p+4));
        acc2[m] = __builtin_amdgcn_mfma_f32_16x16x32_bf16(af, bfr, acc2[m], 0, 0, 0);
      }
    }
    float b2c = b2[wv*16 + l16];
    #pragma unroll
    for (int m=0;m<4;m++){
      #pragma unroll
      for (int r=0;r<4;r++)
        h_ws[(size_t)slot_l[m*16 + quad*4 + r]*64 + wv*16 + l16] = f2bf(acc2[m][r] + b2c);
    }
  }
}

// ---------------- kernel 2.5: streaming aggregation -> packed z (global) ----------------
// 8 threads per node. No LDS, no barriers: pure BW kernel, fully resident.
__global__ __launch_bounds__(256, 8) void k_agg(const float* __restrict__ x,
    const float* __restrict__ u, const int* __restrict__ batch,
    const unsigned short* __restrict__ h_ws, const int* __restrict__ cnt,
    const int* __restrict__ offs, unsigned* __restrict__ zg){
  int t = blockIdx.x*256 + threadIdx.x;
  int n = t >> 3, p = t & 7;
  if (n >= NN) return;
  unsigned* zr = zg + (size_t)n*160;
  // x: cols p*8 .. p*8+7
  {
    const float4* xp = (const float4*)(x + (size_t)n*64 + p*8);
    *(uint4*)(zr + p*8)     = pack4(xp[0]);
    *(uint4*)(zr + p*8 + 4) = pack4(xp[1]);
  }
  // u: cols 128 + p*4 .. +3
  {
    const float4* up = (const float4*)(u + (size_t)batch[n]*32 + p*4);
    *(uint4*)(zr + 128 + p*4) = pack4(up[0]);
  }
  // aggregation over CSR-contiguous bf16 rows
  float a0=0.f,a1=0.f,a2=0.f,a3=0.f,a4=0.f,a5=0.f,a6=0.f,a7=0.f;
  int deg = cnt[n];
  const unsigned short* hp = h_ws + (size_t)offs[n]*64 + p*8;
  int j = 0;
  for (; j + 4 <= deg; j += 4){
    uint4 v0 = *(const uint4*)(hp);
    uint4 v1 = *(const uint4*)(hp + 64);
    uint4 v2 = *(const uint4*)(hp + 128);
    uint4 v3 = *(const uint4*)(hp + 192);
    hp += 256;
    a0 += blo(v0.x); a1 += bhi(v0.x); a2 += blo(v0.y); a3 += bhi(v0.y);
    a4 += blo(v0.z); a5 += bhi(v0.z); a6 += blo(v0.w); a7 += bhi(v0.w);
    a0 += blo(v1.x); a1 += bhi(v1.x); a2 += blo(v1.y); a3 += bhi(v1.y);
    a4 += blo(v1.z); a5 += bhi(v1.z); a6 += blo(v1.w); a7 += bhi(v1.w);
    a0 += blo(v2.x); a1 += bhi(v2.x); a2 += blo(v2.y); a3 += bhi(v2.y);
    a4 += blo(v2.z); a5 += bhi(v2.z); a6 += blo(v2.w); a7 += bhi(v2.w);
    a0 += blo(v3.x); a1 += bhi(v3.x); a2 += blo(v3.y); a3 += bhi(v3.y);
    a4 += blo(v3.z); a5 += bhi(v3.z); a6 += blo(v3.w); a7 += bhi(v3.w);
  }
  for (; j < deg; ++j){
    uint4 v = *(const uint4*)(hp);
    hp += 64;
    a0 += blo(v.x); a1 += bhi(v.x); a2 += blo(v.y); a3 += bhi(v.y);
    a4 += blo(v.z); a5 += bhi(v.z); a6 += blo(v.w); a7 += bhi(v.w);
  }
  float rc = 1.0f / fmaxf((float)deg, 1.0f);
  *(uint4*)(zr + 64 + p*8)     = pack4(make_float4(a0*rc, a1*rc, a2*rc, a3*rc));
  *(uint4*)(zr + 64 + p*8 + 4) = pack4(make_float4(a4*rc, a5*rc, a6*rc, a7*rc));
}

// ---------------- kernel 3: node MLP (MFMA hi/lo) + heads + reparam ----------------
// 128 threads / 16 nodes per block: 6 blocks/CU (LDS 25,088 B), convoy-breaking.
#define T2STR 132
#define ZSSTR 36
#define H3STR 260   // h3 stride (f32 / packed u32 elems), 16B-aligned rows
__global__ __launch_bounds__(128, 3) void k_node(const unsigned* __restrict__ zg,
    const unsigned short* __restrict__ W3Th, const unsigned short* __restrict__ W3Tl,
    const float* __restrict__ b3,
    const float* __restrict__ g3, const float* __restrict__ be3,
    const unsigned short* __restrict__ W4Th, const unsigned short* __restrict__ W4Tl,
    const float* __restrict__ b4,
    const float* __restrict__ g4, const float* __restrict__ be4,
    const float* __restrict__ Wm, const float* __restrict__ bm,
    const float* __restrict__ Wv, const float* __restrict__ bv,
    const float* __restrict__ Wx, const float* __restrict__ bx,
    float* __restrict__ out){
  // arena: [0, 16*H3STR*4) h3f: GEMM1 out fp32 -> packed h3 -> hm[16][64]
  //        rest: t2 fp32 (T2STR) -> zs fp32 (ZSSTR)
  __shared__ __align__(16) char arena[(16*H3STR + 16*T2STR)*4];   // 25,088 B
  float*    h3f = (float*)arena;
  unsigned* h3p = (unsigned*)arena;
  float*    t2S = (float*)(arena + 16*H3STR*4);

  const int tid = threadIdx.x;
  const int base = blockIdx.x * 16;
  const int wv   = tid >> 6;        // 0..1
  const int lane = tid & 63;
  const int quad = lane >> 4;
  const int l16  = lane & 15;

  // ---- GEMM1 (MFMA): C[16x256] = Z[16x160] @ W3, hi/lo compensated; A from global zg ----
  // wave wv -> n-tiles wv*8 .. +7 (full 16-tile coverage), single m-tile
  {
    const unsigned* az = zg + (size_t)(base + l16)*160 + quad*8;
    f32x4 acc[8];
    #pragma unroll
    for (int i=0;i<8;i++) acc[i] = (f32x4){0.f,0.f,0.f,0.f};
    #pragma unroll
    for (int ks=0; ks<5; ks++){
      uint4 p0 = *(const uint4*)(az + ks*32);
      uint4 p1 = *(const uint4*)(az + ks*32 + 4);
      bf16x8 ah, al;
      unpack8(p0, p1, ah, al);
      #pragma unroll
      for (int i=0;i<8;i++){
        int nt = wv*8 + i;
        bf16x8 bh = *(const bf16x8*)(W3Th + (size_t)(nt*16 + l16)*160 + ks*32 + quad*8);
        bf16x8 bl = *(const bf16x8*)(W3Tl + (size_t)(nt*16 + l16)*160 + ks*32 + quad*8);
        acc[i] = __builtin_amdgcn_mfma_f32_16x16x32_bf16(ah, bh, acc[i], 0, 0, 0);
        acc[i] = __builtin_amdgcn_mfma_f32_16x16x32_bf16(al, bh, acc[i], 0, 0, 0);
        acc[i] = __builtin_amdgcn_mfma_f32_16x16x32_bf16(ah, bl, acc[i], 0, 0, 0);
      }
    }
    #pragma unroll
    for (int i=0;i<8;i++){
      int nt = wv*8 + i;
      float bc = b3[nt*16 + l16];
      #pragma unroll
      for (int r=0;r<4;r++)
        h3f[(quad*4 + r)*H3STR + nt*16 + l16] = acc[i][r] + bc;
    }
  }
  __syncthreads();   // B1a
  // ---- LN(256)+ReLU, pack hi/lo in place (8 rows per wave) ----
  {
    float4 gg  = *(const float4*)(g3 + lane*4);
    float4 bet = *(const float4*)(be3 + lane*4);
    #pragma unroll
    for (int r=0;r<8;r++){
      int row = wv*8 + r;
      float4 v = *(const float4*)(h3f + row*H3STR + lane*4);
      float s  = v.x + v.y + v.z + v.w;
      float ss = fmaf(v.x,v.x, fmaf(v.y,v.y, fmaf(v.z,v.z, v.w*v.w)));
      #pragma unroll
      for (int off=32; off; off>>=1){ s += __shfl_xor(s,off); ss += __shfl_xor(ss,off); }
      float mean = s * (1.0f/256.0f);
      float inv  = rsqrtf(ss*(1.0f/256.0f) - mean*mean + 1e-5f);
      float4 o;
      o.x = fmaxf(fmaf((v.x-mean)*inv, gg.x, bet.x), 0.f);
      o.y = fmaxf(fmaf((v.y-mean)*inv, gg.y, bet.y), 0.f);
      o.z = fmaxf(fmaf((v.z-mean)*inv, gg.z, bet.z), 0.f);
      o.w = fmaxf(fmaf((v.w-mean)*inv, gg.w, bet.w), 0.f);
      *(uint4*)(h3p + row*H3STR + lane*4) = pack4(o);
    }
  }
  __syncthreads();   // B1b
  // ---- GEMM2 (MFMA): C2[16x128] = H3[16x256] @ W4, hi/lo compensated ----
  // wave wv -> n-tiles wv*4 .. +3 (full 8-tile coverage), single m-tile
  {
    f32x4 acc[4];
    #pragma unroll
    for (int i=0;i<4;i++) acc[i] = (f32x4){0.f,0.f,0.f,0.f};
    #pragma unroll
    for (int ks=0; ks<8; ks++){
      const unsigned* ap = h3p + l16*H3STR + ks*32 + quad*8;
      uint4 p0 = *(const uint4*)ap;
      uint4 p1 = *(const uint4*)(ap + 4);
      bf16x8 ah, al;
      unpack8(p0, p1, ah, al);
      #pragma unroll
      for (int i=0;i<4;i++){
        int nt = wv*4 + i;
        bf16x8 bh = *(const bf16x8*)(W4Th + (size_t)(nt*16 + l16)*256 + ks*32 + quad*8);
        bf16x8 bl = *(const bf16x8*)(W4Tl + (size_t)(nt*16 + l16)*256 + ks*32 + quad*8);
        acc[i] = __builtin_amdgcn_mfma_f32_16x16x32_bf16(ah, bh, acc[i], 0, 0, 0);
        acc[i] = __builtin_amdgcn_mfma_f32_16x16x32_bf16(al, bh, acc[i], 0, 0, 0);
        acc[i] = __builtin_amdgcn_mfma_f32_16x16x32_bf16(ah, bl, acc[i], 0, 0, 0);
      }
    }
    #pragma unroll
    for (int i=0;i<4;i++){
      int nt = wv*4 + i;
      float bc = b4[nt*16 + l16];
      #pragma unroll
      for (int r=0;r<4;r++)
        t2S[(quad*4 + r)*T2STR + nt*16 + l16] = acc[i][r] + bc;
    }
  }
  __syncthreads();   // B2a
  // ---- LN(128)+ReLU in place (fp32, heads read fp32) ----
  {
    const int jq = tid & 31, rb = tid >> 5;   // rb 0..3
    float4 gg  = *(const float4*)(g4 + 4*jq);
    float4 bet = *(const float4*)(be4 + 4*jq);
    #pragma unroll
    for (int r=0;r<4;r++){
      int row = rb*4 + r;
      float4 v = *(const float4*)(t2S + row*T2STR + 4*jq);
      float s  = v.x + v.y + v.z + v.w;
      float ss = fmaf(v.x,v.x, fmaf(v.y,v.y, fmaf(v.z,v.z, v.w*v.w)));
      #pragma unroll
      for (int off=16; off; off>>=1){ s += __shfl_xor(s,off); ss += __shfl_xor(ss,off); }
      float mean = s * (1.0f/128.0f);
      float inv  = rsqrtf(ss*(1.0f/128.0f) - mean*mean + 1e-5f);
      float4 o;
      o.x = fmaxf(fmaf((v.x-mean)*inv, gg.x, bet.x), 0.f);
      o.y = fmaxf(fmaf((v.y-mean)*inv, gg.y, bet.y), 0.f);
      o.z = fmaxf(fmaf((v.z-mean)*inv, gg.z, bet.z), 0.f);
      o.w = fmaxf(fmaf((v.w-mean)*inv, gg.w, bet.w), 0.f);
      *(float4*)(t2S + row*T2STR + 4*jq) = o;
    }
  }
  __syncthreads();   // B2
  // ---- heads: mu | lv  (fp32 VALU) ----
  {
    const int jq = tid & 15, rb = tid >> 4;   // rb 0..7
    const float* Wp = (jq < 8) ? Wm : Wv;
    const int cq = (jq & 7) * 4;
    float4 acc[2];
    #pragma unroll
    for (int r=0;r<2;r++) acc[r] = make_float4(0.f,0.f,0.f,0.f);
    #pragma unroll 2
    for (int k=0;k<128;k+=4){
      float4 w0 = *(const float4*)(Wp + (k+0)*32 + cq);
      float4 w1 = *(const float4*)(Wp + (k+1)*32 + cq);
      float4 w2 = *(const float4*)(Wp + (k+2)*32 + cq);
      float4 w3 = *(const float4*)(Wp + (k+3)*32 + cq);
      #pragma unroll
      for (int r=0;r<2;r++){
        float4 z = *(const float4*)(t2S + (rb*2+r)*T2STR + k);
        fma4(acc[r], z.x, w0); fma4(acc[r], z.y, w1);
        fma4(acc[r], z.z, w2); fma4(acc[r], z.w, w3);
      }
    }
    const float* bp = (jq < 8) ? bm : bv;
    float4 bb = *(const float4*)(bp + cq);
    const long long sec = (jq < 8) ? (long long)NN*64 : ((long long)NN*64 + (long long)NN*32);
    #pragma unroll
    for (int r=0;r<2;r++){
      float4 v = acc[r];
      v.x += bb.x; v.y += bb.y; v.z += bb.z; v.w += bb.w;
      int rr = rb*2 + r;
      *(float4*)(h3f + rr*64 + ((jq<8)?0:32) + cq) = v;
      int n = base + rr;
      if (n < NN) *(float4*)(out + sec + (long long)n*32 + cq) = v;
    }
  }
  __syncthreads();   // B3
  // ---- reparameterize (16 rows x 32 = 512 elems, 128 threads x 4) ----
  #pragma unroll
  for (int i=0;i<4;i++){
    int l = tid + 128*i;
    int r = l >> 5, jj = l & 31;
    float mu = h3f[r*64 + jj];
    float lv = h3f[r*64 + 32 + jj];
    unsigned idx = (unsigned)((base + r)*32 + jj);
    float e = eps_at(idx);
    t2S[r*ZSSTR + jj] = fmaf(e, expf(0.5f*lv), mu);
  }
  __syncthreads();   // B4
  // ---- out = zs @ Wx + bx (fp32 VALU) ----
  {
    const int jq = tid & 15, rb = tid >> 4;   // rb 0..7
    float4 acc[2];
    #pragma unroll
    for (int r=0;r<2;r++) acc[r] = make_float4(0.f,0.f,0.f,0.f);
    #pragma unroll
    for (int k=0;k<32;k+=4){
      float4 w0 = *(const float4*)(Wx + (k+0)*64 + 4*jq);
      float4 w1 = *(const float4*)(Wx + (k+1)*64 + 4*jq);
      float4 w2 = *(const float4*)(Wx + (k+2)*64 + 4*jq);
      float4 w3 = *(const float4*)(Wx + (k+3)*64 + 4*jq);
      #pragma unroll
      for (int r=0;r<2;r++){
        float4 z = *(const float4*)(t2S + (rb*2+r)*ZSSTR + k);
        fma4(acc[r], z.x, w0); fma4(acc[r], z.y, w1);
        fma4(acc[r], z.z, w2); fma4(acc[r], z.w, w3);
      }
    }
    float4 bb = *(const float4*)(bx + 4*jq);
    #pragma unroll
    for (int r=0;r<2;r++){
      int n = base + rb*2 + r;
      if (n < NN){
        float4 v = acc[r];
        v.x += bb.x; v.y += bb.y; v.z += bb.z; v.w += bb.w;
        *(float4*)(out + (long long)n*64 + 4*jq) = v;
      }
    }
  }
}

extern "C" void kernel_launch(void* const* d_in, const int* in_sizes, int n_in,
                              void* d_out, int out_size, void* d_ws, size_t ws_size,
                              hipStream_t stream) {
  const float* x     = (const float*)d_in[0];
  const int*   ei    = (const int*)d_in[1];
  const float* ea    = (const float*)d_in[2];
  const float* u     = (const float*)d_in[3];
  const int*   batch = (const int*)d_in[4];
  const float* W1 = (const float*)d_in[6];
  const float* b1 = (const float*)d_in[7];
  const float* g1 = (const float*)d_in[8];
  const float* be1= (const float*)d_in[9];
  const float* W2 = (const float*)d_in[10];
  const float* b2 = (const float*)d_in[11];
  const float* W3 = (const float*)d_in[12];
  const float* b3 = (const float*)d_in[13];
  const float* g3 = (const float*)d_in[14];
  const float* be3= (const float*)d_in[15];
  const float* W4 = (const float*)d_in[16];
  const float* b4 = (const float*)d_in[17];
  const float* g4 = (const float*)d_in[18];
  const float* be4= (const float*)d_in[19];
  const float* Wm = (const float*)d_in[20];
  const float* bm = (const float*)d_in[21];
  const float* Wv = (const float*)d_in[22];
  const float* bv = (const float*)d_in[23];
  const float* Wx = (const float*)d_in[24];
  const float* bx = (const float*)d_in[25];

  char* W = (char*)d_ws;
  size_t off = 0;
  unsigned short* h_ws = (unsigned short*)(W + off); off += (size_t)EE*64*2;  // 51.2 MB bf16
  int* cnt      = (int*)(W + off);  off += (size_t)NN*4;
  int* offs     = (int*)(W + off);  off += (size_t)NN*4;
  int* cursor   = (int*)(W + off);  off += (size_t)NN*4;
  int* epos     = (int*)(W + off);  off += (size_t)EE*4;
  int* partials = (int*)(W + off);  off += 256;
  unsigned short* xb  = (unsigned short*)(W + off); off += (size_t)NN*64*2;  // 6.4 MB
  unsigned short* W1T = (unsigned short*)(W + off); off += 128*128*2;
  unsigned short* W2T = (unsigned short*)(W + off); off += 64*128*2;
  unsigned short* W3Th = (unsigned short*)(W + off); off += 256*160*2;
  unsigned short* W3Tl = (unsigned short*)(W + off); off += 256*160*2;
  unsigned short* W4Th = (unsigned short*)(W + off); off += 128*256*2;
  unsigned short* W4Tl = (unsigned short*)(W + off); off += 128*256*2;
  off = (off + 255) & ~(size_t)255;
  unsigned* zg = (unsigned*)(W + off); off += (size_t)(NN + 32)*160*4;       // 32 MB packed z (+pad rows)
  float* out = (float*)d_out;

  hipMemsetAsync(cnt, 0, (size_t)NN*sizeof(int), stream);

  k_prep_x<<<(NN*64/8 + 255)/256, 256, 0, stream>>>(x, xb);
  k_prep_w<<<1, 256, 0, stream>>>(W1, W2, W1T, W2T);
  k_prep_w34<<<384, 256, 0, stream>>>(W3, W4, W3Th, W3Tl, W4Th, W4Tl);
  k_hist <<<(EE+255)/256, 256, 0, stream>>>(ei, cnt);
  k_scan1<<<NB, 256, 0, stream>>>(cnt, offs, partials);
  k_scan2<<<1, 64, 0, stream>>>(partials);
  k_scan3<<<NB, 256, 0, stream>>>(offs, partials, cursor);
  k_fill <<<(EE+255)/256, 256, 0, stream>>>(ei, cursor, epos);

  k_edge<<<EE/64, 256, 0, stream>>>(ei, ea, xb, W1T, b1, g1, be1, W2T, b2, epos, h_ws);
  k_agg <<<(NN*8 + 255)/256, 256, 0, stream>>>(x, u, batch, h_ws, cnt, offs, zg);
  k_node<<<(NN+15)/16, 128, 0, stream>>>(zg,
                                         W3Th, W3Tl, b3, g3, be3,
                                         W4Th, W4Tl, b4, g4, be4,
                                         Wm,bm, Wv,bv, Wx,bx, out);
}

// Round 6
// 495.017 us; speedup vs baseline: 1.1833x; 1.1143x over previous
//
#include <hip/hip_runtime.h>

#define NN 50000
#define EE 400000
#define NB 49   // ceil(NN/1024) scan blocks

typedef __attribute__((ext_vector_type(8))) short bf16x8;
typedef __attribute__((ext_vector_type(4))) float f32x4;

__device__ __forceinline__ void fma4(float4& a, float s, const float4& w){
  a.x = fmaf(s, w.x, a.x);
  a.y = fmaf(s, w.y, a.y);
  a.z = fmaf(s, w.z, a.z);
  a.w = fmaf(s, w.w, a.w);
}

__device__ __forceinline__ unsigned short f2bf(float f){
  unsigned u = __float_as_uint(f);
  unsigned r = (u + 0x7fffu + ((u >> 16) & 1u)) >> 16;   // RNE
  return (unsigned short)r;
}

__device__ __forceinline__ bf16x8 cvt8(float4 lo, float4 hi){
  bf16x8 r;
  r[0]=(short)f2bf(lo.x); r[1]=(short)f2bf(lo.y); r[2]=(short)f2bf(lo.z); r[3]=(short)f2bf(lo.w);
  r[4]=(short)f2bf(hi.x); r[5]=(short)f2bf(hi.y); r[6]=(short)f2bf(hi.z); r[7]=(short)f2bf(hi.w);
  return r;
}

// pack fp32 -> (bf16_hi << 16) | bf16_lo, where hi+lo ~= v to ~16 mantissa bits
__device__ __forceinline__ unsigned packhl(float v){
  unsigned hi = f2bf(v);
  float fh = __uint_as_float(hi << 16);
  unsigned lo = f2bf(v - fh);
  return (hi << 16) | lo;
}

__device__ __forceinline__ uint4 pack4(float4 v){
  uint4 p;
  p.x = packhl(v.x); p.y = packhl(v.y); p.z = packhl(v.z); p.w = packhl(v.w);
  return p;
}

__device__ __forceinline__ void unpack8(uint4 p0, uint4 p1, bf16x8& hi, bf16x8& lo){
  hi[0]=(short)(p0.x>>16); lo[0]=(short)(p0.x & 0xffffu);
  hi[1]=(short)(p0.y>>16); lo[1]=(short)(p0.y & 0xffffu);
  hi[2]=(short)(p0.z>>16); lo[2]=(short)(p0.z & 0xffffu);
  hi[3]=(short)(p0.w>>16); lo[3]=(short)(p0.w & 0xffffu);
  hi[4]=(short)(p1.x>>16); lo[4]=(short)(p1.x & 0xffffu);
  hi[5]=(short)(p1.y>>16); lo[5]=(short)(p1.y & 0xffffu);
  hi[6]=(short)(p1.z>>16); lo[6]=(short)(p1.z & 0xffffu);
  hi[7]=(short)(p1.w>>16); lo[7]=(short)(p1.w & 0xffffu);
}

// bf16-pair helpers for reading h_ws (bf16) as fp32
__device__ __forceinline__ float blo(unsigned u){ return __uint_as_float(u << 16); }
__device__ __forceinline__ float bhi(unsigned u){ return __uint_as_float(u & 0xffff0000u); }

__device__ __forceinline__ unsigned rotl32(unsigned v, int d){ return (v<<d)|(v>>(32-d)); }

// jax.random.normal(key(42)) under jax_threefry_partitionable: counter (0,idx), bits=x0^x1. Verified R3.
__device__ __forceinline__ float eps_at(unsigned idx){
  const unsigned k0 = 0u, k1 = 42u, k2 = 0x1BD11BDAu ^ 0u ^ 42u;
  unsigned x0 = 0u + k0, x1 = idx + k1;
  const int rotA[4] = {13,15,26,6};
  const int rotB[4] = {17,29,16,24};
  #pragma unroll
  for (int i=0;i<4;i++){ x0 += x1; x1 = rotl32(x1, rotA[i]); x1 ^= x0; }
  x0 += k1; x1 += k2 + 1u;
  #pragma unroll
  for (int i=0;i<4;i++){ x0 += x1; x1 = rotl32(x1, rotB[i]); x1 ^= x0; }
  x0 += k2; x1 += k0 + 2u;
  #pragma unroll
  for (int i=0;i<4;i++){ x0 += x1; x1 = rotl32(x1, rotA[i]); x1 ^= x0; }
  x0 += k0; x1 += k1 + 3u;
  #pragma unroll
  for (int i=0;i<4;i++){ x0 += x1; x1 = rotl32(x1, rotB[i]); x1 ^= x0; }
  x0 += k1; x1 += k2 + 4u;
  #pragma unroll
  for (int i=0;i<4;i++){ x0 += x1; x1 = rotl32(x1, rotA[i]); x1 ^= x0; }
  x0 += k2; x1 += k0 + 5u;
  unsigned bits = x0 ^ x1;
  float f = __uint_as_float((bits >> 9) | 0x3f800000u) - 1.0f;
  const float lo = -0.99999994f;
  float u = f * 2.0f + lo;
  u = fmaxf(u, lo);
  float w = -log1pf(-u*u);
  float p;
  if (w < 5.0f){
    w -= 2.5f;
    p = 2.81022636e-08f;
    p = fmaf(p,w, 3.43273939e-07f);
    p = fmaf(p,w,-3.5233877e-06f);
    p = fmaf(p,w,-4.39150654e-06f);
    p = fmaf(p,w, 0.00021858087f);
    p = fmaf(p,w,-0.00125372503f);
    p = fmaf(p,w,-0.00417768164f);
    p = fmaf(p,w, 0.246640727f);
    p = fmaf(p,w, 1.50140941f);
  } else {
    w = sqrtf(w) - 3.0f;
    p = -0.000200214257f;
    p = fmaf(p,w, 0.000100950558f);
    p = fmaf(p,w, 0.00134934322f);
    p = fmaf(p,w,-0.00367342844f);
    p = fmaf(p,w, 0.00573950773f);
    p = fmaf(p,w,-0.0076224613f);
    p = fmaf(p,w, 0.00943887047f);
    p = fmaf(p,w, 1.00167406f);
    p = fmaf(p,w, 2.83297682f);
  }
  return 1.41421356237f * (p * u);
}

// ================= prep: bf16 conversions =================
__global__ __launch_bounds__(256) void k_prep_x(const float* __restrict__ x,
                                                unsigned short* __restrict__ xb){
  int t = blockIdx.x*256 + threadIdx.x;           // one bf16x8 per thread
  if (t < NN*64/8){
    const float4* p = (const float4*)(x + t*8);
    bf16x8 v = cvt8(p[0], p[1]);
    *(bf16x8*)(xb + t*8) = v;
  }
}

// W1T[n][k] = W1[k][n] (128x128), W2T[n][k] = W2[k][n] (64x128), bf16
__global__ __launch_bounds__(256) void k_prep_w(const float* __restrict__ W1,
                                                const float* __restrict__ W2,
                                                unsigned short* __restrict__ W1T,
                                                unsigned short* __restrict__ W2T){
  for (int i = threadIdx.x; i < 128*128; i += 256){
    int n = i >> 7, k = i & 127;
    W1T[i] = f2bf(W1[k*128 + n]);
  }
  for (int i = threadIdx.x; i < 64*128; i += 256){
    int n = i >> 7, k = i & 127;
    W2T[i] = f2bf(W2[k*64 + n]);
  }
}

// W3T hi/lo [256][160] from W3[160][256]; W4T hi/lo [128][256] from W4[256][128]
__global__ __launch_bounds__(256) void k_prep_w34(const float* __restrict__ W3,
                                                  const float* __restrict__ W4,
                                                  unsigned short* __restrict__ W3Th,
                                                  unsigned short* __restrict__ W3Tl,
                                                  unsigned short* __restrict__ W4Th,
                                                  unsigned short* __restrict__ W4Tl){
  int b = blockIdx.x;
  if (b < 256){
    int n = b;
    for (int k = threadIdx.x; k < 160; k += 256){
      float w = W3[k*256 + n];
      unsigned h = f2bf(w);
      float fh = __uint_as_float(h << 16);
      W3Th[n*160 + k] = (unsigned short)h;
      W3Tl[n*160 + k] = f2bf(w - fh);
    }
  } else {
    int n = b - 256;            // < 128
    int k = threadIdx.x;        // 256 threads, K=256
    float w = W4[k*128 + n];
    unsigned h = f2bf(w);
    float fh = __uint_as_float(h << 16);
    W4Th[n*256 + k] = (unsigned short)h;
    W4Tl[n*256 + k] = f2bf(w - fh);
  }
}

// ================= CSR construction =================
__global__ __launch_bounds__(256) void k_hist(const int* __restrict__ ei, int* __restrict__ cnt){
  int e = blockIdx.x*256 + threadIdx.x;
  if (e < EE) atomicAdd(&cnt[ei[EE + e]], 1);
}

__global__ __launch_bounds__(256) void k_scan1(const int* __restrict__ cnt,
                                               int* __restrict__ offs,
                                               int* __restrict__ partials){
  __shared__ int sdata[256];
  const int t = threadIdx.x, b = blockIdx.x;
  const int base = b*1024 + t*4;
  int v0 = (base+0 < NN) ? cnt[base+0] : 0;
  int v1 = (base+1 < NN) ? cnt[base+1] : 0;
  int v2 = (base+2 < NN) ? cnt[base+2] : 0;
  int v3 = (base+3 < NN) ? cnt[base+3] : 0;
  int tsum = v0+v1+v2+v3;
  sdata[t] = tsum;
  __syncthreads();
  for (int off=1; off<256; off<<=1){
    int add = (t >= off) ? sdata[t-off] : 0;
    __syncthreads();
    sdata[t] += add;
    __syncthreads();
  }
  int run = sdata[t] - tsum;
  if (base+0 < NN) offs[base+0] = run;  run += v0;
  if (base+1 < NN) offs[base+1] = run;  run += v1;
  if (base+2 < NN) offs[base+2] = run;  run += v2;
  if (base+3 < NN) offs[base+3] = run;
  if (t == 255) partials[b] = sdata[255];
}

__global__ __launch_bounds__(64) void k_scan2(int* __restrict__ partials){
  int l = threadIdx.x;
  int v = (l < NB) ? partials[l] : 0;
  int inc = v;
  #pragma unroll
  for (int off=1; off<64; off<<=1){
    int t = __shfl_up(inc, off);
    if (l >= off) inc += t;
  }
  if (l < NB) partials[l] = inc - v;
}

__global__ __launch_bounds__(256) void k_scan3(int* __restrict__ offs,
                                               const int* __restrict__ partials,
                                               int* __restrict__ cursor){
  const int t = threadIdx.x, b = blockIdx.x;
  const int base = b*1024 + t*4;
  int add = partials[b];
  #pragma unroll
  for (int k=0;k<4;k++){
    int i = base + k;
    if (i < NN){ int o = offs[i] + add; offs[i] = o; cursor[i] = o; }
  }
}

// inverse permutation: epos[e] = CSR slot of edge e  (coalesced write)
__global__ __launch_bounds__(256) void k_fill(const int* __restrict__ ei,
                                              int* __restrict__ cursor,
                                              int* __restrict__ epos){
  int e = blockIdx.x*256 + threadIdx.x;
  if (e < EE){
    int c = ei[EE + e];
    epos[e] = atomicAdd(&cursor[c], 1);
  }
}

// ---------------- kernel 2: edge MLP via MFMA -> h_ws (bf16, CSR-ordered) ----------------
#define H1STR 132
__global__ __launch_bounds__(256, 4) void k_edge(const int* __restrict__ ei,
    const float* __restrict__ ea,
    const unsigned short* __restrict__ xb,
    const unsigned short* __restrict__ W1T, const float* __restrict__ b1,
    const float* __restrict__ g1, const float* __restrict__ be1,
    const unsigned short* __restrict__ W2T, const float* __restrict__ b2,
    const int* __restrict__ epos,
    unsigned short* __restrict__ h_ws){
  __shared__ __align__(16) float h1[64*H1STR];   // 33,792 B
  __shared__ int rows_l[64];
  __shared__ int slot_l[64];
  const int tid  = threadIdx.x;
  const int base = blockIdx.x * 64;
  const int wv   = tid >> 6;        // wave 0..3
  const int lane = tid & 63;
  const int quad = lane >> 4;       // 0..3
  const int l16  = lane & 15;
  if (tid < 64) rows_l[tid] = ei[base + tid];
  if (tid >= 128 && tid < 192) slot_l[tid-128] = epos[base + tid - 128];
  __syncthreads();
  // ---- GEMM1: wave wv owns n-groups {2wv, 2wv+1}, all 4 m-groups ----
  {
    int rw[4];
    #pragma unroll
    for (int m=0;m<4;m++) rw[m] = rows_l[m*16 + l16];
    f32x4 acc[4][2];
    #pragma unroll
    for (int m=0;m<4;m++){ acc[m][0] = (f32x4){0.f,0.f,0.f,0.f}; acc[m][1] = (f32x4){0.f,0.f,0.f,0.f}; }
    #pragma unroll
    for (int ks=0; ks<4; ks++){
      bf16x8 af[4];
      if (ks < 2){
        #pragma unroll
        for (int m=0;m<4;m++)
          af[m] = *(const bf16x8*)(xb + (size_t)rw[m]*64 + ks*32 + quad*8);
      } else {
        #pragma unroll
        for (int m=0;m<4;m++){
          const float* p = ea + (size_t)(base + m*16 + l16)*64 + (ks-2)*32 + quad*8;
          af[m] = cvt8(*(const float4*)p, *(const float4*)(p+4));
        }
      }
      bf16x8 bf0 = *(const bf16x8*)(W1T + (size_t)((2*wv+0)*16 + l16)*128 + ks*32 + quad*8);
      bf16x8 bf1 = *(const bf16x8*)(W1T + (size_t)((2*wv+1)*16 + l16)*128 + ks*32 + quad*8);
      #pragma unroll
      for (int m=0;m<4;m++){
        acc[m][0] = __builtin_amdgcn_mfma_f32_16x16x32_bf16(af[m], bf0, acc[m][0], 0, 0, 0);
        acc[m][1] = __builtin_amdgcn_mfma_f32_16x16x32_bf16(af[m], bf1, acc[m][1], 0, 0, 0);
      }
    }
    #pragma unroll
    for (int nl=0; nl<2; nl++){
      float b1c = b1[(2*wv+nl)*16 + l16];
      #pragma unroll
      for (int m=0;m<4;m++){
        #pragma unroll
        for (int r=0;r<4;r++)
          h1[(m*16 + quad*4 + r)*H1STR + (2*wv+nl)*16 + l16] = acc[m][nl][r] + b1c;
      }
    }
  }
  __syncthreads();
  // ---- LayerNorm(128) + ReLU ----
  {
    const float gA = g1[lane], gB = g1[lane+64];
    const float bA = be1[lane], bB = be1[lane+64];
    for (int r = wv*16; r < wv*16 + 16; ++r){
      float a = h1[r*H1STR + lane];
      float b = h1[r*H1STR + 64 + lane];
      float s = a + b, ss = fmaf(a,a,b*b);
      #pragma unroll
      for (int off=32; off; off>>=1){
        s  += __shfl_xor(s, off);
        ss += __shfl_xor(ss, off);
      }
      float mean = s * (1.0f/128.0f);
      float var  = ss * (1.0f/128.0f) - mean*mean;
      float inv = rsqrtf(var + 1e-5f);
      h1[r*H1STR + lane]      = fmaxf(fmaf((a-mean)*inv, gA, bA), 0.f);
      h1[r*H1STR + 64 + lane] = fmaxf(fmaf((b-mean)*inv, gB, bB), 0.f);
    }
  }
  __syncthreads();
  // ---- GEMM2 ----
  {
    f32x4 acc2[4];
    #pragma unroll
    for (int m=0;m<4;m++) acc2[m] = (f32x4){0.f,0.f,0.f,0.f};
    #pragma unroll
    for (int ks=0; ks<4; ks++){
      bf16x8 bfr = *(const bf16x8*)(W2T + (size_t)(wv*16 + l16)*128 + ks*32 + quad*8);
      #pragma unroll
      for (int m=0;m<4;m++){
        const float* p = h1 + (m*16 + l16)*H1STR + ks*32 + quad*8;
        bf16x8 af = cvt8(*(const float4*)p, *(const float4*)(p+4));
        acc2[m] = __builtin_amdgcn_mfma_f32_16x16x32_bf16(af, bfr, acc2[m], 0, 0, 0);
      }
    }
    float b2c = b2[wv*16 + l16];
    #pragma unroll
    for (int m=0;m<4;m++){
      #pragma unroll
      for (int r=0;r<4;r++)
        h_ws[(size_t)slot_l[m*16 + quad*4 + r]*64 + wv*16 + l16] = f2bf(acc2[m][r] + b2c);
    }
  }
}

// ---------------- kernel 2.5: streaming aggregation -> packed z (global) ----------------
// 8 threads per node. No LDS, no barriers: pure BW kernel, fully resident.
__global__ __launch_bounds__(256, 8) void k_agg(const float* __restrict__ x,
    const float* __restrict__ u, const int* __restrict__ batch,
    const unsigned short* __restrict__ h_ws, const int* __restrict__ cnt,
    const int* __restrict__ offs, unsigned* __restrict__ zg){
  int t = blockIdx.x*256 + threadIdx.x;
  int n = t >> 3, p = t & 7;
  if (n >= NN) return;
  unsigned* zr = zg + (size_t)n*160;
  // x: cols p*8 .. p*8+7
  {
    const float4* xp = (const float4*)(x + (size_t)n*64 + p*8);
    *(uint4*)(zr + p*8)     = pack4(xp[0]);
    *(uint4*)(zr + p*8 + 4) = pack4(xp[1]);
  }
  // u: cols 128 + p*4 .. +3
  {
    const float4* up = (const float4*)(u + (size_t)batch[n]*32 + p*4);
    *(uint4*)(zr + 128 + p*4) = pack4(up[0]);
  }
  // aggregation over CSR-contiguous bf16 rows
  float a0=0.f,a1=0.f,a2=0.f,a3=0.f,a4=0.f,a5=0.f,a6=0.f,a7=0.f;
  int deg = cnt[n];
  const unsigned short* hp = h_ws + (size_t)offs[n]*64 + p*8;
  int j = 0;
  for (; j + 4 <= deg; j += 4){
    uint4 v0 = *(const uint4*)(hp);
    uint4 v1 = *(const uint4*)(hp + 64);
    uint4 v2 = *(const uint4*)(hp + 128);
    uint4 v3 = *(const uint4*)(hp + 192);
    hp += 256;
    a0 += blo(v0.x); a1 += bhi(v0.x); a2 += blo(v0.y); a3 += bhi(v0.y);
    a4 += blo(v0.z); a5 += bhi(v0.z); a6 += blo(v0.w); a7 += bhi(v0.w);
    a0 += blo(v1.x); a1 += bhi(v1.x); a2 += blo(v1.y); a3 += bhi(v1.y);
    a4 += blo(v1.z); a5 += bhi(v1.z); a6 += blo(v1.w); a7 += bhi(v1.w);
    a0 += blo(v2.x); a1 += bhi(v2.x); a2 += blo(v2.y); a3 += bhi(v2.y);
    a4 += blo(v2.z); a5 += bhi(v2.z); a6 += blo(v2.w); a7 += bhi(v2.w);
    a0 += blo(v3.x); a1 += bhi(v3.x); a2 += blo(v3.y); a3 += bhi(v3.y);
    a4 += blo(v3.z); a5 += bhi(v3.z); a6 += blo(v3.w); a7 += bhi(v3.w);
  }
  for (; j < deg; ++j){
    uint4 v = *(const uint4*)(hp);
    hp += 64;
    a0 += blo(v.x); a1 += bhi(v.x); a2 += blo(v.y); a3 += bhi(v.y);
    a4 += blo(v.z); a5 += bhi(v.z); a6 += blo(v.w); a7 += bhi(v.w);
  }
  float rc = 1.0f / fmaxf((float)deg, 1.0f);
  *(uint4*)(zr + 64 + p*8)     = pack4(make_float4(a0*rc, a1*rc, a2*rc, a3*rc));
  *(uint4*)(zr + 64 + p*8 + 4) = pack4(make_float4(a4*rc, a5*rc, a6*rc, a7*rc));
}

// ---------------- kernel 3: node MLP (MFMA hi/lo) + heads + reparam ----------------
// 256 threads / 64 nodes per block: weight traffic per node cut 4x vs R5.
// Wave wv: GEMM1 n-tiles wv*4..+3 x m-tiles 0..3; GEMM2 n-tiles wv*2..+1 x m 0..3.
#define T2STR 132
#define ZSSTR 36
#define H3STR 260   // h3 stride (f32 / packed u32 elems), 16B-aligned rows
__global__ __launch_bounds__(256, 2) void k_node(const unsigned* __restrict__ zg,
    const unsigned short* __restrict__ W3Th, const unsigned short* __restrict__ W3Tl,
    const float* __restrict__ b3,
    const float* __restrict__ g3, const float* __restrict__ be3,
    const unsigned short* __restrict__ W4Th, const unsigned short* __restrict__ W4Tl,
    const float* __restrict__ b4,
    const float* __restrict__ g4, const float* __restrict__ be4,
    const float* __restrict__ Wm, const float* __restrict__ bm,
    const float* __restrict__ Wv, const float* __restrict__ bv,
    const float* __restrict__ Wx, const float* __restrict__ bx,
    float* __restrict__ out){
  // arena (66,560 B): phase1 h3[64][H3STR] fp32 -> packed u32 in place.
  // After GEMM2 (reg-resident) t2[64][T2STR] fp32 overwrites [0,33792);
  // hm[64][64] at 33792; zs[64][ZSSTR] at 50176.
  __shared__ __align__(16) char arena[64*H3STR*4];
  float*    h3f = (float*)arena;
  unsigned* h3p = (unsigned*)arena;
  float*    t2S = (float*)arena;
  float*    hmS = (float*)(arena + 33792);
  float*    zsS = (float*)(arena + 50176);

  const int tid = threadIdx.x;
  const int base = blockIdx.x * 64;
  const int wv   = tid >> 6;        // 0..3
  const int lane = tid & 63;
  const int quad = lane >> 4;
  const int l16  = lane & 15;

  // ---- GEMM1 (MFMA): C[64x256] = Z[64x160] @ W3, hi/lo compensated; A from global zg ----
  {
    f32x4 acc[4][4];   // [m-tile][n]
    #pragma unroll
    for (int m=0;m<4;m++)
      #pragma unroll
      for (int i=0;i<4;i++) acc[m][i] = (f32x4){0.f,0.f,0.f,0.f};
    #pragma unroll
    for (int ks=0; ks<5; ks++){
      bf16x8 ah[4], al[4];
      #pragma unroll
      for (int m=0;m<4;m++){
        const unsigned* az = zg + (size_t)(base + m*16 + l16)*160 + ks*32 + quad*8;
        uint4 p0 = *(const uint4*)az;
        uint4 p1 = *(const uint4*)(az + 4);
        unpack8(p0, p1, ah[m], al[m]);
      }
      #pragma unroll
      for (int i=0;i<4;i++){
        int nt = wv*4 + i;
        bf16x8 bh = *(const bf16x8*)(W3Th + (size_t)(nt*16 + l16)*160 + ks*32 + quad*8);
        bf16x8 bl = *(const bf16x8*)(W3Tl + (size_t)(nt*16 + l16)*160 + ks*32 + quad*8);
        #pragma unroll
        for (int m=0;m<4;m++){
          acc[m][i] = __builtin_amdgcn_mfma_f32_16x16x32_bf16(ah[m], bh, acc[m][i], 0, 0, 0);
          acc[m][i] = __builtin_amdgcn_mfma_f32_16x16x32_bf16(al[m], bh, acc[m][i], 0, 0, 0);
          acc[m][i] = __builtin_amdgcn_mfma_f32_16x16x32_bf16(ah[m], bl, acc[m][i], 0, 0, 0);
        }
      }
    }
    #pragma unroll
    for (int i=0;i<4;i++){
      int nt = wv*4 + i;
      float bc = b3[nt*16 + l16];
      #pragma unroll
      for (int m=0;m<4;m++)
        #pragma unroll
        for (int r=0;r<4;r++)
          h3f[(m*16 + quad*4 + r)*H3STR + nt*16 + l16] = acc[m][i][r] + bc;
    }
  }
  __syncthreads();   // B1a
  // ---- LN(256)+ReLU, pack hi/lo in place (16 rows per wave) ----
  {
    float4 gg  = *(const float4*)(g3 + lane*4);
    float4 bet = *(const float4*)(be3 + lane*4);
    #pragma unroll
    for (int r=0;r<16;r++){
      int row = wv*16 + r;
      float4 v = *(const float4*)(h3f + row*H3STR + lane*4);
      float s  = v.x + v.y + v.z + v.w;
      float ss = fmaf(v.x,v.x, fmaf(v.y,v.y, fmaf(v.z,v.z, v.w*v.w)));
      #pragma unroll
      for (int off=32; off; off>>=1){ s += __shfl_xor(s,off); ss += __shfl_xor(ss,off); }
      float mean = s * (1.0f/256.0f);
      float inv  = rsqrtf(ss*(1.0f/256.0f) - mean*mean + 1e-5f);
      float4 o;
      o.x = fmaxf(fmaf((v.x-mean)*inv, gg.x, bet.x), 0.f);
      o.y = fmaxf(fmaf((v.y-mean)*inv, gg.y, bet.y), 0.f);
      o.z = fmaxf(fmaf((v.z-mean)*inv, gg.z, bet.z), 0.f);
      o.w = fmaxf(fmaf((v.w-mean)*inv, gg.w, bet.w), 0.f);
      *(uint4*)(h3p + row*H3STR + lane*4) = pack4(o);
    }
  }
  __syncthreads();   // B1b
  // ---- GEMM2 (MFMA): C2[64x128] = H3[64x256] @ W4, hi/lo; results in regs, then t2 overwrites arena ----
  {
    f32x4 acc2[4][2];
    #pragma unroll
    for (int m=0;m<4;m++){ acc2[m][0] = (f32x4){0.f,0.f,0.f,0.f}; acc2[m][1] = (f32x4){0.f,0.f,0.f,0.f}; }
    #pragma unroll
    for (int ks=0; ks<8; ks++){
      bf16x8 ah[4], al[4];
      #pragma unroll
      for (int m=0;m<4;m++){
        const unsigned* ap = h3p + (m*16 + l16)*H3STR + ks*32 + quad*8;
        uint4 p0 = *(const uint4*)ap;
        uint4 p1 = *(const uint4*)(ap + 4);
        unpack8(p0, p1, ah[m], al[m]);
      }
      #pragma unroll
      for (int i=0;i<2;i++){
        int nt = wv*2 + i;
        bf16x8 bh = *(const bf16x8*)(W4Th + (size_t)(nt*16 + l16)*256 + ks*32 + quad*8);
        bf16x8 bl = *(const bf16x8*)(W4Tl + (size_t)(nt*16 + l16)*256 + ks*32 + quad*8);
        #pragma unroll
        for (int m=0;m<4;m++){
          acc2[m][i] = __builtin_amdgcn_mfma_f32_16x16x32_bf16(ah[m], bh, acc2[m][i], 0, 0, 0);
          acc2[m][i] = __builtin_amdgcn_mfma_f32_16x16x32_bf16(al[m], bh, acc2[m][i], 0, 0, 0);
          acc2[m][i] = __builtin_amdgcn_mfma_f32_16x16x32_bf16(ah[m], bl, acc2[m][i], 0, 0, 0);
        }
      }
    }
    __syncthreads();   // B2w: all waves done reading h3p; arena reusable
    #pragma unroll
    for (int i=0;i<2;i++){
      int nt = wv*2 + i;
      float bc = b4[nt*16 + l16];
      #pragma unroll
      for (int m=0;m<4;m++)
        #pragma unroll
        for (int r=0;r<4;r++)
          t2S[(m*16 + quad*4 + r)*T2STR + nt*16 + l16] = acc2[m][i][r] + bc;
    }
  }
  __syncthreads();   // B2a
  // ---- LN(128)+ReLU in place (fp32) ----
  {
    const int jq = tid & 31, rb = tid >> 5;   // rb 0..7
    float4 gg  = *(const float4*)(g4 + 4*jq);
    float4 bet = *(const float4*)(be4 + 4*jq);
    #pragma unroll
    for (int r=0;r<8;r++){
      int row = rb*8 + r;
      float4 v = *(const float4*)(t2S + row*T2STR + 4*jq);
      float s  = v.x + v.y + v.z + v.w;
      float ss = fmaf(v.x,v.x, fmaf(v.y,v.y, fmaf(v.z,v.z, v.w*v.w)));
      #pragma unroll
      for (int off=16; off; off>>=1){ s += __shfl_xor(s,off); ss += __shfl_xor(ss,off); }
      float mean = s * (1.0f/128.0f);
      float inv  = rsqrtf(ss*(1.0f/128.0f) - mean*mean + 1e-5f);
      float4 o;
      o.x = fmaxf(fmaf((v.x-mean)*inv, gg.x, bet.x), 0.f);
      o.y = fmaxf(fmaf((v.y-mean)*inv, gg.y, bet.y), 0.f);
      o.z = fmaxf(fmaf((v.z-mean)*inv, gg.z, bet.z), 0.f);
      o.w = fmaxf(fmaf((v.w-mean)*inv, gg.w, bet.w), 0.f);
      *(float4*)(t2S + row*T2STR + 4*jq) = o;
    }
  }
  __syncthreads();   // B2b
  // ---- heads: mu | lv  (fp32 VALU) ----
  {
    const int jq = tid & 15, rb = tid >> 4;   // rb 0..15, 4 rows each
    const float* Wp = (jq < 8) ? Wm : Wv;
    const int cq = (jq & 7) * 4;
    float4 acc[4];
    #pragma unroll
    for (int r=0;r<4;r++) acc[r] = make_float4(0.f,0.f,0.f,0.f);
    #pragma unroll 2
    for (int k=0;k<128;k+=4){
      float4 w0 = *(const float4*)(Wp + (k+0)*32 + cq);
      float4 w1 = *(const float4*)(Wp + (k+1)*32 + cq);
      float4 w2 = *(const float4*)(Wp + (k+2)*32 + cq);
      float4 w3 = *(const float4*)(Wp + (k+3)*32 + cq);
      #pragma unroll
      for (int r=0;r<4;r++){
        float4 z = *(const float4*)(t2S + (rb*4+r)*T2STR + k);
        fma4(acc[r], z.x, w0); fma4(acc[r], z.y, w1);
        fma4(acc[r], z.z, w2); fma4(acc[r], z.w, w3);
      }
    }
    const float* bp = (jq < 8) ? bm : bv;
    float4 bb = *(const float4*)(bp + cq);
    const long long sec = (jq < 8) ? (long long)NN*64 : ((long long)NN*64 + (long long)NN*32);
    #pragma unroll
    for (int r=0;r<4;r++){
      float4 v = acc[r];
      v.x += bb.x; v.y += bb.y; v.z += bb.z; v.w += bb.w;
      int rr = rb*4 + r;
      *(float4*)(hmS + rr*64 + ((jq<8)?0:32) + cq) = v;
      int n = base + rr;
      if (n < NN) *(float4*)(out + sec + (long long)n*32 + cq) = v;
    }
  }
  __syncthreads();   // B3
  // ---- reparameterize (64 rows x 32 = 2048 elems, 256 threads x 8) ----
  #pragma unroll
  for (int i=0;i<8;i++){
    int l = tid + 256*i;
    int r = l >> 5, jj = l & 31;
    float mu = hmS[r*64 + jj];
    float lv = hmS[r*64 + 32 + jj];
    unsigned idx = (unsigned)((base + r)*32 + jj);
    float e = eps_at(idx);
    zsS[r*ZSSTR + jj] = fmaf(e, expf(0.5f*lv), mu);
  }
  __syncthreads();   // B4
  // ---- out = zs @ Wx + bx (fp32 VALU) ----
  {
    const int jq = tid & 15, rb = tid >> 4;   // rb 0..15, 4 rows each
    float4 acc[4];
    #pragma unroll
    for (int r=0;r<4;r++) acc[r] = make_float4(0.f,0.f,0.f,0.f);
    #pragma unroll
    for (int k=0;k<32;k+=4){
      float4 w0 = *(const float4*)(Wx + (k+0)*64 + 4*jq);
      float4 w1 = *(const float4*)(Wx + (k+1)*64 + 4*jq);
      float4 w2 = *(const float4*)(Wx + (k+2)*64 + 4*jq);
      float4 w3 = *(const float4*)(Wx + (k+3)*64 + 4*jq);
      #pragma unroll
      for (int r=0;r<4;r++){
        float4 z = *(const float4*)(zsS + (rb*4+r)*ZSSTR + k);
        fma4(acc[r], z.x, w0); fma4(acc[r], z.y, w1);
        fma4(acc[r], z.z, w2); fma4(acc[r], z.w, w3);
      }
    }
    float4 bb = *(const float4*)(bx + 4*jq);
    #pragma unroll
    for (int r=0;r<4;r++){
      int n = base + rb*4 + r;
      if (n < NN){
        float4 v = acc[r];
        v.x += bb.x; v.y += bb.y; v.z += bb.z; v.w += bb.w;
        *(float4*)(out + (long long)n*64 + 4*jq) = v;
      }
    }
  }
}

extern "C" void kernel_launch(void* const* d_in, const int* in_sizes, int n_in,
                              void* d_out, int out_size, void* d_ws, size_t ws_size,
                              hipStream_t stream) {
  const float* x     = (const float*)d_in[0];
  const int*   ei    = (const int*)d_in[1];
  const float* ea    = (const float*)d_in[2];
  const float* u     = (const float*)d_in[3];
  const int*   batch = (const int*)d_in[4];
  const float* W1 = (const float*)d_in[6];
  const float* b1 = (const float*)d_in[7];
  const float* g1 = (const float*)d_in[8];
  const float* be1= (const float*)d_in[9];
  const float* W2 = (const float*)d_in[10];
  const float* b2 = (const float*)d_in[11];
  const float* W3 = (const float*)d_in[12];
  const float* b3 = (const float*)d_in[13];
  const float* g3 = (const float*)d_in[14];
  const float* be3= (const float*)d_in[15];
  const float* W4 = (const float*)d_in[16];
  const float* b4 = (const float*)d_in[17];
  const float* g4 = (const float*)d_in[18];
  const float* be4= (const float*)d_in[19];
  const float* Wm = (const float*)d_in[20];
  const float* bm = (const float*)d_in[21];
  const float* Wv = (const float*)d_in[22];
  const float* bv = (const float*)d_in[23];
  const float* Wx = (const float*)d_in[24];
  const float* bx = (const float*)d_in[25];

  char* W = (char*)d_ws;
  size_t off = 0;
  unsigned short* h_ws = (unsigned short*)(W + off); off += (size_t)EE*64*2;  // 51.2 MB bf16
  int* cnt      = (int*)(W + off);  off += (size_t)NN*4;
  int* offs     = (int*)(W + off);  off += (size_t)NN*4;
  int* cursor   = (int*)(W + off);  off += (size_t)NN*4;
  int* epos     = (int*)(W + off);  off += (size_t)EE*4;
  int* partials = (int*)(W + off);  off += 256;
  unsigned short* xb  = (unsigned short*)(W + off); off += (size_t)NN*64*2;  // 6.4 MB
  unsigned short* W1T = (unsigned short*)(W + off); off += 128*128*2;
  unsigned short* W2T = (unsigned short*)(W + off); off += 64*128*2;
  unsigned short* W3Th = (unsigned short*)(W + off); off += 256*160*2;
  unsigned short* W3Tl = (unsigned short*)(W + off); off += 256*160*2;
  unsigned short* W4Th = (unsigned short*)(W + off); off += 128*256*2;
  unsigned short* W4Tl = (unsigned short*)(W + off); off += 128*256*2;
  off = (off + 255) & ~(size_t)255;
  unsigned* zg = (unsigned*)(W + off); off += (size_t)(NN + 64)*160*4;       // packed z (+pad rows)
  float* out = (float*)d_out;

  hipMemsetAsync(cnt, 0, (size_t)NN*sizeof(int), stream);

  k_prep_x<<<(NN*64/8 + 255)/256, 256, 0, stream>>>(x, xb);
  k_prep_w<<<1, 256, 0, stream>>>(W1, W2, W1T, W2T);
  k_prep_w34<<<384, 256, 0, stream>>>(W3, W4, W3Th, W3Tl, W4Th, W4Tl);
  k_hist <<<(EE+255)/256, 256, 0, stream>>>(ei, cnt);
  k_scan1<<<NB, 256, 0, stream>>>(cnt, offs, partials);
  k_scan2<<<1, 64, 0, stream>>>(partials);
  k_scan3<<<NB, 256, 0, stream>>>(offs, partials, cursor);
  k_fill <<<(EE+255)/256, 256, 0, stream>>>(ei, cursor, epos);

  k_edge<<<EE/64, 256, 0, stream>>>(ei, ea, xb, W1T, b1, g1, be1, W2T, b2, epos, h_ws);
  k_agg <<<(NN*8 + 255)/256, 256, 0, stream>>>(x, u, batch, h_ws, cnt, offs, zg);
  k_node<<<(NN+63)/64, 256, 0, stream>>>(zg,
                                         W3Th, W3Tl, b3, g3, be3,
                                         W4Th, W4Tl, b4, g4, be4,
                                         Wm,bm, Wv,bv, Wx,bx, out);
}

// Round 8
// 484.021 us; speedup vs baseline: 1.2102x; 1.0227x over previous
//
#include <hip/hip_runtime.h>

#define NN 50000
#define EE 400000
#define NB 49   // ceil(NN/1024) scan blocks

typedef __attribute__((ext_vector_type(8))) short bf16x8;
typedef __attribute__((ext_vector_type(4))) float f32x4;

__device__ __forceinline__ void fma4(float4& a, float s, const float4& w){
  a.x = fmaf(s, w.x, a.x);
  a.y = fmaf(s, w.y, a.y);
  a.z = fmaf(s, w.z, a.z);
  a.w = fmaf(s, w.w, a.w);
}

__device__ __forceinline__ unsigned short f2bf(float f){
  unsigned u = __float_as_uint(f);
  unsigned r = (u + 0x7fffu + ((u >> 16) & 1u)) >> 16;   // RNE
  return (unsigned short)r;
}

// HW packed bf16 convert (RNE on gfx950): dst = [bf16(hi)<<16 | bf16(lo)]
__device__ __forceinline__ unsigned cvtpk(float lo, float hi){
  unsigned r;
  asm("v_cvt_pk_bf16_f32 %0, %1, %2" : "=v"(r) : "v"(lo), "v"(hi));
  return r;
}

// 8 fp32 -> bf16x8 via 4 cvt_pk (replaces 8x f2bf bit-twiddle)
__device__ __forceinline__ bf16x8 cvt8pk(float4 a, float4 b){
  union { unsigned u[4]; bf16x8 v; } r;
  r.u[0] = cvtpk(a.x, a.y);
  r.u[1] = cvtpk(a.z, a.w);
  r.u[2] = cvtpk(b.x, b.y);
  r.u[3] = cvtpk(b.z, b.w);
  return r.v;
}

// fp32x4 -> packed (hi<<16|lo) u32x4 via cvt_pk + v_perm
__device__ __forceinline__ uint4 pack4pk(float4 v){
  unsigned h01 = cvtpk(v.x, v.y);
  unsigned h23 = cvtpk(v.z, v.w);
  float f0 = __uint_as_float(h01 << 16);
  float f1 = __uint_as_float(h01 & 0xffff0000u);
  float f2 = __uint_as_float(h23 << 16);
  float f3 = __uint_as_float(h23 & 0xffff0000u);
  unsigned l01 = cvtpk(v.x - f0, v.y - f1);
  unsigned l23 = cvtpk(v.z - f2, v.w - f3);
  uint4 p;
  p.x = __builtin_amdgcn_perm(h01, l01, 0x05040100u);  // [h.lo16 | l.lo16]
  p.y = __builtin_amdgcn_perm(h01, l01, 0x07060302u);  // [h.hi16 | l.hi16]
  p.z = __builtin_amdgcn_perm(h23, l23, 0x05040100u);
  p.w = __builtin_amdgcn_perm(h23, l23, 0x07060302u);
  return p;
}

// packed u32x8 -> hi/lo bf16x8 via 8 v_perm (replaces shift/mask unpack)
__device__ __forceinline__ void unpack8pk(uint4 p0, uint4 p1, bf16x8& hi, bf16x8& lo){
  union { unsigned u[4]; bf16x8 v; } H, L;
  H.u[0] = __builtin_amdgcn_perm(p0.y, p0.x, 0x07060302u);
  L.u[0] = __builtin_amdgcn_perm(p0.y, p0.x, 0x05040100u);
  H.u[1] = __builtin_amdgcn_perm(p0.w, p0.z, 0x07060302u);
  L.u[1] = __builtin_amdgcn_perm(p0.w, p0.z, 0x05040100u);
  H.u[2] = __builtin_amdgcn_perm(p1.y, p1.x, 0x07060302u);
  L.u[2] = __builtin_amdgcn_perm(p1.y, p1.x, 0x05040100u);
  H.u[3] = __builtin_amdgcn_perm(p1.w, p1.z, 0x07060302u);
  L.u[3] = __builtin_amdgcn_perm(p1.w, p1.z, 0x05040100u);
  hi = H.v; lo = L.v;
}

// bf16-pair helpers for reading h_ws (bf16) as fp32
__device__ __forceinline__ float blo(unsigned u){ return __uint_as_float(u << 16); }
__device__ __forceinline__ float bhi(unsigned u){ return __uint_as_float(u & 0xffff0000u); }

__device__ __forceinline__ unsigned rotl32(unsigned v, int d){ return (v<<d)|(v>>(32-d)); }

// jax.random.normal(key(42)) under jax_threefry_partitionable: counter (0,idx), bits=x0^x1. Verified R3.
__device__ __forceinline__ float eps_at(unsigned idx){
  const unsigned k0 = 0u, k1 = 42u, k2 = 0x1BD11BDAu ^ 0u ^ 42u;
  unsigned x0 = 0u + k0, x1 = idx + k1;
  const int rotA[4] = {13,15,26,6};
  const int rotB[4] = {17,29,16,24};
  #pragma unroll
  for (int i=0;i<4;i++){ x0 += x1; x1 = rotl32(x1, rotA[i]); x1 ^= x0; }
  x0 += k1; x1 += k2 + 1u;
  #pragma unroll
  for (int i=0;i<4;i++){ x0 += x1; x1 = rotl32(x1, rotB[i]); x1 ^= x0; }
  x0 += k2; x1 += k0 + 2u;
  #pragma unroll
  for (int i=0;i<4;i++){ x0 += x1; x1 = rotl32(x1, rotA[i]); x1 ^= x0; }
  x0 += k0; x1 += k1 + 3u;
  #pragma unroll
  for (int i=0;i<4;i++){ x0 += x1; x1 = rotl32(x1, rotB[i]); x1 ^= x0; }
  x0 += k1; x1 += k2 + 4u;
  #pragma unroll
  for (int i=0;i<4;i++){ x0 += x1; x1 = rotl32(x1, rotA[i]); x1 ^= x0; }
  x0 += k2; x1 += k0 + 5u;
  unsigned bits = x0 ^ x1;
  float f = __uint_as_float((bits >> 9) | 0x3f800000u) - 1.0f;
  const float lo = -0.99999994f;
  float u = f * 2.0f + lo;
  u = fmaxf(u, lo);
  float w = -log1pf(-u*u);
  float p;
  if (w < 5.0f){
    w -= 2.5f;
    p = 2.81022636e-08f;
    p = fmaf(p,w, 3.43273939e-07f);
    p = fmaf(p,w,-3.5233877e-06f);
    p = fmaf(p,w,-4.39150654e-06f);
    p = fmaf(p,w, 0.00021858087f);
    p = fmaf(p,w,-0.00125372503f);
    p = fmaf(p,w,-0.00417768164f);
    p = fmaf(p,w, 0.246640727f);
    p = fmaf(p,w, 1.50140941f);
  } else {
    w = sqrtf(w) - 3.0f;
    p = -0.000200214257f;
    p = fmaf(p,w, 0.000100950558f);
    p = fmaf(p,w, 0.00134934322f);
    p = fmaf(p,w,-0.00367342844f);
    p = fmaf(p,w, 0.00573950773f);
    p = fmaf(p,w,-0.0076224613f);
    p = fmaf(p,w, 0.00943887047f);
    p = fmaf(p,w, 1.00167406f);
    p = fmaf(p,w, 2.83297682f);
  }
  return 1.41421356237f * (p * u);
}

// ================= prep: bf16 conversions =================
__global__ __launch_bounds__(256) void k_prep_x(const float* __restrict__ x,
                                                unsigned short* __restrict__ xb){
  int t = blockIdx.x*256 + threadIdx.x;           // one bf16x8 per thread
  if (t < NN*64/8){
    const float4* p = (const float4*)(x + t*8);
    bf16x8 v = cvt8pk(p[0], p[1]);
    *(bf16x8*)(xb + t*8) = v;
  }
}

// W1T[n][k] = W1[k][n] (128x128), W2T[n][k] = W2[k][n] (64x128), bf16
__global__ __launch_bounds__(256) void k_prep_w(const float* __restrict__ W1,
                                                const float* __restrict__ W2,
                                                unsigned short* __restrict__ W1T,
                                                unsigned short* __restrict__ W2T){
  for (int i = threadIdx.x; i < 128*128; i += 256){
    int n = i >> 7, k = i & 127;
    W1T[i] = f2bf(W1[k*128 + n]);
  }
  for (int i = threadIdx.x; i < 64*128; i += 256){
    int n = i >> 7, k = i & 127;
    W2T[i] = f2bf(W2[k*64 + n]);
  }
}

// W3T hi/lo [256][160] from W3[160][256]; W4T hi/lo [128][256] from W4[256][128]
__global__ __launch_bounds__(256) void k_prep_w34(const float* __restrict__ W3,
                                                  const float* __restrict__ W4,
                                                  unsigned short* __restrict__ W3Th,
                                                  unsigned short* __restrict__ W3Tl,
                                                  unsigned short* __restrict__ W4Th,
                                                  unsigned short* __restrict__ W4Tl){
  int b = blockIdx.x;
  if (b < 256){
    int n = b;
    for (int k = threadIdx.x; k < 160; k += 256){
      float w = W3[k*256 + n];
      unsigned h = f2bf(w);
      float fh = __uint_as_float(h << 16);
      W3Th[n*160 + k] = (unsigned short)h;
      W3Tl[n*160 + k] = f2bf(w - fh);
    }
  } else {
    int n = b - 256;            // < 128
    int k = threadIdx.x;        // 256 threads, K=256
    float w = W4[k*128 + n];
    unsigned h = f2bf(w);
    float fh = __uint_as_float(h << 16);
    W4Th[n*256 + k] = (unsigned short)h;
    W4Tl[n*256 + k] = f2bf(w - fh);
  }
}

// ================= CSR construction =================
__global__ __launch_bounds__(256) void k_hist(const int* __restrict__ ei, int* __restrict__ cnt){
  int e = blockIdx.x*256 + threadIdx.x;
  if (e < EE) atomicAdd(&cnt[ei[EE + e]], 1);
}

__global__ __launch_bounds__(256) void k_scan1(const int* __restrict__ cnt,
                                               int* __restrict__ offs,
                                               int* __restrict__ partials){
  __shared__ int sdata[256];
  const int t = threadIdx.x, b = blockIdx.x;
  const int base = b*1024 + t*4;
  int v0 = (base+0 < NN) ? cnt[base+0] : 0;
  int v1 = (base+1 < NN) ? cnt[base+1] : 0;
  int v2 = (base+2 < NN) ? cnt[base+2] : 0;
  int v3 = (base+3 < NN) ? cnt[base+3] : 0;
  int tsum = v0+v1+v2+v3;
  sdata[t] = tsum;
  __syncthreads();
  for (int off=1; off<256; off<<=1){
    int add = (t >= off) ? sdata[t-off] : 0;
    __syncthreads();
    sdata[t] += add;
    __syncthreads();
  }
  int run = sdata[t] - tsum;
  if (base+0 < NN) offs[base+0] = run;  run += v0;
  if (base+1 < NN) offs[base+1] = run;  run += v1;
  if (base+2 < NN) offs[base+2] = run;  run += v2;
  if (base+3 < NN) offs[base+3] = run;
  if (t == 255) partials[b] = sdata[255];
}

__global__ __launch_bounds__(64) void k_scan2(int* __restrict__ partials){
  int l = threadIdx.x;
  int v = (l < NB) ? partials[l] : 0;
  int inc = v;
  #pragma unroll
  for (int off=1; off<64; off<<=1){
    int t = __shfl_up(inc, off);
    if (l >= off) inc += t;
  }
  if (l < NB) partials[l] = inc - v;
}

__global__ __launch_bounds__(256) void k_scan3(int* __restrict__ offs,
                                               const int* __restrict__ partials,
                                               int* __restrict__ cursor){
  const int t = threadIdx.x, b = blockIdx.x;
  const int base = b*1024 + t*4;
  int add = partials[b];
  #pragma unroll
  for (int k=0;k<4;k++){
    int i = base + k;
    if (i < NN){ int o = offs[i] + add; offs[i] = o; cursor[i] = o; }
  }
}

// inverse permutation: epos[e] = CSR slot of edge e  (coalesced write)
__global__ __launch_bounds__(256) void k_fill(const int* __restrict__ ei,
                                              int* __restrict__ cursor,
                                              int* __restrict__ epos){
  int e = blockIdx.x*256 + threadIdx.x;
  if (e < EE){
    int c = ei[EE + e];
    epos[e] = atomicAdd(&cursor[c], 1);
  }
}

// ---------------- kernel 2: edge MLP via MFMA -> h_ws (bf16, CSR-ordered) ----------------
#define H1STR 132
__global__ __launch_bounds__(256, 4) void k_edge(const int* __restrict__ ei,
    const float* __restrict__ ea,
    const unsigned short* __restrict__ xb,
    const unsigned short* __restrict__ W1T, const float* __restrict__ b1,
    const float* __restrict__ g1, const float* __restrict__ be1,
    const unsigned short* __restrict__ W2T, const float* __restrict__ b2,
    const int* __restrict__ epos,
    unsigned short* __restrict__ h_ws){
  __shared__ __align__(16) float h1[64*H1STR];   // 33,792 B
  __shared__ int slot_l[64];
  const int tid  = threadIdx.x;
  const int base = blockIdx.x * 64;
  const int wv   = tid >> 6;        // wave 0..3
  const int lane = tid & 63;
  const int quad = lane >> 4;       // 0..3
  const int l16  = lane & 15;
  if (tid >= 128 && tid < 192) slot_l[tid-128] = epos[base + tid - 128];
  // (slot_l reads happen after B1/B2 barriers; no barrier needed here)
  // ---- GEMM1: wave wv owns n-groups {2wv, 2wv+1}, all 4 m-groups ----
  {
    int rw[4];
    #pragma unroll
    for (int m=0;m<4;m++) rw[m] = ei[base + m*16 + l16];   // direct, L1-coalesced
    f32x4 acc[4][2];
    #pragma unroll
    for (int m=0;m<4;m++){ acc[m][0] = (f32x4){0.f,0.f,0.f,0.f}; acc[m][1] = (f32x4){0.f,0.f,0.f,0.f}; }
    #pragma unroll
    for (int ks=0; ks<4; ks++){
      bf16x8 af[4];
      if (ks < 2){
        #pragma unroll
        for (int m=0;m<4;m++)
          af[m] = *(const bf16x8*)(xb + (size_t)rw[m]*64 + ks*32 + quad*8);
      } else {
        #pragma unroll
        for (int m=0;m<4;m++){
          const float* p = ea + (size_t)(base + m*16 + l16)*64 + (ks-2)*32 + quad*8;
          af[m] = cvt8pk(*(const float4*)p, *(const float4*)(p+4));
        }
      }
      bf16x8 bf0 = *(const bf16x8*)(W1T + (size_t)((2*wv+0)*16 + l16)*128 + ks*32 + quad*8);
      bf16x8 bf1 = *(const bf16x8*)(W1T + (size_t)((2*wv+1)*16 + l16)*128 + ks*32 + quad*8);
      #pragma unroll
      for (int m=0;m<4;m++){
        acc[m][0] = __builtin_amdgcn_mfma_f32_16x16x32_bf16(af[m], bf0, acc[m][0], 0, 0, 0);
        acc[m][1] = __builtin_amdgcn_mfma_f32_16x16x32_bf16(af[m], bf1, acc[m][1], 0, 0, 0);
      }
    }
    #pragma unroll
    for (int nl=0; nl<2; nl++){
      float b1c = b1[(2*wv+nl)*16 + l16];
      #pragma unroll
      for (int m=0;m<4;m++){
        #pragma unroll
        for (int r=0;r<4;r++)
          h1[(m*16 + quad*4 + r)*H1STR + (2*wv+nl)*16 + l16] = acc[m][nl][r] + b1c;
      }
    }
  }
  __syncthreads();   // B1
  // ---- LayerNorm(128) + ReLU ----
  {
    const float gA = g1[lane], gB = g1[lane+64];
    const float bA = be1[lane], bB = be1[lane+64];
    for (int r = wv*16; r < wv*16 + 16; ++r){
      float a = h1[r*H1STR + lane];
      float b = h1[r*H1STR + 64 + lane];
      float s = a + b, ss = fmaf(a,a,b*b);
      #pragma unroll
      for (int off=32; off; off>>=1){
        s  += __shfl_xor(s, off);
        ss += __shfl_xor(ss, off);
      }
      float mean = s * (1.0f/128.0f);
      float var  = ss * (1.0f/128.0f) - mean*mean;
      float inv = rsqrtf(var + 1e-5f);
      h1[r*H1STR + lane]      = fmaxf(fmaf((a-mean)*inv, gA, bA), 0.f);
      h1[r*H1STR + 64 + lane] = fmaxf(fmaf((b-mean)*inv, gB, bB), 0.f);
    }
  }
  __syncthreads();   // B2
  // ---- GEMM2 ----
  {
    f32x4 acc2[4];
    #pragma unroll
    for (int m=0;m<4;m++) acc2[m] = (f32x4){0.f,0.f,0.f,0.f};
    #pragma unroll
    for (int ks=0; ks<4; ks++){
      bf16x8 bfr = *(const bf16x8*)(W2T + (size_t)(wv*16 + l16)*128 + ks*32 + quad*8);
      #pragma unroll
      for (int m=0;m<4;m++){
        const float* p = h1 + (m*16 + l16)*H1STR + ks*32 + quad*8;
        bf16x8 af = cvt8pk(*(const float4*)p, *(const float4*)(p+4));
        acc2[m] = __builtin_amdgcn_mfma_f32_16x16x32_bf16(af, bfr, acc2[m], 0, 0, 0);
      }
    }
    float b2c = b2[wv*16 + l16];
    #pragma unroll
    for (int m=0;m<4;m++){
      #pragma unroll
      for (int r=0;r<4;r++)
        h_ws[(size_t)slot_l[m*16 + quad*4 + r]*64 + wv*16 + l16] = f2bf(acc2[m][r] + b2c);
    }
  }
}

// ---------------- kernel 2.5: streaming aggregation -> zg hi/lo bf16 planes ----------------
// 8 threads per node. No LDS, no barriers: pure BW kernel, fully resident.
__global__ __launch_bounds__(256, 8) void k_agg(const float* __restrict__ x,
    const float* __restrict__ u, const int* __restrict__ batch,
    const unsigned short* __restrict__ h_ws, const int* __restrict__ cnt,
    const int* __restrict__ offs,
    unsigned short* __restrict__ zgh, unsigned short* __restrict__ zgl){
  int t = blockIdx.x*256 + threadIdx.x;
  int n = t >> 3, p = t & 7;
  if (n >= NN) return;
  const size_t rb = (size_t)n*160;
  // x: cols p*8 .. p*8+7  (16B per plane)
  {
    const float4* xp = (const float4*)(x + (size_t)n*64 + p*8);
    float4 a = xp[0], b = xp[1];
    unsigned h0 = cvtpk(a.x,a.y), h1v = cvtpk(a.z,a.w), h2 = cvtpk(b.x,b.y), h3v = cvtpk(b.z,b.w);
    *(uint4*)(zgh + rb + p*8) = make_uint4(h0,h1v,h2,h3v);
    float4 fh0 = make_float4(__uint_as_float(h0<<16), __uint_as_float(h0&0xffff0000u),
                             __uint_as_float(h1v<<16), __uint_as_float(h1v&0xffff0000u));
    float4 fh1 = make_float4(__uint_as_float(h2<<16), __uint_as_float(h2&0xffff0000u),
                             __uint_as_float(h3v<<16), __uint_as_float(h3v&0xffff0000u));
    unsigned l0 = cvtpk(a.x-fh0.x, a.y-fh0.y), l1 = cvtpk(a.z-fh0.z, a.w-fh0.w);
    unsigned l2 = cvtpk(b.x-fh1.x, b.y-fh1.y), l3 = cvtpk(b.z-fh1.z, b.w-fh1.w);
    *(uint4*)(zgl + rb + p*8) = make_uint4(l0,l1,l2,l3);
  }
  // u: cols 128 + p*4 .. +3  (8B per plane)
  {
    const float4* up = (const float4*)(u + (size_t)batch[n]*32 + p*4);
    float4 a = up[0];
    unsigned h0 = cvtpk(a.x,a.y), h1v = cvtpk(a.z,a.w);
    *(uint2*)(zgh + rb + 128 + p*4) = make_uint2(h0,h1v);
    unsigned l0 = cvtpk(a.x-__uint_as_float(h0<<16), a.y-__uint_as_float(h0&0xffff0000u));
    unsigned l1 = cvtpk(a.z-__uint_as_float(h1v<<16), a.w-__uint_as_float(h1v&0xffff0000u));
    *(uint2*)(zgl + rb + 128 + p*4) = make_uint2(l0,l1);
  }
  // aggregation over CSR-contiguous bf16 rows
  float a0=0.f,a1=0.f,a2=0.f,a3=0.f,a4=0.f,a5=0.f,a6=0.f,a7=0.f;
  int deg = cnt[n];
  const unsigned short* hp = h_ws + (size_t)offs[n]*64 + p*8;
  int j = 0;
  for (; j + 4 <= deg; j += 4){
    uint4 v0 = *(const uint4*)(hp);
    uint4 v1 = *(const uint4*)(hp + 64);
    uint4 v2 = *(const uint4*)(hp + 128);
    uint4 v3 = *(const uint4*)(hp + 192);
    hp += 256;
    a0 += blo(v0.x); a1 += bhi(v0.x); a2 += blo(v0.y); a3 += bhi(v0.y);
    a4 += blo(v0.z); a5 += bhi(v0.z); a6 += blo(v0.w); a7 += bhi(v0.w);
    a0 += blo(v1.x); a1 += bhi(v1.x); a2 += blo(v1.y); a3 += bhi(v1.y);
    a4 += blo(v1.z); a5 += bhi(v1.z); a6 += blo(v1.w); a7 += bhi(v1.w);
    a0 += blo(v2.x); a1 += bhi(v2.x); a2 += blo(v2.y); a3 += bhi(v2.y);
    a4 += blo(v2.z); a5 += bhi(v2.z); a6 += blo(v2.w); a7 += bhi(v2.w);
    a0 += blo(v3.x); a1 += bhi(v3.x); a2 += blo(v3.y); a3 += bhi(v3.y);
    a4 += blo(v3.z); a5 += bhi(v3.z); a6 += blo(v3.w); a7 += bhi(v3.w);
  }
  for (; j < deg; ++j){
    uint4 v = *(const uint4*)(hp);
    hp += 64;
    a0 += blo(v.x); a1 += bhi(v.x); a2 += blo(v.y); a3 += bhi(v.y);
    a4 += blo(v.z); a5 += bhi(v.z); a6 += blo(v.w); a7 += bhi(v.w);
  }
  float rc = 1.0f / fmaxf((float)deg, 1.0f);
  float4 A = make_float4(a0*rc, a1*rc, a2*rc, a3*rc);
  float4 B = make_float4(a4*rc, a5*rc, a6*rc, a7*rc);
  unsigned h0 = cvtpk(A.x,A.y), h1v = cvtpk(A.z,A.w), h2 = cvtpk(B.x,B.y), h3v = cvtpk(B.z,B.w);
  *(uint4*)(zgh + rb + 64 + p*8) = make_uint4(h0,h1v,h2,h3v);
  unsigned l0 = cvtpk(A.x-__uint_as_float(h0<<16),  A.y-__uint_as_float(h0&0xffff0000u));
  unsigned l1 = cvtpk(A.z-__uint_as_float(h1v<<16), A.w-__uint_as_float(h1v&0xffff0000u));
  unsigned l2 = cvtpk(B.x-__uint_as_float(h2<<16),  B.y-__uint_as_float(h2&0xffff0000u));
  unsigned l3 = cvtpk(B.z-__uint_as_float(h3v<<16), B.w-__uint_as_float(h3v&0xffff0000u));
  *(uint4*)(zgl + rb + 64 + p*8) = make_uint4(l0,l1,l2,l3);
}

// ---------------- kernel 3: node MLP (MFMA hi/lo) + heads + reparam ----------------
// 256 threads / 64 nodes per block. Wave wv: GEMM1 n-tiles wv*4..+3 x m 0..3;
// GEMM2 n-tiles wv*2..+1 x m 0..3. A-planes: zg hi/lo bf16 (no unpack in GEMM1).
#define T2STR 132
#define ZSSTR 36
#define H3STR 260   // h3 stride (f32 / packed u32 elems), 16B-aligned rows
__global__ __launch_bounds__(256, 2) void k_node(
    const unsigned short* __restrict__ zgh, const unsigned short* __restrict__ zgl,
    const unsigned short* __restrict__ W3Th, const unsigned short* __restrict__ W3Tl,
    const float* __restrict__ b3,
    const float* __restrict__ g3, const float* __restrict__ be3,
    const unsigned short* __restrict__ W4Th, const unsigned short* __restrict__ W4Tl,
    const float* __restrict__ b4,
    const float* __restrict__ g4, const float* __restrict__ be4,
    const float* __restrict__ Wm, const float* __restrict__ bm,
    const float* __restrict__ Wv, const float* __restrict__ bv,
    const float* __restrict__ Wx, const float* __restrict__ bx,
    float* __restrict__ out){
  // arena (66,560 B): phase1 h3[64][H3STR] fp32 -> packed u32 in place.
  // After GEMM2 (reg-resident) t2[64][T2STR] fp32 overwrites [0,33792);
  // hm[64][64] at 33792; zs[64][ZSSTR] at 50176.
  __shared__ __align__(16) char arena[64*H3STR*4];
  float*    h3f = (float*)arena;
  unsigned* h3p = (unsigned*)arena;
  float*    t2S = (float*)arena;
  float*    hmS = (float*)(arena + 33792);
  float*    zsS = (float*)(arena + 50176);

  const int tid = threadIdx.x;
  const int base = blockIdx.x * 64;
  const int wv   = tid >> 6;        // 0..3
  const int lane = tid & 63;
  const int quad = lane >> 4;
  const int l16  = lane & 15;

  // ---- GEMM1 (MFMA): C[64x256] = Z[64x160] @ W3, hi/lo compensated; A from zg planes ----
  {
    f32x4 acc[4][4];   // [m-tile][n]
    #pragma unroll
    for (int m=0;m<4;m++)
      #pragma unroll
      for (int i=0;i<4;i++) acc[m][i] = (f32x4){0.f,0.f,0.f,0.f};
    #pragma unroll
    for (int ks=0; ks<5; ks++){
      bf16x8 ah[4], al[4];
      #pragma unroll
      for (int m=0;m<4;m++){
        size_t o = (size_t)(base + m*16 + l16)*160 + ks*32 + quad*8;
        ah[m] = *(const bf16x8*)(zgh + o);
        al[m] = *(const bf16x8*)(zgl + o);
      }
      #pragma unroll
      for (int i=0;i<4;i++){
        int nt = wv*4 + i;
        bf16x8 bh = *(const bf16x8*)(W3Th + (size_t)(nt*16 + l16)*160 + ks*32 + quad*8);
        bf16x8 bl = *(const bf16x8*)(W3Tl + (size_t)(nt*16 + l16)*160 + ks*32 + quad*8);
        #pragma unroll
        for (int m=0;m<4;m++){
          acc[m][i] = __builtin_amdgcn_mfma_f32_16x16x32_bf16(ah[m], bh, acc[m][i], 0, 0, 0);
          acc[m][i] = __builtin_amdgcn_mfma_f32_16x16x32_bf16(al[m], bh, acc[m][i], 0, 0, 0);
          acc[m][i] = __builtin_amdgcn_mfma_f32_16x16x32_bf16(ah[m], bl, acc[m][i], 0, 0, 0);
        }
      }
    }
    #pragma unroll
    for (int i=0;i<4;i++){
      int nt = wv*4 + i;
      float bc = b3[nt*16 + l16];
      #pragma unroll
      for (int m=0;m<4;m++)
        #pragma unroll
        for (int r=0;r<4;r++)
          h3f[(m*16 + quad*4 + r)*H3STR + nt*16 + l16] = acc[m][i][r] + bc;
    }
  }
  __syncthreads();   // B1a
  // ---- LN(256)+ReLU, pack hi/lo in place (16 rows per wave) ----
  {
    float4 gg  = *(const float4*)(g3 + lane*4);
    float4 bet = *(const float4*)(be3 + lane*4);
    #pragma unroll
    for (int r=0;r<16;r++){
      int row = wv*16 + r;
      float4 v = *(const float4*)(h3f + row*H3STR + lane*4);
      float s  = v.x + v.y + v.z + v.w;
      float ss = fmaf(v.x,v.x, fmaf(v.y,v.y, fmaf(v.z,v.z, v.w*v.w)));
      #pragma unroll
      for (int off=32; off; off>>=1){ s += __shfl_xor(s,off); ss += __shfl_xor(ss,off); }
      float mean = s * (1.0f/256.0f);
      float inv  = rsqrtf(ss*(1.0f/256.0f) - mean*mean + 1e-5f);
      float4 o;
      o.x = fmaxf(fmaf((v.x-mean)*inv, gg.x, bet.x), 0.f);
      o.y = fmaxf(fmaf((v.y-mean)*inv, gg.y, bet.y), 0.f);
      o.z = fmaxf(fmaf((v.z-mean)*inv, gg.z, bet.z), 0.f);
      o.w = fmaxf(fmaf((v.w-mean)*inv, gg.w, bet.w), 0.f);
      *(uint4*)(h3p + row*H3STR + lane*4) = pack4pk(o);
    }
  }
  __syncthreads();   // B1b
  // ---- GEMM2 (MFMA): C2[64x128] = H3[64x256] @ W4, hi/lo; results in regs, then t2 overwrites arena ----
  {
    f32x4 acc2[4][2];
    #pragma unroll
    for (int m=0;m<4;m++){ acc2[m][0] = (f32x4){0.f,0.f,0.f,0.f}; acc2[m][1] = (f32x4){0.f,0.f,0.f,0.f}; }
    #pragma unroll
    for (int ks=0; ks<8; ks++){
      bf16x8 ah[4], al[4];
      #pragma unroll
      for (int m=0;m<4;m++){
        const unsigned* ap = h3p + (m*16 + l16)*H3STR + ks*32 + quad*8;
        uint4 p0 = *(const uint4*)ap;
        uint4 p1 = *(const uint4*)(ap + 4);
        unpack8pk(p0, p1, ah[m], al[m]);
      }
      #pragma unroll
      for (int i=0;i<2;i++){
        int nt = wv*2 + i;
        bf16x8 bh = *(const bf16x8*)(W4Th + (size_t)(nt*16 + l16)*256 + ks*32 + quad*8);
        bf16x8 bl = *(const bf16x8*)(W4Tl + (size_t)(nt*16 + l16)*256 + ks*32 + quad*8);
        #pragma unroll
        for (int m=0;m<4;m++){
          acc2[m][i] = __builtin_amdgcn_mfma_f32_16x16x32_bf16(ah[m], bh, acc2[m][i], 0, 0, 0);
          acc2[m][i] = __builtin_amdgcn_mfma_f32_16x16x32_bf16(al[m], bh, acc2[m][i], 0, 0, 0);
          acc2[m][i] = __builtin_amdgcn_mfma_f32_16x16x32_bf16(ah[m], bl, acc2[m][i], 0, 0, 0);
        }
      }
    }
    __syncthreads();   // B2w: all waves done reading h3p; arena reusable
    #pragma unroll
    for (int i=0;i<2;i++){
      int nt = wv*2 + i;
      float bc = b4[nt*16 + l16];
      #pragma unroll
      for (int m=0;m<4;m++)
        #pragma unroll
        for (int r=0;r<4;r++)
          t2S[(m*16 + quad*4 + r)*T2STR + nt*16 + l16] = acc2[m][i][r] + bc;
    }
  }
  __syncthreads();   // B2a
  // ---- LN(128)+ReLU in place (fp32) ----
  {
    const int jq = tid & 31, rb = tid >> 5;   // rb 0..7
    float4 gg  = *(const float4*)(g4 + 4*jq);
    float4 bet = *(const float4*)(be4 + 4*jq);
    #pragma unroll
    for (int r=0;r<8;r++){
      int row = rb*8 + r;
      float4 v = *(const float4*)(t2S + row*T2STR + 4*jq);
      float s  = v.x + v.y + v.z + v.w;
      float ss = fmaf(v.x,v.x, fmaf(v.y,v.y, fmaf(v.z,v.z, v.w*v.w)));
      #pragma unroll
      for (int off=16; off; off>>=1){ s += __shfl_xor(s,off); ss += __shfl_xor(ss,off); }
      float mean = s * (1.0f/128.0f);
      float inv  = rsqrtf(ss*(1.0f/128.0f) - mean*mean + 1e-5f);
      float4 o;
      o.x = fmaxf(fmaf((v.x-mean)*inv, gg.x, bet.x), 0.f);
      o.y = fmaxf(fmaf((v.y-mean)*inv, gg.y, bet.y), 0.f);
      o.z = fmaxf(fmaf((v.z-mean)*inv, gg.z, bet.z), 0.f);
      o.w = fmaxf(fmaf((v.w-mean)*inv, gg.w, bet.w), 0.f);
      *(float4*)(t2S + row*T2STR + 4*jq) = o;
    }
  }
  __syncthreads();   // B2b
  // ---- heads: mu | lv  (fp32 VALU) ----
  {
    const int jq = tid & 15, rb = tid >> 4;   // rb 0..15, 4 rows each
    const float* Wp = (jq < 8) ? Wm : Wv;
    const int cq = (jq & 7) * 4;
    float4 acc[4];
    #pragma unroll
    for (int r=0;r<4;r++) acc[r] = make_float4(0.f,0.f,0.f,0.f);
    #pragma unroll 2
    for (int k=0;k<128;k+=4){
      float4 w0 = *(const float4*)(Wp + (k+0)*32 + cq);
      float4 w1 = *(const float4*)(Wp + (k+1)*32 + cq);
      float4 w2 = *(const float4*)(Wp + (k+2)*32 + cq);
      float4 w3 = *(const float4*)(Wp + (k+3)*32 + cq);
      #pragma unroll
      for (int r=0;r<4;r++){
        float4 z = *(const float4*)(t2S + (rb*4+r)*T2STR + k);
        fma4(acc[r], z.x, w0); fma4(acc[r], z.y, w1);
        fma4(acc[r], z.z, w2); fma4(acc[r], z.w, w3);
      }
    }
    const float* bp = (jq < 8) ? bm : bv;
    float4 bb = *(const float4*)(bp + cq);
    const long long sec = (jq < 8) ? (long long)NN*64 : ((long long)NN*64 + (long long)NN*32);
    #pragma unroll
    for (int r=0;r<4;r++){
      float4 v = acc[r];
      v.x += bb.x; v.y += bb.y; v.z += bb.z; v.w += bb.w;
      int rr = rb*4 + r;
      *(float4*)(hmS + rr*64 + ((jq<8)?0:32) + cq) = v;
      int n = base + rr;
      if (n < NN) *(float4*)(out + sec + (long long)n*32 + cq) = v;
    }
  }
  __syncthreads();   // B3
  // ---- reparameterize (64 rows x 32 = 2048 elems, 256 threads x 8) ----
  #pragma unroll
  for (int i=0;i<8;i++){
    int l = tid + 256*i;
    int r = l >> 5, jj = l & 31;
    float mu = hmS[r*64 + jj];
    float lv = hmS[r*64 + 32 + jj];
    unsigned idx = (unsigned)((base + r)*32 + jj);
    float e = eps_at(idx);
    zsS[r*ZSSTR + jj] = fmaf(e, expf(0.5f*lv), mu);
  }
  __syncthreads();   // B4
  // ---- out = zs @ Wx + bx (fp32 VALU) ----
  {
    const int jq = tid & 15, rb = tid >> 4;   // rb 0..15, 4 rows each
    float4 acc[4];
    #pragma unroll
    for (int r=0;r<4;r++) acc[r] = make_float4(0.f,0.f,0.f,0.f);
    #pragma unroll
    for (int k=0;k<32;k+=4){
      float4 w0 = *(const float4*)(Wx + (k+0)*64 + 4*jq);
      float4 w1 = *(const float4*)(Wx + (k+1)*64 + 4*jq);
      float4 w2 = *(const float4*)(Wx + (k+2)*64 + 4*jq);
      float4 w3 = *(const float4*)(Wx + (k+3)*64 + 4*jq);
      #pragma unroll
      for (int r=0;r<4;r++){
        float4 z = *(const float4*)(zsS + (rb*4+r)*ZSSTR + k);
        fma4(acc[r], z.x, w0); fma4(acc[r], z.y, w1);
        fma4(acc[r], z.z, w2); fma4(acc[r], z.w, w3);
      }
    }
    float4 bb = *(const float4*)(bx + 4*jq);
    #pragma unroll
    for (int r=0;r<4;r++){
      int n = base + rb*4 + r;
      if (n < NN){
        float4 v = acc[r];
        v.x += bb.x; v.y += bb.y; v.z += bb.z; v.w += bb.w;
        *(float4*)(out + (long long)n*64 + 4*jq) = v;
      }
    }
  }
}

extern "C" void kernel_launch(void* const* d_in, const int* in_sizes, int n_in,
                              void* d_out, int out_size, void* d_ws, size_t ws_size,
                              hipStream_t stream) {
  const float* x     = (const float*)d_in[0];
  const int*   ei    = (const int*)d_in[1];
  const float* ea    = (const float*)d_in[2];
  const float* u     = (const float*)d_in[3];
  const int*   batch = (const int*)d_in[4];
  const float* W1 = (const float*)d_in[6];
  const float* b1 = (const float*)d_in[7];
  const float* g1 = (const float*)d_in[8];
  const float* be1= (const float*)d_in[9];
  const float* W2 = (const float*)d_in[10];
  const float* b2 = (const float*)d_in[11];
  const float* W3 = (const float*)d_in[12];
  const float* b3 = (const float*)d_in[13];
  const float* g3 = (const float*)d_in[14];
  const float* be3= (const float*)d_in[15];
  const float* W4 = (const float*)d_in[16];
  const float* b4 = (const float*)d_in[17];
  const float* g4 = (const float*)d_in[18];
  const float* be4= (const float*)d_in[19];
  const float* Wm = (const float*)d_in[20];
  const float* bm = (const float*)d_in[21];
  const float* Wv = (const float*)d_in[22];
  const float* bv = (const float*)d_in[23];
  const float* Wx = (const float*)d_in[24];
  const float* bx = (const float*)d_in[25];

  char* W = (char*)d_ws;
  size_t off = 0;
  unsigned short* h_ws = (unsigned short*)(W + off); off += (size_t)EE*64*2;  // 51.2 MB bf16
  int* cnt      = (int*)(W + off);  off += (size_t)NN*4;
  int* offs     = (int*)(W + off);  off += (size_t)NN*4;
  int* cursor   = (int*)(W + off);  off += (size_t)NN*4;
  int* epos     = (int*)(W + off);  off += (size_t)EE*4;
  int* partials = (int*)(W + off);  off += 256;
  unsigned short* xb  = (unsigned short*)(W + off); off += (size_t)NN*64*2;  // 6.4 MB
  unsigned short* W1T = (unsigned short*)(W + off); off += 128*128*2;
  unsigned short* W2T = (unsigned short*)(W + off); off += 64*128*2;
  unsigned short* W3Th = (unsigned short*)(W + off); off += 256*160*2;
  unsigned short* W3Tl = (unsigned short*)(W + off); off += 256*160*2;
  unsigned short* W4Th = (unsigned short*)(W + off); off += 128*256*2;
  unsigned short* W4Tl = (unsigned short*)(W + off); off += 128*256*2;
  off = (off + 255) & ~(size_t)255;
  unsigned short* zgh = (unsigned short*)(W + off); off += (size_t)(NN + 64)*160*2;  // 16 MB hi plane
  unsigned short* zgl = (unsigned short*)(W + off); off += (size_t)(NN + 64)*160*2;  // 16 MB lo plane
  float* out = (float*)d_out;

  hipMemsetAsync(cnt, 0, (size_t)NN*sizeof(int), stream);

  k_prep_x<<<(NN*64/8 + 255)/256, 256, 0, stream>>>(x, xb);
  k_prep_w<<<1, 256, 0, stream>>>(W1, W2, W1T, W2T);
  k_prep_w34<<<384, 256, 0, stream>>>(W3, W4, W3Th, W3Tl, W4Th, W4Tl);
  k_hist <<<(EE+255)/256, 256, 0, stream>>>(ei, cnt);
  k_scan1<<<NB, 256, 0, stream>>>(cnt, offs, partials);
  k_scan2<<<1, 64, 0, stream>>>(partials);
  k_scan3<<<NB, 256, 0, stream>>>(offs, partials, cursor);
  k_fill <<<(EE+255)/256, 256, 0, stream>>>(ei, cursor, epos);

  k_edge<<<EE/64, 256, 0, stream>>>(ei, ea, xb, W1T, b1, g1, be1, W2T, b2, epos, h_ws);
  k_agg <<<(NN*8 + 255)/256, 256, 0, stream>>>(x, u, batch, h_ws, cnt, offs, zgh, zgl);
  k_node<<<(NN+63)/64, 256, 0, stream>>>(zgh, zgl,
                                         W3Th, W3Tl, b3, g3, be3,
                                         W4Th, W4Tl, b4, g4, be4,
                                         Wm,bm, Wv,bv, Wx,bx, out);
}